// Round 6
// baseline (863.367 us; speedup 1.0000x reference)
//
#include <hip/hip_runtime.h>
#include <stdint.h>

typedef unsigned short u16;
typedef __bf16 bf16x8 __attribute__((ext_vector_type(8)));
typedef float f32x4 __attribute__((ext_vector_type(4)));

#define D_MODEL 2048
#define NHEADS 16
#define DK 128
#define DFF 5504
#define DFFP 5632   // DFF padded to 256 multiple
#define BB 2
#define SS 2048
#define MTOK 4096
#define DQKV 6144

#define AS1 __attribute__((address_space(1)))
#define AS3 __attribute__((address_space(3)))

__device__ __forceinline__ u16 f2bf(float f){
  union { float f; uint32_t u; } v; v.f = f;
  uint32_t r = v.u + 0x7fffu + ((v.u >> 16) & 1u);
  return (u16)(r >> 16);
}
__device__ __forceinline__ float bf2f(u16 u){
  union { uint32_t u; float f; } v; v.u = ((uint32_t)u) << 16;
  return v.f;
}
__device__ __forceinline__ u16 cvt_bf16(float f){
  union { __bf16 h; u16 u; } v; v.h = (__bf16)f; return v.u;
}
__device__ __forceinline__ float fexp2(float x){
#if __has_builtin(__builtin_amdgcn_exp2f)
  return __builtin_amdgcn_exp2f(x);
#else
  return exp2f(x);
#endif
}

// ---- fp32 W[K][Nsrc] -> bf16 Wt[n][K], zero-fill n >= Nsrc (padded dest) ----
__global__ __launch_bounds__(256) void k_transpose_w(const float* __restrict__ W,
                                                     u16* __restrict__ Wt, int K, int Nsrc){
  __shared__ float tile[32][33];
  int n0 = blockIdx.x * 32, k0 = blockIdx.y * 32;
  int tx = threadIdx.x, ty = threadIdx.y;  // (32,8)
  #pragma unroll
  for (int r = 0; r < 4; ++r){
    int n = n0 + tx;
    tile[ty + r*8][tx] = (n < Nsrc) ? W[(size_t)(k0 + ty + r*8) * Nsrc + n] : 0.0f;
  }
  __syncthreads();
  #pragma unroll
  for (int r = 0; r < 4; ++r)
    Wt[(size_t)(n0 + ty + r*8) * K + k0 + tx] = f2bf(tile[tx][ty + r*8]);
}

// ---- per-head V transpose from fused QKV ----
__global__ __launch_bounds__(256) void k_transpose_v(const u16* __restrict__ V,
                                                     u16* __restrict__ Vt, int ld){
  __shared__ u16 tile[32][33];
  int s0 = blockIdx.x * 32;
  int bh = blockIdx.y >> 2, dt = blockIdx.y & 3;
  int b = bh >> 4, h = bh & 15;
  int tx = threadIdx.x, ty = threadIdx.y;
  #pragma unroll
  for (int r = 0; r < 4; ++r)
    tile[ty + r*8][tx] = V[(size_t)(b*SS + s0 + ty + r*8) * ld + h*DK + dt*32 + tx];
  __syncthreads();
  #pragma unroll
  for (int r = 0; r < 4; ++r)
    Vt[(size_t)(bh*DK + dt*32 + ty + r*8) * SS + s0 + tx] = tile[tx][ty + r*8];
}

__global__ __launch_bounds__(256) void k_concat3(const float* __restrict__ a,
                                                 const float* __restrict__ b,
                                                 const float* __restrict__ c,
                                                 float* __restrict__ o){
  int i = blockIdx.x*256 + threadIdx.x;
  if (i >= DQKV) return;
  o[i] = (i < 2048) ? a[i] : (i < 4096 ? b[i-2048] : c[i-4096]);
}

// ---- RMSNorm: fp32 row -> bf16 row ----
__global__ __launch_bounds__(256) void k_rmsnorm(const float* __restrict__ X,
                                                 const float* __restrict__ g,
                                                 u16* __restrict__ out){
  int row = blockIdx.x, tid = threadIdx.x;
  const float* x = X + (size_t)row * D_MODEL;
  float4 a = ((const float4*)x)[tid*2];
  float4 b = ((const float4*)x)[tid*2+1];
  float ss = a.x*a.x + a.y*a.y + a.z*a.z + a.w*a.w
           + b.x*b.x + b.y*b.y + b.z*b.z + b.w*b.w;
  #pragma unroll
  for (int m = 1; m < 64; m <<= 1) ss += __shfl_xor(ss, m, 64);
  __shared__ float red[4];
  if ((tid & 63) == 0) red[tid >> 6] = ss;
  __syncthreads();
  float tot = red[0] + red[1] + red[2] + red[3];
  float sc = rsqrtf(tot * (1.0f / D_MODEL) + 1e-6f);
  float4 ga = ((const float4*)g)[tid*2];
  float4 gb = ((const float4*)g)[tid*2+1];
  uint32_t w0 = f2bf(a.x*sc*ga.x) | ((uint32_t)f2bf(a.y*sc*ga.y) << 16);
  uint32_t w1 = f2bf(a.z*sc*ga.z) | ((uint32_t)f2bf(a.w*sc*ga.w) << 16);
  uint32_t w2 = f2bf(b.x*sc*gb.x) | ((uint32_t)f2bf(b.y*sc*gb.y) << 16);
  uint32_t w3 = f2bf(b.z*sc*gb.z) | ((uint32_t)f2bf(b.w*sc*gb.w) << 16);
  ((uint4*)(out + (size_t)row * D_MODEL))[tid] = make_uint4(w0, w1, w2, w3);
}

// ================= 256x256 8-wave GEMM, 4-buffer counted-vmcnt pipeline =================
// C[M][N] (ldc) = A[M][K](lda) * Bt[N][K](ldb)^T. K%32==0, M%256==0, N%256==0.
// LDS: 4 bufs x (A 256x32 | B 256x32) bf16 = 128 KiB dynamic.
// Swizzle (both sides): phys_chunk = chunk ^ ((row>>1)&3)  -> 2-way banks (free).
// EPI 0: bf16 out +bias; EPI 2: bf16 out; EPI 4: bf16 out, silu(aux)*acc in-place.
template<int EPI>
__global__ __launch_bounds__(512, 2) void k_gemm256(
    const u16* __restrict__ A, const u16* __restrict__ Bt,
    const float* __restrict__ bias, const u16* __restrict__ aux,
    void* __restrict__ Cout, int M, int N, int K,
    int lda, int ldb, int ldc)
{
  extern __shared__ __align__(16) char smem[];
  int tid = threadIdx.x;
  int lane = tid & 63, wid = tid >> 6;
  int wr = wid >> 2, wc = wid & 3;
  int lrow = lane & 15, lhi = lane >> 4;

  // bijective XCD swizzle (m204), row-major over N
  int nwg = gridDim.x, wg = blockIdx.x;
  int qq = nwg >> 3, rr = nwg & 7;
  int xcd = wg & 7, sub = wg >> 3;
  int swz = (xcd < rr ? xcd*(qq+1) : rr*(qq+1) + (xcd-rr)*qq) + sub;
  int nbx = N >> 8;
  int m0 = (swz / nbx) << 8, n0 = (swz % nbx) << 8;

  const int nk = K >> 5;

  auto stageA = [&](int tt){
    int b = tt & 3, kk = tt << 5;
    #pragma unroll
    for (int L = 0; L < 2; ++L){
      int slot = L*512 + tid;
      int row = slot >> 2, pc = slot & 3;
      int c = pc ^ ((row >> 1) & 3);
      __builtin_amdgcn_global_load_lds(
        (const AS1 void*)(A + (size_t)(m0 + row)*lda + kk + c*8),
        (AS3 void*)(smem + b*32768 + slot*16), 16, 0, 0);
    }
  };
  auto stageB = [&](int tt){
    int b = tt & 3, kk = tt << 5;
    #pragma unroll
    for (int L = 0; L < 2; ++L){
      int slot = L*512 + tid;
      int row = slot >> 2, pc = slot & 3;
      int c = pc ^ ((row >> 1) & 3);
      __builtin_amdgcn_global_load_lds(
        (const AS1 void*)(Bt + (size_t)(n0 + row)*ldb + kk + c*8),
        (AS3 void*)(smem + b*32768 + 16384 + slot*16), 16, 0, 0);
    }
  };
  auto ldsA = [&](int b, int row)->bf16x8 {
    int phys = lhi ^ ((row >> 1) & 3);
    return *(const bf16x8*)(smem + b*32768 + row*64 + phys*16);
  };
  auto ldsB = [&](int b, int row)->bf16x8 {
    int phys = lhi ^ ((row >> 1) & 3);
    return *(const bf16x8*)(smem + b*32768 + 16384 + row*64 + phys*16);
  };

  f32x4 acc[8][4] = {};

  // prologue: stage tiles 0,1; wait tile 0 (keep tile 1 in flight)
  stageA(0); stageB(0);
  stageA(1); stageB(1);
  asm volatile("s_waitcnt vmcnt(4)" ::: "memory");
  __builtin_amdgcn_sched_barrier(0);
  __builtin_amdgcn_s_barrier();

  for (int t = 0; t < nk; ++t){
    int cb = t & 3;
    bool pf = (t + 2 < nk);
    // ---- phase 0: frags (A rows 0-63 of wave half + all B) ----
    bf16x8 a0[4], b0[4];
    #pragma unroll
    for (int i = 0; i < 4; ++i) a0[i] = ldsA(cb, wr*128 + i*16 + lrow);
    #pragma unroll
    for (int j = 0; j < 4; ++j) b0[j] = ldsB(cb, wc*64 + j*16 + lrow);
    if (pf) stageA(t + 2);
    __builtin_amdgcn_s_barrier();
    asm volatile("s_waitcnt lgkmcnt(0)" ::: "memory");
    __builtin_amdgcn_sched_barrier(0);
    __builtin_amdgcn_s_setprio(1);
    #pragma unroll
    for (int i = 0; i < 4; ++i)
      #pragma unroll
      for (int j = 0; j < 4; ++j)
        acc[i][j] = __builtin_amdgcn_mfma_f32_16x16x32_bf16(a0[i], b0[j], acc[i][j], 0, 0, 0);
    __builtin_amdgcn_s_setprio(0);
    __builtin_amdgcn_s_barrier();
    // ---- phase 1: frags (A rows 64-127), reuse B ----
    bf16x8 a1[4];
    #pragma unroll
    for (int i = 0; i < 4; ++i) a1[i] = ldsA(cb, wr*128 + 64 + i*16 + lrow);
    if (pf) stageB(t + 2);
    __builtin_amdgcn_s_barrier();
    asm volatile("s_waitcnt lgkmcnt(0)" ::: "memory");
    __builtin_amdgcn_sched_barrier(0);
    __builtin_amdgcn_s_setprio(1);
    #pragma unroll
    for (int i = 0; i < 4; ++i)
      #pragma unroll
      for (int j = 0; j < 4; ++j)
        acc[4+i][j] = __builtin_amdgcn_mfma_f32_16x16x32_bf16(a1[i], b0[j], acc[4+i][j], 0, 0, 0);
    __builtin_amdgcn_s_setprio(0);
    // counted drain once per K-tile: tile t+1 landed, tile t+2's 4 stay in flight
    if (pf) asm volatile("s_waitcnt vmcnt(4)" ::: "memory");
    else    asm volatile("s_waitcnt vmcnt(0)" ::: "memory");
    __builtin_amdgcn_sched_barrier(0);
    __builtin_amdgcn_s_barrier();
  }

  #pragma unroll
  for (int i = 0; i < 8; ++i){
    #pragma unroll
    for (int j = 0; j < 4; ++j){
      int col = n0 + wc*64 + j*16 + lrow;
      float bv = 0.f;
      if constexpr (EPI == 0) bv = bias[col];
      #pragma unroll
      for (int q = 0; q < 4; ++q){
        int row = m0 + wr*128 + i*16 + lhi*4 + q;
        size_t idx = (size_t)row*ldc + col;
        float v = acc[i][j][q] + bv;
        if constexpr (EPI == 4){
          float a0v = bf2f(aux[idx]);
          v = a0v / (1.f + __expf(-a0v)) * v;
        }
        ((u16*)Cout)[idx] = f2bf(v);
      }
    }
  }
}

// ---- 128x128 GEMM (m97 structure, 3-buffer counted vmcnt) with ld params ----
// EPI 1: f32 out +bias +res; EPI 3: f32 out +res; EPI 0/2/4 as before (fallback path)
template<int EPI>
__global__ __launch_bounds__(256) void k_gemm_bt(
    const u16* __restrict__ A, const u16* __restrict__ Bt,
    const float* __restrict__ bias, const float* __restrict__ res,
    const u16* __restrict__ aux,
    void* __restrict__ Cout, int M, int N, int K,
    int lda, int ldb, int ldc)
{
  __shared__ __align__(16) u16 As[3][128*32];
  __shared__ __align__(16) u16 Bs[3][128*32];
  int tid = threadIdx.x;

  int nwg = gridDim.x, wg = blockIdx.x;
  int qq = nwg >> 3, rr = nwg & 7;
  int xcd = wg & 7, sub = wg >> 3;
  int swz = (xcd < rr ? xcd*(qq+1) : rr*(qq+1) + (xcd-rr)*qq) + sub;
  int nbx = N >> 7;
  int m0 = (swz / nbx) << 7, n0 = (swz % nbx) << 7;

  int lane = tid & 63, wave = tid >> 6;
  int wr = wave >> 1, wc = wave & 1;
  int lrow = lane & 15, lhi = lane >> 4;
  f32x4 acc[4][4] = {};
  int srow = tid >> 2;
  int scol = (tid & 3) * 8;
  const int nk = K >> 5;

  auto stage = [&](int slot, int kt){
    int k0 = kt << 5;
    #pragma unroll
    for (int c = 0; c < 2; ++c){
      int r = c*64 + srow;
      __builtin_amdgcn_global_load_lds(
        (const AS1 void*)(A + (size_t)(m0 + r)*lda + k0 + scol),
        (AS3 void*)(&As[slot][r*32 + scol]), 16, 0, 0);
      __builtin_amdgcn_global_load_lds(
        (const AS1 void*)(Bt + (size_t)(n0 + r)*ldb + k0 + scol),
        (AS3 void*)(&Bs[slot][r*32 + scol]), 16, 0, 0);
    }
  };

  stage(0, 0);
  if (nk > 1) stage(1, 1);
  if (nk > 1) asm volatile("s_waitcnt vmcnt(4)" ::: "memory");
  else        asm volatile("s_waitcnt vmcnt(0)" ::: "memory");
  __builtin_amdgcn_s_barrier();

  for (int kt = 0; kt < nk; ++kt){
    int cur = kt % 3;
    if (kt + 2 < nk) stage((kt + 2) % 3, kt + 2);
    bf16x8 af[4], bfv[4];
    #pragma unroll
    for (int i = 0; i < 4; ++i){
      af[i]  = *(const bf16x8*)(&As[cur][(wr*64 + i*16 + lrow)*32 + lhi*8]);
      bfv[i] = *(const bf16x8*)(&Bs[cur][(wc*64 + i*16 + lrow)*32 + lhi*8]);
    }
    #pragma unroll
    for (int i = 0; i < 4; ++i)
      #pragma unroll
      for (int j = 0; j < 4; ++j)
        acc[i][j] = __builtin_amdgcn_mfma_f32_16x16x32_bf16(af[i], bfv[j], acc[i][j], 0, 0, 0);
    if (kt + 2 < nk) asm volatile("s_waitcnt vmcnt(4)" ::: "memory");
    else             asm volatile("s_waitcnt vmcnt(0)" ::: "memory");
    __builtin_amdgcn_s_barrier();
  }

  #pragma unroll
  for (int i = 0; i < 4; ++i){
    #pragma unroll
    for (int j = 0; j < 4; ++j){
      int col = n0 + wc*64 + j*16 + lrow;
      float bv = 0.f;
      if constexpr (EPI == 0 || EPI == 1) bv = bias[col];
      #pragma unroll
      for (int q = 0; q < 4; ++q){
        int row = m0 + wr*64 + i*16 + lhi*4 + q;
        size_t idx = (size_t)row*ldc + col;
        float v = acc[i][j][q] + bv;
        if constexpr (EPI == 1 || EPI == 3) v += res[idx];
        if constexpr (EPI == 4){
          float a0 = bf2f(aux[idx]);
          v = a0 / (1.f + __expf(-a0)) * v;
        }
        if constexpr (EPI == 0 || EPI == 2 || EPI == 4) ((u16*)Cout)[idx] = f2bf(v);
        else ((float*)Cout)[idx] = v;
      }
    }
  }
}

// ---- causal flash attention, 2-phase pipelined LDS staging (unchanged) ----
__global__ __launch_bounds__(256) void k_attn(
    const u16* __restrict__ Q, const u16* __restrict__ Kb,
    const u16* __restrict__ Vt, u16* __restrict__ O, int ldq)
{
  int tid = threadIdx.x, lane = tid & 63, wave = tid >> 6;
  int lrow = lane & 15, lhi = lane >> 4;
  int bh = blockIdx.y, b = bh >> 4, h = bh & 15;
  int qi = gridDim.x - 1 - blockIdx.x;
  int qs = qi * 64;
  int nt = qi + 1;
  int qrow = qs + wave * 16;

  __shared__ __align__(16) u16 Kbuf[2][64*128];
  __shared__ __align__(16) u16 Vbuf[2][128*64];
  __shared__ __align__(16) u16 P_lds[4][16*64];
  char* pw = (char*)&P_lds[wave][0];
  const float sc2 = 0.08838834764831845f * 1.44269504088896340736f;

  bf16x8 qf[4];
  const u16* qbase = Q + (size_t)(b*SS + qrow + lrow)*ldq + h*DK + lhi*8;
  #pragma unroll
  for (int dc = 0; dc < 4; ++dc) qf[dc] = *(const bf16x8*)(qbase + dc*32);

  auto stage = [&](int bufi, int kt){
    int kv0 = kt << 6;
    char* kd = (char*)&Kbuf[bufi][0];
    char* vd = (char*)&Vbuf[bufi][0];
    #pragma unroll
    for (int p = 0; p < 4; ++p){
      int r  = p*16 + wave*4 + (lane >> 4);
      int cg = (lane & 15) ^ (r & 7);
      __builtin_amdgcn_global_load_lds(
        (const AS1 void*)(Kb + (size_t)(b*SS + kv0 + r)*ldq + h*DK + cg*8),
        (AS3 void*)(kd + p*4096 + wave*1024 + lane*16), 16, 0, 0);
      int d  = p*32 + wave*8 + (lane >> 3);
      int cv = (lane & 7) ^ (d & 7);
      __builtin_amdgcn_global_load_lds(
        (const AS1 void*)(Vt + (size_t)bh*DK*SS + (size_t)d*SS + kv0 + cv*8),
        (AS3 void*)(vd + p*4096 + wave*1024 + lane*16), 16, 0, 0);
    }
  };

  f32x4 accO[8] = {};
  float mr[4] = {-1e30f,-1e30f,-1e30f,-1e30f};
  float lr[4] = {0.f,0.f,0.f,0.f};

  stage(0, 0);
  __syncthreads();

  for (int kt = 0; kt < nt; ++kt){
    int cur = kt & 1;
    if (kt + 1 < nt) stage(cur ^ 1, kt + 1);
    int kv0 = kt << 6;
    const char* kl = (const char*)&Kbuf[cur][0];
    const char* vl = (const char*)&Vbuf[cur][0];

    f32x4 sf[4];
    #pragma unroll
    for (int hf = 0; hf < 4; ++hf){
      int rl = hf*16 + lrow;
      int sw = rl & 7;
      f32x4 a = {};
      #pragma unroll
      for (int dc = 0; dc < 4; ++dc){
        bf16x8 kf = *(const bf16x8*)(kl + rl*256 + (((lhi + dc*4) ^ sw) << 4));
        a = __builtin_amdgcn_mfma_f32_16x16x32_bf16(qf[dc], kf, a, 0, 0, 0);
      }
      sf[hf] = a;
    }

    float p[4][4], mx[4];
    #pragma unroll
    for (int q = 0; q < 4; ++q){
      float s0 = sf[0][q]*sc2, s1 = sf[1][q]*sc2, s2 = sf[2][q]*sc2, s3 = sf[3][q]*sc2;
      if (kt == nt - 1){
        int qg = qrow + lhi*4 + q;
        if (kv0      + lrow > qg) s0 = -1e30f;
        if (kv0 + 16 + lrow > qg) s1 = -1e30f;
        if (kv0 + 32 + lrow > qg) s2 = -1e30f;
        if (kv0 + 48 + lrow > qg) s3 = -1e30f;
      }
      p[q][0]=s0; p[q][1]=s1; p[q][2]=s2; p[q][3]=s3;
      float m = fmaxf(fmaxf(s0,s1), fmaxf(s2,s3));
      m = fmaxf(m, __shfl_xor(m, 1, 64));
      m = fmaxf(m, __shfl_xor(m, 2, 64));
      m = fmaxf(m, __shfl_xor(m, 4, 64));
      m = fmaxf(m, __shfl_xor(m, 8, 64));
      mx[q] = m;
    }
    float dmax = fmaxf(fmaxf(mx[0]-mr[0], mx[1]-mr[1]), fmaxf(mx[2]-mr[2], mx[3]-mr[3]));
    bool rescale = !__all(dmax <= 8.0f);
    float al[4];
    #pragma unroll
    for (int q = 0; q < 4; ++q){
      if (rescale){
        float mn = fmaxf(mr[q], mx[q]);
        al[q] = fexp2(mr[q] - mn);
        mr[q] = mn;
      } else al[q] = 1.0f;
      p[q][0] = fexp2(p[q][0] - mr[q]);
      p[q][1] = fexp2(p[q][1] - mr[q]);
      p[q][2] = fexp2(p[q][2] - mr[q]);
      p[q][3] = fexp2(p[q][3] - mr[q]);
      float sm = (p[q][0] + p[q][1]) + (p[q][2] + p[q][3]);
      sm += __shfl_xor(sm, 1, 64);
      sm += __shfl_xor(sm, 2, 64);
      sm += __shfl_xor(sm, 4, 64);
      sm += __shfl_xor(sm, 8, 64);
      lr[q] = lr[q]*al[q] + sm;
    }
    if (rescale){
      #pragma unroll
      for (int f = 0; f < 8; ++f)
        #pragma unroll
        for (int q = 0; q < 4; ++q) accO[f][q] *= al[q];
    }

    #pragma unroll
    for (int q = 0; q < 4; ++q){
      int row = lhi*4 + q;
      int rb = row*128, sw = (row & 7) << 4;
      #pragma unroll
      for (int hf = 0; hf < 4; ++hf)
        *(u16*)(pw + rb + ((hf*32 + lrow*2) ^ sw)) = cvt_bf16(p[q][hf]);
    }
    __builtin_amdgcn_sched_barrier(0);
    int rsw = (lrow & 7) << 4;
    bf16x8 pa0 = *(const bf16x8*)(pw + lrow*128 + ((     lhi*16) ^ rsw));
    bf16x8 pa1 = *(const bf16x8*)(pw + lrow*128 + ((64 + lhi*16) ^ rsw));

    #pragma unroll
    for (int f = 0; f < 8; ++f){
      int d = f*16 + lrow;
      int swv = d & 7;
      bf16x8 v0 = *(const bf16x8*)(vl + d*128 + (((lhi    ) ^ swv) << 4));
      bf16x8 v1 = *(const bf16x8*)(vl + d*128 + (((lhi + 4) ^ swv) << 4));
      accO[f] = __builtin_amdgcn_mfma_f32_16x16x32_bf16(pa0, v0, accO[f], 0, 0, 0);
      accO[f] = __builtin_amdgcn_mfma_f32_16x16x32_bf16(pa1, v1, accO[f], 0, 0, 0);
    }

    __syncthreads();
  }

  #pragma unroll
  for (int q = 0; q < 4; ++q){
    float inv = 1.0f / lr[q];
    #pragma unroll
    for (int f = 0; f < 8; ++f){
      int row = b*SS + qrow + lhi*4 + q;
      int col = h*DK + f*16 + lrow;
      O[(size_t)row*D_MODEL + col] = cvt_bf16(accO[f][q] * inv);
    }
  }
}

extern "C" void kernel_launch(void* const* d_in, const int* in_sizes, int n_in,
                              void* d_out, int out_size, void* d_ws, size_t ws_size,
                              hipStream_t stream)
{
  (void)in_sizes; (void)n_in; (void)out_size;
  const float* x  = (const float*)d_in[0];
  const float* wq = (const float*)d_in[2];
  const float* bq = (const float*)d_in[3];
  const float* wk = (const float*)d_in[4];
  const float* bk = (const float*)d_in[5];
  const float* wv = (const float*)d_in[6];
  const float* bv = (const float*)d_in[7];
  const float* wo = (const float*)d_in[8];
  const float* bo = (const float*)d_in[9];
  const float* g1 = (const float*)d_in[10];
  const float* g2 = (const float*)d_in[11];
  const float* w1 = (const float*)d_in[12];
  const float* w3 = (const float*)d_in[13];  // w3 precedes w2 in dict order
  const float* w2 = (const float*)d_in[14];
  float* out = (float*)d_out;

  const size_t MB = 1u << 20;
  const size_t WFF2 = (size_t)D_MODEL * DFF * sizeof(u16);   // w2t bytes
  const size_t NEED = 112*MB + WFF2 + 32768;
  if (ws_size < NEED) return;
  char* ws = (char*)d_ws;
  u16* bufA = (u16*)(ws + 0);        // 16 MiB: nbf1 -> aob -> nbf2
  u16* qkv  = (u16*)(ws + 16*MB);    // 48 MiB fused QKV [4096][6144]
  u16* h1   = qkv;                   // [4096][5632] = 46.1 MiB, aliases qkv after attn
  u16* wqkvt= (u16*)(ws + 64*MB);    // 24 MiB: wq^T|wk^T|wv^T [6144][2048]
  u16* w1t  = wqkvt;                 // [5632][2048] = 23.07 MiB, aliases after QKV GEMM
  u16* wot  = (u16*)(ws + 88*MB);    // 8 MiB
  u16* w3t  = (u16*)(ws + 88*MB);    // [5632][2048], aliases wot+vtb after O-proj
  u16* vtb  = (u16*)(ws + 96*MB);    // 16 MiB
  u16* w2t  = (u16*)(ws + 112*MB);   // [2048][5504] = 22.54 MiB
  float* bqkv = (float*)(ws + 112*MB + WFF2);
  // fp32 residual x1 lives in d_out

  // dynamic-LDS opt-in for the 256^2 kernels (capture-safe: not a stream op)
  bool big = true;
  big &= hipFuncSetAttribute((const void*)k_gemm256<0>, hipFuncAttributeMaxDynamicSharedMemorySize, 131072) == hipSuccess;
  big &= hipFuncSetAttribute((const void*)k_gemm256<2>, hipFuncAttributeMaxDynamicSharedMemorySize, 131072) == hipSuccess;
  big &= hipFuncSetAttribute((const void*)k_gemm256<4>, hipFuncAttributeMaxDynamicSharedMemorySize, 131072) == hipSuccess;

  dim3 tb(32, 8);
  k_transpose_w<<<dim3(64,64), tb, 0, stream>>>(wq, wqkvt,               D_MODEL, D_MODEL);
  k_transpose_w<<<dim3(64,64), tb, 0, stream>>>(wk, wqkvt + 2048*2048,   D_MODEL, D_MODEL);
  k_transpose_w<<<dim3(64,64), tb, 0, stream>>>(wv, wqkvt + 2*2048*2048, D_MODEL, D_MODEL);
  k_transpose_w<<<dim3(64,64), tb, 0, stream>>>(wo, wot, D_MODEL, D_MODEL);
  k_transpose_w<<<dim3(64, DFF/32), tb, 0, stream>>>(w2, w2t, DFF, D_MODEL);
  k_concat3<<<24, 256, 0, stream>>>(bq, bk, bv, bqkv);

  k_rmsnorm<<<MTOK, 256, 0, stream>>>(x, g1, bufA);
  if (big)
    k_gemm256<0><<<(MTOK/256)*(DQKV/256), 512, 131072, stream>>>(bufA, wqkvt, bqkv, nullptr, qkv, MTOK, DQKV, D_MODEL, D_MODEL, D_MODEL, DQKV);
  else
    k_gemm_bt<0><<<(DQKV/128)*(MTOK/128), 256, 0, stream>>>(bufA, wqkvt, bqkv, nullptr, nullptr, qkv, MTOK, DQKV, D_MODEL, D_MODEL, D_MODEL, DQKV);
  k_transpose_v<<<dim3(SS/32, 128), tb, 0, stream>>>(qkv + 4096, vtb, DQKV);
  k_attn<<<dim3(SS/64, BB*NHEADS), 256, 0, stream>>>(qkv, qkv + 2048, vtb, bufA, DQKV);
  // w1 transpose into wqkvt region (dead after QKV GEMM); padded rows [5504,5632) zeroed
  k_transpose_w<<<dim3(DFFP/32, 64), tb, 0, stream>>>(w1, w1t, D_MODEL, DFF);
  k_gemm_bt<1><<<16*32, 256, 0, stream>>>(bufA, wot, bo, x, nullptr, out, MTOK, D_MODEL, D_MODEL, D_MODEL, D_MODEL, D_MODEL);
  // w3 transpose into wot+vtb region (dead after O-proj / attn)
  k_transpose_w<<<dim3(DFFP/32, 64), tb, 0, stream>>>(w3, w3t, D_MODEL, DFF);
  k_rmsnorm<<<MTOK, 256, 0, stream>>>(out, g2, bufA);
  if (big){
    k_gemm256<2><<<(MTOK/256)*(DFFP/256), 512, 131072, stream>>>(bufA, w1t, nullptr, nullptr, h1, MTOK, DFFP, D_MODEL, D_MODEL, D_MODEL, DFFP);
    k_gemm256<4><<<(MTOK/256)*(DFFP/256), 512, 131072, stream>>>(bufA, w3t, nullptr, h1, h1, MTOK, DFFP, D_MODEL, D_MODEL, D_MODEL, DFFP);
  } else {
    k_gemm_bt<2><<<(DFFP/128)*32, 256, 0, stream>>>(bufA, w1t, nullptr, nullptr, nullptr, h1, MTOK, DFFP, D_MODEL, D_MODEL, D_MODEL, DFFP);
    k_gemm_bt<4><<<(DFFP/128)*32, 256, 0, stream>>>(bufA, w3t, nullptr, nullptr, h1, h1, MTOK, DFFP, D_MODEL, D_MODEL, D_MODEL, DFFP);
  }
  // W2: A=h1 [4096][5632] (lda=DFFP), B=w2t [2048][5504] (ldb=DFF), K=DFF
  k_gemm_bt<3><<<16*32, 256, 0, stream>>>(h1, w2t, nullptr, out, nullptr, out, MTOK, D_MODEL, DFF, DFFP, DFF, D_MODEL);
}

// Round 7
// 841.414 us; speedup vs baseline: 1.0261x; 1.0261x over previous
//
#include <hip/hip_runtime.h>
#include <stdint.h>

typedef unsigned short u16;
typedef __bf16 bf16x8 __attribute__((ext_vector_type(8)));
typedef float f32x4 __attribute__((ext_vector_type(4)));

#define D_MODEL 2048
#define NHEADS 16
#define DK 128
#define DFF 5504
#define DFFP 5632   // DFF padded to 256 multiple
#define BB 2
#define SS 2048
#define MTOK 4096
#define DQKV 6144

#define AS1 __attribute__((address_space(1)))
#define AS3 __attribute__((address_space(3)))

__device__ __forceinline__ u16 f2bf(float f){
  union { float f; uint32_t u; } v; v.f = f;
  uint32_t r = v.u + 0x7fffu + ((v.u >> 16) & 1u);
  return (u16)(r >> 16);
}
__device__ __forceinline__ float bf2f(u16 u){
  union { uint32_t u; float f; } v; v.u = ((uint32_t)u) << 16;
  return v.f;
}
__device__ __forceinline__ u16 cvt_bf16(float f){
  union { __bf16 h; u16 u; } v; v.h = (__bf16)f; return v.u;
}
__device__ __forceinline__ float fexp2(float x){
#if __has_builtin(__builtin_amdgcn_exp2f)
  return __builtin_amdgcn_exp2f(x);
#else
  return exp2f(x);
#endif
}

// ---- fp32 W[K][Nsrc] -> bf16 Wt[n][K], zero-fill n >= Nsrc ----
__global__ __launch_bounds__(256) void k_transpose_w(const float* __restrict__ W,
                                                     u16* __restrict__ Wt, int K, int Nsrc){
  __shared__ float tile[32][33];
  int n0 = blockIdx.x * 32, k0 = blockIdx.y * 32;
  int tx = threadIdx.x, ty = threadIdx.y;  // (32,8)
  #pragma unroll
  for (int r = 0; r < 4; ++r){
    int n = n0 + tx;
    tile[ty + r*8][tx] = (n < Nsrc) ? W[(size_t)(k0 + ty + r*8) * Nsrc + n] : 0.0f;
  }
  __syncthreads();
  #pragma unroll
  for (int r = 0; r < 4; ++r)
    Wt[(size_t)(n0 + ty + r*8) * K + k0 + tx] = f2bf(tile[tx][ty + r*8]);
}

// ---- per-head V transpose from fused QKV ----
__global__ __launch_bounds__(256) void k_transpose_v(const u16* __restrict__ V,
                                                     u16* __restrict__ Vt, int ld){
  __shared__ u16 tile[32][33];
  int s0 = blockIdx.x * 32;
  int bh = blockIdx.y >> 2, dt = blockIdx.y & 3;
  int b = bh >> 4, h = bh & 15;
  int tx = threadIdx.x, ty = threadIdx.y;
  #pragma unroll
  for (int r = 0; r < 4; ++r)
    tile[ty + r*8][tx] = V[(size_t)(b*SS + s0 + ty + r*8) * ld + h*DK + dt*32 + tx];
  __syncthreads();
  #pragma unroll
  for (int r = 0; r < 4; ++r)
    Vt[(size_t)(bh*DK + dt*32 + ty + r*8) * SS + s0 + tx] = tile[tx][ty + r*8];
}

__global__ __launch_bounds__(256) void k_concat3(const float* __restrict__ a,
                                                 const float* __restrict__ b,
                                                 const float* __restrict__ c,
                                                 float* __restrict__ o){
  int i = blockIdx.x*256 + threadIdx.x;
  if (i >= DQKV) return;
  o[i] = (i < 2048) ? a[i] : (i < 4096 ? b[i-2048] : c[i-4096]);
}

// ---- RMSNorm: fp32 row -> bf16 row ----
__global__ __launch_bounds__(256) void k_rmsnorm(const float* __restrict__ X,
                                                 const float* __restrict__ g,
                                                 u16* __restrict__ out){
  int row = blockIdx.x, tid = threadIdx.x;
  const float* x = X + (size_t)row * D_MODEL;
  float4 a = ((const float4*)x)[tid*2];
  float4 b = ((const float4*)x)[tid*2+1];
  float ss = a.x*a.x + a.y*a.y + a.z*a.z + a.w*a.w
           + b.x*b.x + b.y*b.y + b.z*b.z + b.w*b.w;
  #pragma unroll
  for (int m = 1; m < 64; m <<= 1) ss += __shfl_xor(ss, m, 64);
  __shared__ float red[4];
  if ((tid & 63) == 0) red[tid >> 6] = ss;
  __syncthreads();
  float tot = red[0] + red[1] + red[2] + red[3];
  float sc = rsqrtf(tot * (1.0f / D_MODEL) + 1e-6f);
  float4 ga = ((const float4*)g)[tid*2];
  float4 gb = ((const float4*)g)[tid*2+1];
  uint32_t w0 = f2bf(a.x*sc*ga.x) | ((uint32_t)f2bf(a.y*sc*ga.y) << 16);
  uint32_t w1 = f2bf(a.z*sc*ga.z) | ((uint32_t)f2bf(a.w*sc*ga.w) << 16);
  uint32_t w2 = f2bf(b.x*sc*gb.x) | ((uint32_t)f2bf(b.y*sc*gb.y) << 16);
  uint32_t w3 = f2bf(b.z*sc*gb.z) | ((uint32_t)f2bf(b.w*sc*gb.w) << 16);
  ((uint4*)(out + (size_t)row * D_MODEL))[tid] = make_uint4(w0, w1, w2, w3);
}

// ============ 256x256 8-wave GEMM — faithful m201 8-phase template ============
// BK=64, 2 dbuf x (A[2 half][128][64] | B[2 half][128][64]) bf16 = 128 KiB.
// st_16x32 swizzle: phys = logical ^ (((logical>>9)&1)<<5), inverse-applied on
// the global source (rule 21). Per K-tile: 4 phases (Q00,Q01,Q11,Q10), reads
// 12/4/8/0 b128 with A/B register reuse, stage issues {R0+S0, S1, R2, -} of
// tile t+1, checkpoints vmcnt(6)/vmcnt(6)/-/vmcnt(4) (never drain mid-loop).
// EPI 0: bf16 out +bias; EPI 2: bf16 out; EPI 4: bf16 out, silu(aux)*acc.
template<int EPI>
__global__ __launch_bounds__(512, 2) void k_gemm8p(
    const u16* __restrict__ A, const u16* __restrict__ Bt,
    const float* __restrict__ bias, const u16* __restrict__ aux,
    void* __restrict__ Cout, int M, int N, int K,
    int lda, int ldb, int ldc)
{
  extern __shared__ __align__(16) char smem[];
  const int tid = threadIdx.x;
  const int lane = tid & 63, wid = tid >> 6;
  const int wr = wid >> 2, wc = wid & 3;        // 2M x 4N waves
  const int lrow = lane & 15, lhi = lane >> 4;

  // bijective XCD swizzle (m204), row-major over N
  int nwg = gridDim.x, wg = blockIdx.x;
  int qq = nwg >> 3, rr = nwg & 7;
  int xcd = wg & 7, sub = wg >> 3;
  int swz = (xcd < rr ? xcd*(qq+1) : rr*(qq+1) + (xcd-rr)*qq) + sub;
  int nbx = N >> 8;
  int m0 = (swz / nbx) << 8, n0 = (swz % nbx) << 8;

  const int nk = K >> 6;                         // BK = 64
  const int hA = wr, hB = wc >> 1;               // this wave's A/B halves
  const int gA = wc;                             // slice index among 4 sharers
  const int gB = (wr << 1) | (wc & 1);

  // stage A-half hA, region q (q=0: rows 0-63, q=1: rows 64-127); 2 loads/thread
  auto stA = [&](int d, int kk, int q){
    #pragma unroll
    for (int L = 0; L < 2; ++L){
      int p = q*8192 + gA*2048 + L*1024 + lane*16;   // physical byte in half
      int b = p ^ (((p >> 9) & 1) << 5);             // logical byte
      int row = b >> 7, o = b & 127;
      __builtin_amdgcn_global_load_lds(
        (const AS1 void*)(A + (size_t)(m0 + hA*128 + row)*lda + kk + (o >> 1)),
        (AS3 void*)(smem + d*65536 + hA*16384 + p), 16, 0, 0);
    }
  };
  // stage B-half hB, region s (s=0: rows {0-31}u{64-95}, s=1: {32-63}u{96-127})
  auto stB = [&](int d, int kk, int s){
    #pragma unroll
    for (int L = 0; L < 2; ++L){
      int p = s*4096 + (gB >> 1)*8192 + (gB & 1)*2048 + L*1024 + lane*16;
      int b = p ^ (((p >> 9) & 1) << 5);
      int row = b >> 7, o = b & 127;
      __builtin_amdgcn_global_load_lds(
        (const AS1 void*)(Bt + (size_t)(n0 + hB*128 + row)*ldb + kk + (o >> 1)),
        (AS3 void*)(smem + d*65536 + 32768 + hB*16384 + p), 16, 0, 0);
    }
  };
  auto rdA = [&](int d, int rloc, int ks)->bf16x8{
    int b = rloc*128 + ks*64 + lhi*16;
    int p = b ^ (((b >> 9) & 1) << 5);
    return *(const bf16x8*)(smem + d*65536 + hA*16384 + p);
  };
  auto rdB = [&](int d, int rloc, int ks)->bf16x8{
    int b = rloc*128 + ks*64 + lhi*16;
    int p = b ^ (((b >> 9) & 1) << 5);
    return *(const bf16x8*)(smem + d*65536 + 32768 + hB*16384 + p);
  };

  f32x4 acc[8][4] = {};

  // prologue: stage tile 0 in consumption order R0,S0,S1,R2; drain; barrier
  stA(0, 0, 0); stB(0, 0, 0); stB(0, 0, 1); stA(0, 0, 1);
  asm volatile("s_waitcnt vmcnt(0)" ::: "memory");
  __builtin_amdgcn_s_barrier();

  for (int t = 0; t < nk; ++t){
    int d = t & 1, dn = d ^ 1, kkn = (t + 1) << 6;
    bool pf = (t + 1 < nk);
    bf16x8 aR[8], bQ0[4], bQ1[4];

    // ---- phase 0: Q00  (reads A q0: 8, B S-own q0: 4) ----
    #pragma unroll
    for (int ii = 0; ii < 4; ++ii){
      aR[ii*2]   = rdA(d, ii*16 + lrow, 0);
      aR[ii*2+1] = rdA(d, ii*16 + lrow, 1);
    }
    #pragma unroll
    for (int j = 0; j < 2; ++j){
      bQ0[j*2]   = rdB(d, (wc&1)*64 + j*16 + lrow, 0);
      bQ0[j*2+1] = rdB(d, (wc&1)*64 + j*16 + lrow, 1);
    }
    if (pf){ stA(dn, kkn, 0); stB(dn, kkn, 0); }
    asm volatile("s_waitcnt lgkmcnt(0)" ::: "memory");
    __builtin_amdgcn_sched_barrier(0);
    __builtin_amdgcn_s_setprio(1);
    #pragma unroll
    for (int ii = 0; ii < 4; ++ii)
      #pragma unroll
      for (int j = 0; j < 2; ++j){
        acc[ii][j] = __builtin_amdgcn_mfma_f32_16x16x32_bf16(aR[ii*2],   bQ0[j*2],   acc[ii][j], 0, 0, 0);
        acc[ii][j] = __builtin_amdgcn_mfma_f32_16x16x32_bf16(aR[ii*2+1], bQ0[j*2+1], acc[ii][j], 0, 0, 0);
      }
    __builtin_amdgcn_s_setprio(0);
    if (pf) asm volatile("s_waitcnt vmcnt(6)" ::: "memory");   // S1(t) landed
    else    asm volatile("s_waitcnt vmcnt(2)" ::: "memory");
    __builtin_amdgcn_sched_barrier(0);
    __builtin_amdgcn_s_barrier();

    // ---- phase 1: Q01  (reads B S-own q1: 4; reuse aR) ----
    #pragma unroll
    for (int j = 0; j < 2; ++j){
      bQ1[j*2]   = rdB(d, (wc&1)*64 + 32 + j*16 + lrow, 0);
      bQ1[j*2+1] = rdB(d, (wc&1)*64 + 32 + j*16 + lrow, 1);
    }
    if (pf) stB(dn, kkn, 1);
    asm volatile("s_waitcnt lgkmcnt(0)" ::: "memory");
    __builtin_amdgcn_sched_barrier(0);
    __builtin_amdgcn_s_setprio(1);
    #pragma unroll
    for (int ii = 0; ii < 4; ++ii)
      #pragma unroll
      for (int j = 0; j < 2; ++j){
        acc[ii][2+j] = __builtin_amdgcn_mfma_f32_16x16x32_bf16(aR[ii*2],   bQ1[j*2],   acc[ii][2+j], 0, 0, 0);
        acc[ii][2+j] = __builtin_amdgcn_mfma_f32_16x16x32_bf16(aR[ii*2+1], bQ1[j*2+1], acc[ii][2+j], 0, 0, 0);
      }
    __builtin_amdgcn_s_setprio(0);
    if (pf) asm volatile("s_waitcnt vmcnt(6)" ::: "memory");   // R2(t) landed
    else    asm volatile("s_waitcnt vmcnt(0)" ::: "memory");
    __builtin_amdgcn_sched_barrier(0);
    __builtin_amdgcn_s_barrier();

    // ---- phase 2: Q11  (reads A q1: 8; reuse bQ1) ----
    #pragma unroll
    for (int ii = 0; ii < 4; ++ii){
      aR[ii*2]   = rdA(d, 64 + ii*16 + lrow, 0);
      aR[ii*2+1] = rdA(d, 64 + ii*16 + lrow, 1);
    }
    if (pf) stA(dn, kkn, 1);
    asm volatile("s_waitcnt lgkmcnt(0)" ::: "memory");
    __builtin_amdgcn_sched_barrier(0);
    __builtin_amdgcn_s_setprio(1);
    #pragma unroll
    for (int ii = 0; ii < 4; ++ii)
      #pragma unroll
      for (int j = 0; j < 2; ++j){
        acc[4+ii][2+j] = __builtin_amdgcn_mfma_f32_16x16x32_bf16(aR[ii*2],   bQ1[j*2],   acc[4+ii][2+j], 0, 0, 0);
        acc[4+ii][2+j] = __builtin_amdgcn_mfma_f32_16x16x32_bf16(aR[ii*2+1], bQ1[j*2+1], acc[4+ii][2+j], 0, 0, 0);
      }
    __builtin_amdgcn_s_setprio(0);
    __builtin_amdgcn_s_barrier();

    // ---- phase 3: Q10  (no reads; reuse aR + bQ0) ----
    __builtin_amdgcn_s_setprio(1);
    #pragma unroll
    for (int ii = 0; ii < 4; ++ii)
      #pragma unroll
      for (int j = 0; j < 2; ++j){
        acc[4+ii][j] = __builtin_amdgcn_mfma_f32_16x16x32_bf16(aR[ii*2],   bQ0[j*2],   acc[4+ii][j], 0, 0, 0);
        acc[4+ii][j] = __builtin_amdgcn_mfma_f32_16x16x32_bf16(aR[ii*2+1], bQ0[j*2+1], acc[4+ii][j], 0, 0, 0);
      }
    __builtin_amdgcn_s_setprio(0);
    if (pf) asm volatile("s_waitcnt vmcnt(4)" ::: "memory");   // R0,S0(t+1) landed
    __builtin_amdgcn_sched_barrier(0);
    __builtin_amdgcn_s_barrier();
  }

  #pragma unroll
  for (int i = 0; i < 8; ++i){
    #pragma unroll
    for (int j = 0; j < 4; ++j){
      int col = n0 + wc*64 + j*16 + lrow;
      float bv = 0.f;
      if constexpr (EPI == 0) bv = bias[col];
      #pragma unroll
      for (int q = 0; q < 4; ++q){
        int row = m0 + wr*128 + i*16 + lhi*4 + q;
        size_t idx = (size_t)row*ldc + col;
        float v = acc[i][j][q] + bv;
        if constexpr (EPI == 4){
          float a0v = bf2f(aux[idx]);
          v = a0v / (1.f + __expf(-a0v)) * v;
        }
        ((u16*)Cout)[idx] = f2bf(v);
      }
    }
  }
}

// ---- 128x128 GEMM (3-buffer counted vmcnt) — O-proj / W2 / fallback ----
template<int EPI>
__global__ __launch_bounds__(256) void k_gemm_bt(
    const u16* __restrict__ A, const u16* __restrict__ Bt,
    const float* __restrict__ bias, const float* __restrict__ res,
    const u16* __restrict__ aux,
    void* __restrict__ Cout, int M, int N, int K,
    int lda, int ldb, int ldc)
{
  __shared__ __align__(16) u16 As[3][128*32];
  __shared__ __align__(16) u16 Bs[3][128*32];
  int tid = threadIdx.x;

  int nwg = gridDim.x, wg = blockIdx.x;
  int qq = nwg >> 3, rr = nwg & 7;
  int xcd = wg & 7, sub = wg >> 3;
  int swz = (xcd < rr ? xcd*(qq+1) : rr*(qq+1) + (xcd-rr)*qq) + sub;
  int nbx = N >> 7;
  int m0 = (swz / nbx) << 7, n0 = (swz % nbx) << 7;

  int lane = tid & 63, wave = tid >> 6;
  int wr = wave >> 1, wc = wave & 1;
  int lrow = lane & 15, lhi = lane >> 4;
  f32x4 acc[4][4] = {};
  int srow = tid >> 2;
  int scol = (tid & 3) * 8;
  const int nk = K >> 5;

  auto stage = [&](int slot, int kt){
    int k0 = kt << 5;
    #pragma unroll
    for (int c = 0; c < 2; ++c){
      int r = c*64 + srow;
      __builtin_amdgcn_global_load_lds(
        (const AS1 void*)(A + (size_t)(m0 + r)*lda + k0 + scol),
        (AS3 void*)(&As[slot][r*32 + scol]), 16, 0, 0);
      __builtin_amdgcn_global_load_lds(
        (const AS1 void*)(Bt + (size_t)(n0 + r)*ldb + k0 + scol),
        (AS3 void*)(&Bs[slot][r*32 + scol]), 16, 0, 0);
    }
  };

  stage(0, 0);
  if (nk > 1) stage(1, 1);
  if (nk > 1) asm volatile("s_waitcnt vmcnt(4)" ::: "memory");
  else        asm volatile("s_waitcnt vmcnt(0)" ::: "memory");
  __builtin_amdgcn_s_barrier();

  for (int kt = 0; kt < nk; ++kt){
    int cur = kt % 3;
    if (kt + 2 < nk) stage((kt + 2) % 3, kt + 2);
    bf16x8 af[4], bfv[4];
    #pragma unroll
    for (int i = 0; i < 4; ++i){
      af[i]  = *(const bf16x8*)(&As[cur][(wr*64 + i*16 + lrow)*32 + lhi*8]);
      bfv[i] = *(const bf16x8*)(&Bs[cur][(wc*64 + i*16 + lrow)*32 + lhi*8]);
    }
    #pragma unroll
    for (int i = 0; i < 4; ++i)
      #pragma unroll
      for (int j = 0; j < 4; ++j)
        acc[i][j] = __builtin_amdgcn_mfma_f32_16x16x32_bf16(af[i], bfv[j], acc[i][j], 0, 0, 0);
    if (kt + 2 < nk) asm volatile("s_waitcnt vmcnt(4)" ::: "memory");
    else             asm volatile("s_waitcnt vmcnt(0)" ::: "memory");
    __builtin_amdgcn_s_barrier();
  }

  #pragma unroll
  for (int i = 0; i < 4; ++i){
    #pragma unroll
    for (int j = 0; j < 4; ++j){
      int col = n0 + wc*64 + j*16 + lrow;
      float bv = 0.f;
      if constexpr (EPI == 0 || EPI == 1) bv = bias[col];
      #pragma unroll
      for (int q = 0; q < 4; ++q){
        int row = m0 + wr*64 + i*16 + lhi*4 + q;
        size_t idx = (size_t)row*ldc + col;
        float v = acc[i][j][q] + bv;
        if constexpr (EPI == 1 || EPI == 3) v += res[idx];
        if constexpr (EPI == 4){
          float a0 = bf2f(aux[idx]);
          v = a0 / (1.f + __expf(-a0)) * v;
        }
        if constexpr (EPI == 0 || EPI == 2 || EPI == 4) ((u16*)Cout)[idx] = f2bf(v);
        else ((float*)Cout)[idx] = v;
      }
    }
  }
}

// ---- causal flash attention, 2-phase pipelined LDS staging (unchanged) ----
__global__ __launch_bounds__(256) void k_attn(
    const u16* __restrict__ Q, const u16* __restrict__ Kb,
    const u16* __restrict__ Vt, u16* __restrict__ O, int ldq)
{
  int tid = threadIdx.x, lane = tid & 63, wave = tid >> 6;
  int lrow = lane & 15, lhi = lane >> 4;
  int bh = blockIdx.y, b = bh >> 4, h = bh & 15;
  int qi = gridDim.x - 1 - blockIdx.x;
  int qs = qi * 64;
  int nt = qi + 1;
  int qrow = qs + wave * 16;

  __shared__ __align__(16) u16 Kbuf[2][64*128];
  __shared__ __align__(16) u16 Vbuf[2][128*64];
  __shared__ __align__(16) u16 P_lds[4][16*64];
  char* pw = (char*)&P_lds[wave][0];
  const float sc2 = 0.08838834764831845f * 1.44269504088896340736f;

  bf16x8 qf[4];
  const u16* qbase = Q + (size_t)(b*SS + qrow + lrow)*ldq + h*DK + lhi*8;
  #pragma unroll
  for (int dc = 0; dc < 4; ++dc) qf[dc] = *(const bf16x8*)(qbase + dc*32);

  auto stage = [&](int bufi, int kt){
    int kv0 = kt << 6;
    char* kd = (char*)&Kbuf[bufi][0];
    char* vd = (char*)&Vbuf[bufi][0];
    #pragma unroll
    for (int p = 0; p < 4; ++p){
      int r  = p*16 + wave*4 + (lane >> 4);
      int cg = (lane & 15) ^ (r & 7);
      __builtin_amdgcn_global_load_lds(
        (const AS1 void*)(Kb + (size_t)(b*SS + kv0 + r)*ldq + h*DK + cg*8),
        (AS3 void*)(kd + p*4096 + wave*1024 + lane*16), 16, 0, 0);
      int d  = p*32 + wave*8 + (lane >> 3);
      int cv = (lane & 7) ^ (d & 7);
      __builtin_amdgcn_global_load_lds(
        (const AS1 void*)(Vt + (size_t)bh*DK*SS + (size_t)d*SS + kv0 + cv*8),
        (AS3 void*)(vd + p*4096 + wave*1024 + lane*16), 16, 0, 0);
    }
  };

  f32x4 accO[8] = {};
  float mr[4] = {-1e30f,-1e30f,-1e30f,-1e30f};
  float lr[4] = {0.f,0.f,0.f,0.f};

  stage(0, 0);
  __syncthreads();

  for (int kt = 0; kt < nt; ++kt){
    int cur = kt & 1;
    if (kt + 1 < nt) stage(cur ^ 1, kt + 1);
    int kv0 = kt << 6;
    const char* kl = (const char*)&Kbuf[cur][0];
    const char* vl = (const char*)&Vbuf[cur][0];

    f32x4 sf[4];
    #pragma unroll
    for (int hf = 0; hf < 4; ++hf){
      int rl = hf*16 + lrow;
      int sw = rl & 7;
      f32x4 a = {};
      #pragma unroll
      for (int dc = 0; dc < 4; ++dc){
        bf16x8 kf = *(const bf16x8*)(kl + rl*256 + (((lhi + dc*4) ^ sw) << 4));
        a = __builtin_amdgcn_mfma_f32_16x16x32_bf16(qf[dc], kf, a, 0, 0, 0);
      }
      sf[hf] = a;
    }

    float p[4][4], mx[4];
    #pragma unroll
    for (int q = 0; q < 4; ++q){
      float s0 = sf[0][q]*sc2, s1 = sf[1][q]*sc2, s2 = sf[2][q]*sc2, s3 = sf[3][q]*sc2;
      if (kt == nt - 1){
        int qg = qrow + lhi*4 + q;
        if (kv0      + lrow > qg) s0 = -1e30f;
        if (kv0 + 16 + lrow > qg) s1 = -1e30f;
        if (kv0 + 32 + lrow > qg) s2 = -1e30f;
        if (kv0 + 48 + lrow > qg) s3 = -1e30f;
      }
      p[q][0]=s0; p[q][1]=s1; p[q][2]=s2; p[q][3]=s3;
      float m = fmaxf(fmaxf(s0,s1), fmaxf(s2,s3));
      m = fmaxf(m, __shfl_xor(m, 1, 64));
      m = fmaxf(m, __shfl_xor(m, 2, 64));
      m = fmaxf(m, __shfl_xor(m, 4, 64));
      m = fmaxf(m, __shfl_xor(m, 8, 64));
      mx[q] = m;
    }
    float dmax = fmaxf(fmaxf(mx[0]-mr[0], mx[1]-mr[1]), fmaxf(mx[2]-mr[2], mx[3]-mr[3]));
    bool rescale = !__all(dmax <= 8.0f);
    float al[4];
    #pragma unroll
    for (int q = 0; q < 4; ++q){
      if (rescale){
        float mn = fmaxf(mr[q], mx[q]);
        al[q] = fexp2(mr[q] - mn);
        mr[q] = mn;
      } else al[q] = 1.0f;
      p[q][0] = fexp2(p[q][0] - mr[q]);
      p[q][1] = fexp2(p[q][1] - mr[q]);
      p[q][2] = fexp2(p[q][2] - mr[q]);
      p[q][3] = fexp2(p[q][3] - mr[q]);
      float sm = (p[q][0] + p[q][1]) + (p[q][2] + p[q][3]);
      sm += __shfl_xor(sm, 1, 64);
      sm += __shfl_xor(sm, 2, 64);
      sm += __shfl_xor(sm, 4, 64);
      sm += __shfl_xor(sm, 8, 64);
      lr[q] = lr[q]*al[q] + sm;
    }
    if (rescale){
      #pragma unroll
      for (int f = 0; f < 8; ++f)
        #pragma unroll
        for (int q = 0; q < 4; ++q) accO[f][q] *= al[q];
    }

    #pragma unroll
    for (int q = 0; q < 4; ++q){
      int row = lhi*4 + q;
      int rb = row*128, sw = (row & 7) << 4;
      #pragma unroll
      for (int hf = 0; hf < 4; ++hf)
        *(u16*)(pw + rb + ((hf*32 + lrow*2) ^ sw)) = cvt_bf16(p[q][hf]);
    }
    __builtin_amdgcn_sched_barrier(0);
    int rsw = (lrow & 7) << 4;
    bf16x8 pa0 = *(const bf16x8*)(pw + lrow*128 + ((     lhi*16) ^ rsw));
    bf16x8 pa1 = *(const bf16x8*)(pw + lrow*128 + ((64 + lhi*16) ^ rsw));

    #pragma unroll
    for (int f = 0; f < 8; ++f){
      int d = f*16 + lrow;
      int swv = d & 7;
      bf16x8 v0 = *(const bf16x8*)(vl + d*128 + (((lhi    ) ^ swv) << 4));
      bf16x8 v1 = *(const bf16x8*)(vl + d*128 + (((lhi + 4) ^ swv) << 4));
      accO[f] = __builtin_amdgcn_mfma_f32_16x16x32_bf16(pa0, v0, accO[f], 0, 0, 0);
      accO[f] = __builtin_amdgcn_mfma_f32_16x16x32_bf16(pa1, v1, accO[f], 0, 0, 0);
    }

    __syncthreads();
  }

  #pragma unroll
  for (int q = 0; q < 4; ++q){
    float inv = 1.0f / lr[q];
    #pragma unroll
    for (int f = 0; f < 8; ++f){
      int row = b*SS + qrow + lhi*4 + q;
      int col = h*DK + f*16 + lrow;
      O[(size_t)row*D_MODEL + col] = cvt_bf16(accO[f][q] * inv);
    }
  }
}

extern "C" void kernel_launch(void* const* d_in, const int* in_sizes, int n_in,
                              void* d_out, int out_size, void* d_ws, size_t ws_size,
                              hipStream_t stream)
{
  (void)in_sizes; (void)n_in; (void)out_size;
  const float* x  = (const float*)d_in[0];
  const float* wq = (const float*)d_in[2];
  const float* bq = (const float*)d_in[3];
  const float* wk = (const float*)d_in[4];
  const float* bk = (const float*)d_in[5];
  const float* wv = (const float*)d_in[6];
  const float* bv = (const float*)d_in[7];
  const float* wo = (const float*)d_in[8];
  const float* bo = (const float*)d_in[9];
  const float* g1 = (const float*)d_in[10];
  const float* g2 = (const float*)d_in[11];
  const float* w1 = (const float*)d_in[12];
  const float* w3 = (const float*)d_in[13];  // w3 precedes w2 in dict order
  const float* w2 = (const float*)d_in[14];
  float* out = (float*)d_out;

  const size_t MB = 1u << 20;
  const size_t WFF2 = (size_t)D_MODEL * DFF * sizeof(u16);
  const size_t NEED = 112*MB + WFF2 + 32768;
  if (ws_size < NEED) return;
  char* ws = (char*)d_ws;
  u16* bufA = (u16*)(ws + 0);        // 16 MiB: nbf1 -> aob -> nbf2
  u16* qkv  = (u16*)(ws + 16*MB);    // 48 MiB fused QKV [4096][6144]
  u16* h1   = qkv;                   // [4096][5632], aliases qkv after attn
  u16* wqkvt= (u16*)(ws + 64*MB);    // 24 MiB: wq^T|wk^T|wv^T [6144][2048]
  u16* w1t  = wqkvt;                 // [5632][2048], aliases after QKV GEMM
  u16* wot  = (u16*)(ws + 88*MB);    // 8 MiB
  u16* w3t  = (u16*)(ws + 88*MB);    // [5632][2048], aliases wot+vtb after O-proj
  u16* vtb  = (u16*)(ws + 96*MB);    // 16 MiB
  u16* w2t  = (u16*)(ws + 112*MB);   // [2048][5504]
  float* bqkv = (float*)(ws + 112*MB + WFF2);
  // fp32 residual x1 lives in d_out

  bool big = true;
  big &= hipFuncSetAttribute((const void*)k_gemm8p<0>, hipFuncAttributeMaxDynamicSharedMemorySize, 131072) == hipSuccess;
  big &= hipFuncSetAttribute((const void*)k_gemm8p<2>, hipFuncAttributeMaxDynamicSharedMemorySize, 131072) == hipSuccess;
  big &= hipFuncSetAttribute((const void*)k_gemm8p<4>, hipFuncAttributeMaxDynamicSharedMemorySize, 131072) == hipSuccess;

  dim3 tb(32, 8);
  k_transpose_w<<<dim3(64,64), tb, 0, stream>>>(wq, wqkvt,               D_MODEL, D_MODEL);
  k_transpose_w<<<dim3(64,64), tb, 0, stream>>>(wk, wqkvt + 2048*2048,   D_MODEL, D_MODEL);
  k_transpose_w<<<dim3(64,64), tb, 0, stream>>>(wv, wqkvt + 2*2048*2048, D_MODEL, D_MODEL);
  k_transpose_w<<<dim3(64,64), tb, 0, stream>>>(wo, wot, D_MODEL, D_MODEL);
  k_transpose_w<<<dim3(64, DFF/32), tb, 0, stream>>>(w2, w2t, DFF, D_MODEL);
  k_concat3<<<24, 256, 0, stream>>>(bq, bk, bv, bqkv);

  k_rmsnorm<<<MTOK, 256, 0, stream>>>(x, g1, bufA);
  if (big)
    k_gemm8p<0><<<(MTOK/256)*(DQKV/256), 512, 131072, stream>>>(bufA, wqkvt, bqkv, nullptr, qkv, MTOK, DQKV, D_MODEL, D_MODEL, D_MODEL, DQKV);
  else
    k_gemm_bt<0><<<(DQKV/128)*(MTOK/128), 256, 0, stream>>>(bufA, wqkvt, bqkv, nullptr, nullptr, qkv, MTOK, DQKV, D_MODEL, D_MODEL, D_MODEL, DQKV);
  k_transpose_v<<<dim3(SS/32, 128), tb, 0, stream>>>(qkv + 4096, vtb, DQKV);
  k_attn<<<dim3(SS/64, BB*NHEADS), 256, 0, stream>>>(qkv, qkv + 2048, vtb, bufA, DQKV);
  k_transpose_w<<<dim3(DFFP/32, 64), tb, 0, stream>>>(w1, w1t, D_MODEL, DFF);
  k_gemm_bt<1><<<16*32, 256, 0, stream>>>(bufA, wot, bo, x, nullptr, out, MTOK, D_MODEL, D_MODEL, D_MODEL, D_MODEL, D_MODEL);
  k_transpose_w<<<dim3(DFFP/32, 64), tb, 0, stream>>>(w3, w3t, D_MODEL, DFF);
  k_rmsnorm<<<MTOK, 256, 0, stream>>>(out, g2, bufA);
  if (big){
    k_gemm8p<2><<<(MTOK/256)*(DFFP/256), 512, 131072, stream>>>(bufA, w1t, nullptr, nullptr, h1, MTOK, DFFP, D_MODEL, D_MODEL, D_MODEL, DFFP);
    k_gemm8p<4><<<(MTOK/256)*(DFFP/256), 512, 131072, stream>>>(bufA, w3t, nullptr, h1, h1, MTOK, DFFP, D_MODEL, D_MODEL, D_MODEL, DFFP);
  } else {
    k_gemm_bt<2><<<(DFFP/128)*32, 256, 0, stream>>>(bufA, w1t, nullptr, nullptr, nullptr, h1, MTOK, DFFP, D_MODEL, D_MODEL, D_MODEL, DFFP);
    k_gemm_bt<4><<<(DFFP/128)*32, 256, 0, stream>>>(bufA, w3t, nullptr, nullptr, h1, h1, MTOK, DFFP, D_MODEL, D_MODEL, D_MODEL, DFFP);
  }
  k_gemm_bt<3><<<16*32, 256, 0, stream>>>(h1, w2t, nullptr, out, nullptr, out, MTOK, D_MODEL, DFF, DFFP, DFF, D_MODEL);
}

// Round 8
// 834.521 us; speedup vs baseline: 1.0346x; 1.0083x over previous
//
#include <hip/hip_runtime.h>
#include <stdint.h>

typedef unsigned short u16;
typedef __bf16 bf16x8 __attribute__((ext_vector_type(8)));
typedef float f32x4 __attribute__((ext_vector_type(4)));

#define D_MODEL 2048
#define NHEADS 16
#define DK 128
#define DFF 5504
#define DFFP 5632   // DFF padded to 256 multiple
#define BB 2
#define SS 2048
#define MTOK 4096
#define DQKV 6144

#define AS1 __attribute__((address_space(1)))
#define AS3 __attribute__((address_space(3)))

__device__ __forceinline__ u16 f2bf(float f){
  union { float f; uint32_t u; } v; v.f = f;
  uint32_t r = v.u + 0x7fffu + ((v.u >> 16) & 1u);
  return (u16)(r >> 16);
}
__device__ __forceinline__ float bf2f(u16 u){
  union { uint32_t u; float f; } v; v.u = ((uint32_t)u) << 16;
  return v.f;
}
__device__ __forceinline__ u16 cvt_bf16(float f){
  union { __bf16 h; u16 u; } v; v.h = (__bf16)f; return v.u;
}
__device__ __forceinline__ float fexp2(float x){
#if __has_builtin(__builtin_amdgcn_exp2f)
  return __builtin_amdgcn_exp2f(x);
#else
  return exp2f(x);
#endif
}

// ---- fp32 W[K][Nsrc] -> bf16 Wt[n][K], zero-fill n >= Nsrc ----
__global__ __launch_bounds__(256) void k_transpose_w(const float* __restrict__ W,
                                                     u16* __restrict__ Wt, int K, int Nsrc){
  __shared__ float tile[32][33];
  int n0 = blockIdx.x * 32, k0 = blockIdx.y * 32;
  int tx = threadIdx.x, ty = threadIdx.y;  // (32,8)
  #pragma unroll
  for (int r = 0; r < 4; ++r){
    int n = n0 + tx;
    tile[ty + r*8][tx] = (n < Nsrc) ? W[(size_t)(k0 + ty + r*8) * Nsrc + n] : 0.0f;
  }
  __syncthreads();
  #pragma unroll
  for (int r = 0; r < 4; ++r)
    Wt[(size_t)(n0 + ty + r*8) * K + k0 + tx] = f2bf(tile[tx][ty + r*8]);
}

// ---- per-head V transpose from fused QKV ----
__global__ __launch_bounds__(256) void k_transpose_v(const u16* __restrict__ V,
                                                     u16* __restrict__ Vt, int ld){
  __shared__ u16 tile[32][33];
  int s0 = blockIdx.x * 32;
  int bh = blockIdx.y >> 2, dt = blockIdx.y & 3;
  int b = bh >> 4, h = bh & 15;
  int tx = threadIdx.x, ty = threadIdx.y;
  #pragma unroll
  for (int r = 0; r < 4; ++r)
    tile[ty + r*8][tx] = V[(size_t)(b*SS + s0 + ty + r*8) * ld + h*DK + dt*32 + tx];
  __syncthreads();
  #pragma unroll
  for (int r = 0; r < 4; ++r)
    Vt[(size_t)(bh*DK + dt*32 + ty + r*8) * SS + s0 + tx] = tile[tx][ty + r*8];
}

__global__ __launch_bounds__(256) void k_concat3(const float* __restrict__ a,
                                                 const float* __restrict__ b,
                                                 const float* __restrict__ c,
                                                 float* __restrict__ o){
  int i = blockIdx.x*256 + threadIdx.x;
  if (i >= DQKV) return;
  o[i] = (i < 2048) ? a[i] : (i < 4096 ? b[i-2048] : c[i-4096]);
}

// ---- RMSNorm: fp32 row -> bf16 row ----
__global__ __launch_bounds__(256) void k_rmsnorm(const float* __restrict__ X,
                                                 const float* __restrict__ g,
                                                 u16* __restrict__ out){
  int row = blockIdx.x, tid = threadIdx.x;
  const float* x = X + (size_t)row * D_MODEL;
  float4 a = ((const float4*)x)[tid*2];
  float4 b = ((const float4*)x)[tid*2+1];
  float ss = a.x*a.x + a.y*a.y + a.z*a.z + a.w*a.w
           + b.x*b.x + b.y*b.y + b.z*b.z + b.w*b.w;
  #pragma unroll
  for (int m = 1; m < 64; m <<= 1) ss += __shfl_xor(ss, m, 64);
  __shared__ float red[4];
  if ((tid & 63) == 0) red[tid >> 6] = ss;
  __syncthreads();
  float tot = red[0] + red[1] + red[2] + red[3];
  float sc = rsqrtf(tot * (1.0f / D_MODEL) + 1e-6f);
  float4 ga = ((const float4*)g)[tid*2];
  float4 gb = ((const float4*)g)[tid*2+1];
  uint32_t w0 = f2bf(a.x*sc*ga.x) | ((uint32_t)f2bf(a.y*sc*ga.y) << 16);
  uint32_t w1 = f2bf(a.z*sc*ga.z) | ((uint32_t)f2bf(a.w*sc*ga.w) << 16);
  uint32_t w2 = f2bf(b.x*sc*gb.x) | ((uint32_t)f2bf(b.y*sc*gb.y) << 16);
  uint32_t w3 = f2bf(b.z*sc*gb.z) | ((uint32_t)f2bf(b.w*sc*gb.w) << 16);
  ((uint4*)(out + (size_t)row * D_MODEL))[tid] = make_uint4(w0, w1, w2, w3);
}

// ============ 256x256 8-wave GEMM — faithful m201 8-phase template ============
template<int EPI>
__global__ __launch_bounds__(512, 2) void k_gemm8p(
    const u16* __restrict__ A, const u16* __restrict__ Bt,
    const float* __restrict__ bias, const u16* __restrict__ aux,
    void* __restrict__ Cout, int M, int N, int K,
    int lda, int ldb, int ldc)
{
  extern __shared__ __align__(16) char smem[];
  const int tid = threadIdx.x;
  const int lane = tid & 63, wid = tid >> 6;
  const int wr = wid >> 2, wc = wid & 3;        // 2M x 4N waves
  const int lrow = lane & 15, lhi = lane >> 4;

  int nwg = gridDim.x, wg = blockIdx.x;
  int qq = nwg >> 3, rr = nwg & 7;
  int xcd = wg & 7, sub = wg >> 3;
  int swz = (xcd < rr ? xcd*(qq+1) : rr*(qq+1) + (xcd-rr)*qq) + sub;
  int nbx = N >> 8;
  int m0 = (swz / nbx) << 8, n0 = (swz % nbx) << 8;

  const int nk = K >> 6;                         // BK = 64
  const int hA = wr, hB = wc >> 1;
  const int gA = wc;
  const int gB = (wr << 1) | (wc & 1);

  auto stA = [&](int d, int kk, int q){
    #pragma unroll
    for (int L = 0; L < 2; ++L){
      int p = q*8192 + gA*2048 + L*1024 + lane*16;
      int b = p ^ (((p >> 9) & 1) << 5);
      int row = b >> 7, o = b & 127;
      __builtin_amdgcn_global_load_lds(
        (const AS1 void*)(A + (size_t)(m0 + hA*128 + row)*lda + kk + (o >> 1)),
        (AS3 void*)(smem + d*65536 + hA*16384 + p), 16, 0, 0);
    }
  };
  auto stB = [&](int d, int kk, int s){
    #pragma unroll
    for (int L = 0; L < 2; ++L){
      int p = s*4096 + (gB >> 1)*8192 + (gB & 1)*2048 + L*1024 + lane*16;
      int b = p ^ (((p >> 9) & 1) << 5);
      int row = b >> 7, o = b & 127;
      __builtin_amdgcn_global_load_lds(
        (const AS1 void*)(Bt + (size_t)(n0 + hB*128 + row)*ldb + kk + (o >> 1)),
        (AS3 void*)(smem + d*65536 + 32768 + hB*16384 + p), 16, 0, 0);
    }
  };
  auto rdA = [&](int d, int rloc, int ks)->bf16x8{
    int b = rloc*128 + ks*64 + lhi*16;
    int p = b ^ (((b >> 9) & 1) << 5);
    return *(const bf16x8*)(smem + d*65536 + hA*16384 + p);
  };
  auto rdB = [&](int d, int rloc, int ks)->bf16x8{
    int b = rloc*128 + ks*64 + lhi*16;
    int p = b ^ (((b >> 9) & 1) << 5);
    return *(const bf16x8*)(smem + d*65536 + 32768 + hB*16384 + p);
  };

  f32x4 acc[8][4] = {};

  stA(0, 0, 0); stB(0, 0, 0); stB(0, 0, 1); stA(0, 0, 1);
  asm volatile("s_waitcnt vmcnt(0)" ::: "memory");
  __builtin_amdgcn_s_barrier();

  for (int t = 0; t < nk; ++t){
    int d = t & 1, dn = d ^ 1, kkn = (t + 1) << 6;
    bool pf = (t + 1 < nk);
    bf16x8 aR[8], bQ0[4], bQ1[4];

    // ---- phase 0: Q00 ----
    #pragma unroll
    for (int ii = 0; ii < 4; ++ii){
      aR[ii*2]   = rdA(d, ii*16 + lrow, 0);
      aR[ii*2+1] = rdA(d, ii*16 + lrow, 1);
    }
    #pragma unroll
    for (int j = 0; j < 2; ++j){
      bQ0[j*2]   = rdB(d, (wc&1)*64 + j*16 + lrow, 0);
      bQ0[j*2+1] = rdB(d, (wc&1)*64 + j*16 + lrow, 1);
    }
    if (pf){ stA(dn, kkn, 0); stB(dn, kkn, 0); }
    asm volatile("s_waitcnt lgkmcnt(0)" ::: "memory");
    __builtin_amdgcn_sched_barrier(0);
    __builtin_amdgcn_s_setprio(1);
    #pragma unroll
    for (int ii = 0; ii < 4; ++ii)
      #pragma unroll
      for (int j = 0; j < 2; ++j){
        acc[ii][j] = __builtin_amdgcn_mfma_f32_16x16x32_bf16(aR[ii*2],   bQ0[j*2],   acc[ii][j], 0, 0, 0);
        acc[ii][j] = __builtin_amdgcn_mfma_f32_16x16x32_bf16(aR[ii*2+1], bQ0[j*2+1], acc[ii][j], 0, 0, 0);
      }
    __builtin_amdgcn_s_setprio(0);
    if (pf) asm volatile("s_waitcnt vmcnt(6)" ::: "memory");
    else    asm volatile("s_waitcnt vmcnt(2)" ::: "memory");
    __builtin_amdgcn_sched_barrier(0);
    __builtin_amdgcn_s_barrier();

    // ---- phase 1: Q01 ----
    #pragma unroll
    for (int j = 0; j < 2; ++j){
      bQ1[j*2]   = rdB(d, (wc&1)*64 + 32 + j*16 + lrow, 0);
      bQ1[j*2+1] = rdB(d, (wc&1)*64 + 32 + j*16 + lrow, 1);
    }
    if (pf) stB(dn, kkn, 1);
    asm volatile("s_waitcnt lgkmcnt(0)" ::: "memory");
    __builtin_amdgcn_sched_barrier(0);
    __builtin_amdgcn_s_setprio(1);
    #pragma unroll
    for (int ii = 0; ii < 4; ++ii)
      #pragma unroll
      for (int j = 0; j < 2; ++j){
        acc[ii][2+j] = __builtin_amdgcn_mfma_f32_16x16x32_bf16(aR[ii*2],   bQ1[j*2],   acc[ii][2+j], 0, 0, 0);
        acc[ii][2+j] = __builtin_amdgcn_mfma_f32_16x16x32_bf16(aR[ii*2+1], bQ1[j*2+1], acc[ii][2+j], 0, 0, 0);
      }
    __builtin_amdgcn_s_setprio(0);
    if (pf) asm volatile("s_waitcnt vmcnt(6)" ::: "memory");
    else    asm volatile("s_waitcnt vmcnt(0)" ::: "memory");
    __builtin_amdgcn_sched_barrier(0);
    __builtin_amdgcn_s_barrier();

    // ---- phase 2: Q11 ----
    #pragma unroll
    for (int ii = 0; ii < 4; ++ii){
      aR[ii*2]   = rdA(d, 64 + ii*16 + lrow, 0);
      aR[ii*2+1] = rdA(d, 64 + ii*16 + lrow, 1);
    }
    if (pf) stA(dn, kkn, 1);
    asm volatile("s_waitcnt lgkmcnt(0)" ::: "memory");
    __builtin_amdgcn_sched_barrier(0);
    __builtin_amdgcn_s_setprio(1);
    #pragma unroll
    for (int ii = 0; ii < 4; ++ii)
      #pragma unroll
      for (int j = 0; j < 2; ++j){
        acc[4+ii][2+j] = __builtin_amdgcn_mfma_f32_16x16x32_bf16(aR[ii*2],   bQ1[j*2],   acc[4+ii][2+j], 0, 0, 0);
        acc[4+ii][2+j] = __builtin_amdgcn_mfma_f32_16x16x32_bf16(aR[ii*2+1], bQ1[j*2+1], acc[4+ii][2+j], 0, 0, 0);
      }
    __builtin_amdgcn_s_setprio(0);
    __builtin_amdgcn_s_barrier();

    // ---- phase 3: Q10 ----
    __builtin_amdgcn_s_setprio(1);
    #pragma unroll
    for (int ii = 0; ii < 4; ++ii)
      #pragma unroll
      for (int j = 0; j < 2; ++j){
        acc[4+ii][j] = __builtin_amdgcn_mfma_f32_16x16x32_bf16(aR[ii*2],   bQ0[j*2],   acc[4+ii][j], 0, 0, 0);
        acc[4+ii][j] = __builtin_amdgcn_mfma_f32_16x16x32_bf16(aR[ii*2+1], bQ0[j*2+1], acc[4+ii][j], 0, 0, 0);
      }
    __builtin_amdgcn_s_setprio(0);
    if (pf) asm volatile("s_waitcnt vmcnt(4)" ::: "memory");
    __builtin_amdgcn_sched_barrier(0);
    __builtin_amdgcn_s_barrier();
  }

  #pragma unroll
  for (int i = 0; i < 8; ++i){
    #pragma unroll
    for (int j = 0; j < 4; ++j){
      int col = n0 + wc*64 + j*16 + lrow;
      float bv = 0.f;
      if constexpr (EPI == 0) bv = bias[col];
      #pragma unroll
      for (int q = 0; q < 4; ++q){
        int row = m0 + wr*128 + i*16 + lhi*4 + q;
        size_t idx = (size_t)row*ldc + col;
        float v = acc[i][j][q] + bv;
        if constexpr (EPI == 4){
          float a0v = bf2f(aux[idx]);
          v = a0v / (1.f + __expf(-a0v)) * v;
        }
        ((u16*)Cout)[idx] = f2bf(v);
      }
    }
  }
}

// ---- 128x128 GEMM (3-buffer counted vmcnt) — O-proj / W2 / fallback ----
template<int EPI>
__global__ __launch_bounds__(256) void k_gemm_bt(
    const u16* __restrict__ A, const u16* __restrict__ Bt,
    const float* __restrict__ bias, const float* __restrict__ res,
    const u16* __restrict__ aux,
    void* __restrict__ Cout, int M, int N, int K,
    int lda, int ldb, int ldc)
{
  __shared__ __align__(16) u16 As[3][128*32];
  __shared__ __align__(16) u16 Bs[3][128*32];
  int tid = threadIdx.x;

  int nwg = gridDim.x, wg = blockIdx.x;
  int qq = nwg >> 3, rr = nwg & 7;
  int xcd = wg & 7, sub = wg >> 3;
  int swz = (xcd < rr ? xcd*(qq+1) : rr*(qq+1) + (xcd-rr)*qq) + sub;
  int nbx = N >> 7;
  int m0 = (swz / nbx) << 7, n0 = (swz % nbx) << 7;

  int lane = tid & 63, wave = tid >> 6;
  int wr = wave >> 1, wc = wave & 1;
  int lrow = lane & 15, lhi = lane >> 4;
  f32x4 acc[4][4] = {};
  int srow = tid >> 2;
  int scol = (tid & 3) * 8;
  const int nk = K >> 5;

  auto stage = [&](int slot, int kt){
    int k0 = kt << 5;
    #pragma unroll
    for (int c = 0; c < 2; ++c){
      int r = c*64 + srow;
      __builtin_amdgcn_global_load_lds(
        (const AS1 void*)(A + (size_t)(m0 + r)*lda + k0 + scol),
        (AS3 void*)(&As[slot][r*32 + scol]), 16, 0, 0);
      __builtin_amdgcn_global_load_lds(
        (const AS1 void*)(Bt + (size_t)(n0 + r)*ldb + k0 + scol),
        (AS3 void*)(&Bs[slot][r*32 + scol]), 16, 0, 0);
    }
  };

  stage(0, 0);
  if (nk > 1) stage(1, 1);
  if (nk > 1) asm volatile("s_waitcnt vmcnt(4)" ::: "memory");
  else        asm volatile("s_waitcnt vmcnt(0)" ::: "memory");
  __builtin_amdgcn_s_barrier();

  for (int kt = 0; kt < nk; ++kt){
    int cur = kt % 3;
    if (kt + 2 < nk) stage((kt + 2) % 3, kt + 2);
    bf16x8 af[4], bfv[4];
    #pragma unroll
    for (int i = 0; i < 4; ++i){
      af[i]  = *(const bf16x8*)(&As[cur][(wr*64 + i*16 + lrow)*32 + lhi*8]);
      bfv[i] = *(const bf16x8*)(&Bs[cur][(wc*64 + i*16 + lrow)*32 + lhi*8]);
    }
    #pragma unroll
    for (int i = 0; i < 4; ++i)
      #pragma unroll
      for (int j = 0; j < 4; ++j)
        acc[i][j] = __builtin_amdgcn_mfma_f32_16x16x32_bf16(af[i], bfv[j], acc[i][j], 0, 0, 0);
    if (kt + 2 < nk) asm volatile("s_waitcnt vmcnt(4)" ::: "memory");
    else             asm volatile("s_waitcnt vmcnt(0)" ::: "memory");
    __builtin_amdgcn_s_barrier();
  }

  #pragma unroll
  for (int i = 0; i < 4; ++i){
    #pragma unroll
    for (int j = 0; j < 4; ++j){
      int col = n0 + wc*64 + j*16 + lrow;
      float bv = 0.f;
      if constexpr (EPI == 0 || EPI == 1) bv = bias[col];
      #pragma unroll
      for (int q = 0; q < 4; ++q){
        int row = m0 + wr*64 + i*16 + lhi*4 + q;
        size_t idx = (size_t)row*ldc + col;
        float v = acc[i][j][q] + bv;
        if constexpr (EPI == 1 || EPI == 3) v += res[idx];
        if constexpr (EPI == 4){
          float a0 = bf2f(aux[idx]);
          v = a0 / (1.f + __expf(-a0)) * v;
        }
        if constexpr (EPI == 0 || EPI == 2 || EPI == 4) ((u16*)Cout)[idx] = f2bf(v);
        else ((float*)Cout)[idx] = v;
      }
    }
  }
}

// ---- causal flash attention: 128 q-rows/block, 8 waves x 16 rows, KVBLK=64 ----
// Double-buffered cooperative K/V staging (global_load_lds, both-sides XOR
// swizzle); per-wave active/mask gating for causality; 80 KB LDS -> 2 blk/CU.
__global__ __launch_bounds__(512) void k_attn(
    const u16* __restrict__ Q, const u16* __restrict__ Kb,
    const u16* __restrict__ Vt, u16* __restrict__ O, int ldq)
{
  int tid = threadIdx.x, lane = tid & 63, wave = tid >> 6;  // 8 waves
  int lrow = lane & 15, lhi = lane >> 4;
  int bh = blockIdx.y, b = bh >> 4, h = bh & 15;
  int qi = gridDim.x - 1 - blockIdx.x;   // longest blocks dispatched first
  int qs = qi * 128;
  int nt = 2*qi + 2;
  int qrow = qs + wave * 16;

  __shared__ __align__(16) u16 Kbuf[2][64*128];   // 32 KB
  __shared__ __align__(16) u16 Vbuf[2][128*64];   // 32 KB
  __shared__ __align__(16) u16 P_lds[8][16*64];   // 16 KB
  char* pw = (char*)&P_lds[wave][0];
  const float sc2 = 0.08838834764831845f * 1.44269504088896340736f;

  bf16x8 qf[4];
  const u16* qbase = Q + (size_t)(b*SS + qrow + lrow)*ldq + h*DK + lhi*8;
  #pragma unroll
  for (int dc = 0; dc < 4; ++dc) qf[dc] = *(const bf16x8*)(qbase + dc*32);

  // cooperative stage: 512 threads, 2 K-chunks + 2 V-chunks each.
  // dest = wave-uniform base + lane*16 (gload_lds constraint).
  auto stage = [&](int bufi, int kt){
    int kv0 = kt << 6;
    char* kd = (char*)&Kbuf[bufi][0];
    char* vd = (char*)&Vbuf[bufi][0];
    #pragma unroll
    for (int L = 0; L < 2; ++L){
      int cid = wave*128 + L*64 + lane;        // 0..1023
      int r = cid >> 4, c = cid & 15;          // K: row 0..63, chunk 0..15
      int cg = c ^ (r & 7);
      __builtin_amdgcn_global_load_lds(
        (const AS1 void*)(Kb + (size_t)(b*SS + kv0 + r)*ldq + h*DK + cg*8),
        (AS3 void*)(kd + wave*2048 + L*1024 + lane*16), 16, 0, 0);
      int dd = cid >> 3, c8 = cid & 7;         // V: row 0..127, chunk 0..7
      int cv = c8 ^ (dd & 7);
      __builtin_amdgcn_global_load_lds(
        (const AS1 void*)(Vt + (size_t)bh*DK*SS + (size_t)dd*SS + kv0 + cv*8),
        (AS3 void*)(vd + wave*2048 + L*1024 + lane*16), 16, 0, 0);
    }
  };

  f32x4 accO[8] = {};
  float mr[4] = {-1e30f,-1e30f,-1e30f,-1e30f};
  float lr[4] = {0.f,0.f,0.f,0.f};

  stage(0, 0);
  __syncthreads();

  for (int kt = 0; kt < nt; ++kt){
    int cur = kt & 1;
    if (kt + 1 < nt) stage(cur ^ 1, kt + 1);
    int kv0 = kt << 6;
    if (kv0 <= qrow + 15){   // wave-uniform: tile contributes to this wave's rows
      const char* kl = (const char*)&Kbuf[cur][0];
      const char* vl = (const char*)&Vbuf[cur][0];
      bool domask = (kv0 + 63 > qrow);

      f32x4 sf[4];
      #pragma unroll
      for (int hf = 0; hf < 4; ++hf){
        int rl = hf*16 + lrow;
        int sw = rl & 7;
        f32x4 a = {};
        #pragma unroll
        for (int dc = 0; dc < 4; ++dc){
          bf16x8 kf = *(const bf16x8*)(kl + rl*256 + (((lhi + dc*4) ^ sw) << 4));
          a = __builtin_amdgcn_mfma_f32_16x16x32_bf16(qf[dc], kf, a, 0, 0, 0);
        }
        sf[hf] = a;
      }

      float p[4][4], mx[4];
      #pragma unroll
      for (int q = 0; q < 4; ++q){
        float s0 = sf[0][q]*sc2, s1 = sf[1][q]*sc2, s2 = sf[2][q]*sc2, s3 = sf[3][q]*sc2;
        if (domask){
          int qg = qrow + lhi*4 + q;
          if (kv0      + lrow > qg) s0 = -1e30f;
          if (kv0 + 16 + lrow > qg) s1 = -1e30f;
          if (kv0 + 32 + lrow > qg) s2 = -1e30f;
          if (kv0 + 48 + lrow > qg) s3 = -1e30f;
        }
        p[q][0]=s0; p[q][1]=s1; p[q][2]=s2; p[q][3]=s3;
        float m = fmaxf(fmaxf(s0,s1), fmaxf(s2,s3));
        m = fmaxf(m, __shfl_xor(m, 1, 64));
        m = fmaxf(m, __shfl_xor(m, 2, 64));
        m = fmaxf(m, __shfl_xor(m, 4, 64));
        m = fmaxf(m, __shfl_xor(m, 8, 64));
        mx[q] = m;
      }
      float dmax = fmaxf(fmaxf(mx[0]-mr[0], mx[1]-mr[1]), fmaxf(mx[2]-mr[2], mx[3]-mr[3]));
      bool rescale = !__all(dmax <= 8.0f);
      float al[4];
      #pragma unroll
      for (int q = 0; q < 4; ++q){
        if (rescale){
          float mn = fmaxf(mr[q], mx[q]);
          al[q] = fexp2(mr[q] - mn);
          mr[q] = mn;
        } else al[q] = 1.0f;
        p[q][0] = fexp2(p[q][0] - mr[q]);
        p[q][1] = fexp2(p[q][1] - mr[q]);
        p[q][2] = fexp2(p[q][2] - mr[q]);
        p[q][3] = fexp2(p[q][3] - mr[q]);
        float sm = (p[q][0] + p[q][1]) + (p[q][2] + p[q][3]);
        sm += __shfl_xor(sm, 1, 64);
        sm += __shfl_xor(sm, 2, 64);
        sm += __shfl_xor(sm, 4, 64);
        sm += __shfl_xor(sm, 8, 64);
        lr[q] = lr[q]*al[q] + sm;
      }
      if (rescale){
        #pragma unroll
        for (int f = 0; f < 8; ++f)
          #pragma unroll
          for (int q = 0; q < 4; ++q) accO[f][q] *= al[q];
      }

      #pragma unroll
      for (int q = 0; q < 4; ++q){
        int row = lhi*4 + q;
        int rb = row*128, sw = (row & 7) << 4;
        #pragma unroll
        for (int hf = 0; hf < 4; ++hf)
          *(u16*)(pw + rb + ((hf*32 + lrow*2) ^ sw)) = cvt_bf16(p[q][hf]);
      }
      __builtin_amdgcn_sched_barrier(0);
      int rsw = (lrow & 7) << 4;
      bf16x8 pa0 = *(const bf16x8*)(pw + lrow*128 + ((     lhi*16) ^ rsw));
      bf16x8 pa1 = *(const bf16x8*)(pw + lrow*128 + ((64 + lhi*16) ^ rsw));

      #pragma unroll
      for (int f = 0; f < 8; ++f){
        int d = f*16 + lrow;
        int swv = d & 7;
        bf16x8 v0 = *(const bf16x8*)(vl + d*128 + (((lhi    ) ^ swv) << 4));
        bf16x8 v1 = *(const bf16x8*)(vl + d*128 + (((lhi + 4) ^ swv) << 4));
        accO[f] = __builtin_amdgcn_mfma_f32_16x16x32_bf16(pa0, v0, accO[f], 0, 0, 0);
        accO[f] = __builtin_amdgcn_mfma_f32_16x16x32_bf16(pa1, v1, accO[f], 0, 0, 0);
      }
    }
    __syncthreads();
  }

  #pragma unroll
  for (int q = 0; q < 4; ++q){
    float inv = 1.0f / lr[q];
    #pragma unroll
    for (int f = 0; f < 8; ++f){
      int row = b*SS + qrow + lhi*4 + q;
      int col = h*DK + f*16 + lrow;
      O[(size_t)row*D_MODEL + col] = cvt_bf16(accO[f][q] * inv);
    }
  }
}

extern "C" void kernel_launch(void* const* d_in, const int* in_sizes, int n_in,
                              void* d_out, int out_size, void* d_ws, size_t ws_size,
                              hipStream_t stream)
{
  (void)in_sizes; (void)n_in; (void)out_size;
  const float* x  = (const float*)d_in[0];
  const float* wq = (const float*)d_in[2];
  const float* bq = (const float*)d_in[3];
  const float* wk = (const float*)d_in[4];
  const float* bk = (const float*)d_in[5];
  const float* wv = (const float*)d_in[6];
  const float* bv = (const float*)d_in[7];
  const float* wo = (const float*)d_in[8];
  const float* bo = (const float*)d_in[9];
  const float* g1 = (const float*)d_in[10];
  const float* g2 = (const float*)d_in[11];
  const float* w1 = (const float*)d_in[12];
  const float* w3 = (const float*)d_in[13];  // w3 precedes w2 in dict order
  const float* w2 = (const float*)d_in[14];
  float* out = (float*)d_out;

  const size_t MB = 1u << 20;
  const size_t WFF2 = (size_t)D_MODEL * DFF * sizeof(u16);
  const size_t NEED = 112*MB + WFF2 + 32768;
  if (ws_size < NEED) return;
  char* ws = (char*)d_ws;
  u16* bufA = (u16*)(ws + 0);        // 16 MiB: nbf1 -> aob -> nbf2
  u16* qkv  = (u16*)(ws + 16*MB);    // 48 MiB fused QKV [4096][6144]
  u16* h1   = qkv;                   // [4096][5632], aliases qkv after attn
  u16* wqkvt= (u16*)(ws + 64*MB);    // 24 MiB: wq^T|wk^T|wv^T [6144][2048]
  u16* w1t  = wqkvt;                 // [5632][2048], aliases after QKV GEMM
  u16* wot  = (u16*)(ws + 88*MB);    // 8 MiB
  u16* w3t  = (u16*)(ws + 88*MB);    // [5632][2048], aliases wot+vtb after O-proj
  u16* vtb  = (u16*)(ws + 96*MB);    // 16 MiB
  u16* w2t  = (u16*)(ws + 112*MB);   // [2048][5504]
  float* bqkv = (float*)(ws + 112*MB + WFF2);
  // fp32 residual x1 lives in d_out

  bool big = true;
  big &= hipFuncSetAttribute((const void*)k_gemm8p<0>, hipFuncAttributeMaxDynamicSharedMemorySize, 131072) == hipSuccess;
  big &= hipFuncSetAttribute((const void*)k_gemm8p<2>, hipFuncAttributeMaxDynamicSharedMemorySize, 131072) == hipSuccess;
  big &= hipFuncSetAttribute((const void*)k_gemm8p<4>, hipFuncAttributeMaxDynamicSharedMemorySize, 131072) == hipSuccess;

  dim3 tb(32, 8);
  k_transpose_w<<<dim3(64,64), tb, 0, stream>>>(wq, wqkvt,               D_MODEL, D_MODEL);
  k_transpose_w<<<dim3(64,64), tb, 0, stream>>>(wk, wqkvt + 2048*2048,   D_MODEL, D_MODEL);
  k_transpose_w<<<dim3(64,64), tb, 0, stream>>>(wv, wqkvt + 2*2048*2048, D_MODEL, D_MODEL);
  k_transpose_w<<<dim3(64,64), tb, 0, stream>>>(wo, wot, D_MODEL, D_MODEL);
  k_transpose_w<<<dim3(64, DFF/32), tb, 0, stream>>>(w2, w2t, DFF, D_MODEL);
  k_concat3<<<24, 256, 0, stream>>>(bq, bk, bv, bqkv);

  k_rmsnorm<<<MTOK, 256, 0, stream>>>(x, g1, bufA);
  if (big)
    k_gemm8p<0><<<(MTOK/256)*(DQKV/256), 512, 131072, stream>>>(bufA, wqkvt, bqkv, nullptr, qkv, MTOK, DQKV, D_MODEL, D_MODEL, D_MODEL, DQKV);
  else
    k_gemm_bt<0><<<(DQKV/128)*(MTOK/128), 256, 0, stream>>>(bufA, wqkvt, bqkv, nullptr, nullptr, qkv, MTOK, DQKV, D_MODEL, D_MODEL, D_MODEL, DQKV);
  k_transpose_v<<<dim3(SS/32, 128), tb, 0, stream>>>(qkv + 4096, vtb, DQKV);
  k_attn<<<dim3(SS/128, BB*NHEADS), 512, 0, stream>>>(qkv, qkv + 2048, vtb, bufA, DQKV);
  k_transpose_w<<<dim3(DFFP/32, 64), tb, 0, stream>>>(w1, w1t, D_MODEL, DFF);
  k_gemm_bt<1><<<16*32, 256, 0, stream>>>(bufA, wot, bo, x, nullptr, out, MTOK, D_MODEL, D_MODEL, D_MODEL, D_MODEL, D_MODEL);
  k_transpose_w<<<dim3(DFFP/32, 64), tb, 0, stream>>>(w3, w3t, D_MODEL, DFF);
  k_rmsnorm<<<MTOK, 256, 0, stream>>>(out, g2, bufA);
  if (big){
    k_gemm8p<2><<<(MTOK/256)*(DFFP/256), 512, 131072, stream>>>(bufA, w1t, nullptr, nullptr, h1, MTOK, DFFP, D_MODEL, D_MODEL, D_MODEL, DFFP);
    k_gemm8p<4><<<(MTOK/256)*(DFFP/256), 512, 131072, stream>>>(bufA, w3t, nullptr, h1, h1, MTOK, DFFP, D_MODEL, D_MODEL, D_MODEL, DFFP);
  } else {
    k_gemm_bt<2><<<(DFFP/128)*32, 256, 0, stream>>>(bufA, w1t, nullptr, nullptr, nullptr, h1, MTOK, DFFP, D_MODEL, D_MODEL, D_MODEL, DFFP);
    k_gemm_bt<4><<<(DFFP/128)*32, 256, 0, stream>>>(bufA, w3t, nullptr, nullptr, h1, h1, MTOK, DFFP, D_MODEL, D_MODEL, D_MODEL, DFFP);
  }
  k_gemm_bt<3><<<16*32, 256, 0, stream>>>(h1, w2t, nullptr, out, nullptr, out, MTOK, D_MODEL, DFF, DFFP, DFF, D_MODEL);
}

// Round 9
// 777.896 us; speedup vs baseline: 1.1099x; 1.0728x over previous
//
#include <hip/hip_runtime.h>
#include <stdint.h>

typedef unsigned short u16;
typedef __bf16 bf16x8 __attribute__((ext_vector_type(8)));
typedef float f32x4 __attribute__((ext_vector_type(4)));

#define D_MODEL 2048
#define NHEADS 16
#define DK 128
#define DFF 5504
#define DFFP 5632   // DFF padded to 256 multiple
#define BB 2
#define SS 2048
#define MTOK 4096
#define DQKV 6144

#define AS1 __attribute__((address_space(1)))
#define AS3 __attribute__((address_space(3)))

__device__ __forceinline__ u16 f2bf(float f){
  union { float f; uint32_t u; } v; v.f = f;
  uint32_t r = v.u + 0x7fffu + ((v.u >> 16) & 1u);
  return (u16)(r >> 16);
}
__device__ __forceinline__ float bf2f(u16 u){
  union { uint32_t u; float f; } v; v.u = ((uint32_t)u) << 16;
  return v.f;
}
__device__ __forceinline__ u16 cvt_bf16(float f){
  union { __bf16 h; u16 u; } v; v.h = (__bf16)f; return v.u;
}
__device__ __forceinline__ float fexp2(float x){
#if __has_builtin(__builtin_amdgcn_exp2f)
  return __builtin_amdgcn_exp2f(x);
#else
  return exp2f(x);
#endif
}

// ---- fp32 W[K][Nsrc] -> bf16 Wt[n][K], zero-fill n >= Nsrc ----
__global__ __launch_bounds__(256) void k_transpose_w(const float* __restrict__ W,
                                                     u16* __restrict__ Wt, int K, int Nsrc){
  __shared__ float tile[32][33];
  int n0 = blockIdx.x * 32, k0 = blockIdx.y * 32;
  int tx = threadIdx.x, ty = threadIdx.y;  // (32,8)
  #pragma unroll
  for (int r = 0; r < 4; ++r){
    int n = n0 + tx;
    tile[ty + r*8][tx] = (n < Nsrc) ? W[(size_t)(k0 + ty + r*8) * Nsrc + n] : 0.0f;
  }
  __syncthreads();
  #pragma unroll
  for (int r = 0; r < 4; ++r)
    Wt[(size_t)(n0 + ty + r*8) * K + k0 + tx] = f2bf(tile[tx][ty + r*8]);
}

// ---- per-head V transpose from fused QKV ----
__global__ __launch_bounds__(256) void k_transpose_v(const u16* __restrict__ V,
                                                     u16* __restrict__ Vt, int ld){
  __shared__ u16 tile[32][33];
  int s0 = blockIdx.x * 32;
  int bh = blockIdx.y >> 2, dt = blockIdx.y & 3;
  int b = bh >> 4, h = bh & 15;
  int tx = threadIdx.x, ty = threadIdx.y;
  #pragma unroll
  for (int r = 0; r < 4; ++r)
    tile[ty + r*8][tx] = V[(size_t)(b*SS + s0 + ty + r*8) * ld + h*DK + dt*32 + tx];
  __syncthreads();
  #pragma unroll
  for (int r = 0; r < 4; ++r)
    Vt[(size_t)(bh*DK + dt*32 + ty + r*8) * SS + s0 + tx] = tile[tx][ty + r*8];
}

__global__ __launch_bounds__(256) void k_concat3(const float* __restrict__ a,
                                                 const float* __restrict__ b,
                                                 const float* __restrict__ c,
                                                 float* __restrict__ o){
  int i = blockIdx.x*256 + threadIdx.x;
  if (i >= DQKV) return;
  o[i] = (i < 2048) ? a[i] : (i < 4096 ? b[i-2048] : c[i-4096]);
}

// ---- RMSNorm: fp32 row -> bf16 row ----
__global__ __launch_bounds__(256) void k_rmsnorm(const float* __restrict__ X,
                                                 const float* __restrict__ g,
                                                 u16* __restrict__ out){
  int row = blockIdx.x, tid = threadIdx.x;
  const float* x = X + (size_t)row * D_MODEL;
  float4 a = ((const float4*)x)[tid*2];
  float4 b = ((const float4*)x)[tid*2+1];
  float ss = a.x*a.x + a.y*a.y + a.z*a.z + a.w*a.w
           + b.x*b.x + b.y*b.y + b.z*b.z + b.w*b.w;
  #pragma unroll
  for (int m = 1; m < 64; m <<= 1) ss += __shfl_xor(ss, m, 64);
  __shared__ float red[4];
  if ((tid & 63) == 0) red[tid >> 6] = ss;
  __syncthreads();
  float tot = red[0] + red[1] + red[2] + red[3];
  float sc = rsqrtf(tot * (1.0f / D_MODEL) + 1e-6f);
  float4 ga = ((const float4*)g)[tid*2];
  float4 gb = ((const float4*)g)[tid*2+1];
  uint32_t w0 = f2bf(a.x*sc*ga.x) | ((uint32_t)f2bf(a.y*sc*ga.y) << 16);
  uint32_t w1 = f2bf(a.z*sc*ga.z) | ((uint32_t)f2bf(a.w*sc*ga.w) << 16);
  uint32_t w2 = f2bf(b.x*sc*gb.x) | ((uint32_t)f2bf(b.y*sc*gb.y) << 16);
  uint32_t w3 = f2bf(b.z*sc*gb.z) | ((uint32_t)f2bf(b.w*sc*gb.w) << 16);
  ((uint4*)(out + (size_t)row * D_MODEL))[tid] = make_uint4(w0, w1, w2, w3);
}

// ============ 256x256 8-wave GEMM — faithful m201 8-phase template ============
template<int EPI>
__global__ __launch_bounds__(512, 2) void k_gemm8p(
    const u16* __restrict__ A, const u16* __restrict__ Bt,
    const float* __restrict__ bias, const u16* __restrict__ aux,
    void* __restrict__ Cout, int M, int N, int K,
    int lda, int ldb, int ldc)
{
  extern __shared__ __align__(16) char smem[];
  const int tid = threadIdx.x;
  const int lane = tid & 63, wid = tid >> 6;
  const int wr = wid >> 2, wc = wid & 3;        // 2M x 4N waves
  const int lrow = lane & 15, lhi = lane >> 4;

  int nwg = gridDim.x, wg = blockIdx.x;
  int qq = nwg >> 3, rr = nwg & 7;
  int xcd = wg & 7, sub = wg >> 3;
  int swz = (xcd < rr ? xcd*(qq+1) : rr*(qq+1) + (xcd-rr)*qq) + sub;
  int nbx = N >> 8;
  int m0 = (swz / nbx) << 8, n0 = (swz % nbx) << 8;

  const int nk = K >> 6;                         // BK = 64
  const int hA = wr, hB = wc >> 1;
  const int gA = wc;
  const int gB = (wr << 1) | (wc & 1);

  auto stA = [&](int d, int kk, int q){
    #pragma unroll
    for (int L = 0; L < 2; ++L){
      int p = q*8192 + gA*2048 + L*1024 + lane*16;
      int b = p ^ (((p >> 9) & 1) << 5);
      int row = b >> 7, o = b & 127;
      __builtin_amdgcn_global_load_lds(
        (const AS1 void*)(A + (size_t)(m0 + hA*128 + row)*lda + kk + (o >> 1)),
        (AS3 void*)(smem + d*65536 + hA*16384 + p), 16, 0, 0);
    }
  };
  auto stB = [&](int d, int kk, int s){
    #pragma unroll
    for (int L = 0; L < 2; ++L){
      int p = s*4096 + (gB >> 1)*8192 + (gB & 1)*2048 + L*1024 + lane*16;
      int b = p ^ (((p >> 9) & 1) << 5);
      int row = b >> 7, o = b & 127;
      __builtin_amdgcn_global_load_lds(
        (const AS1 void*)(Bt + (size_t)(n0 + hB*128 + row)*ldb + kk + (o >> 1)),
        (AS3 void*)(smem + d*65536 + 32768 + hB*16384 + p), 16, 0, 0);
    }
  };
  auto rdA = [&](int d, int rloc, int ks)->bf16x8{
    int b = rloc*128 + ks*64 + lhi*16;
    int p = b ^ (((b >> 9) & 1) << 5);
    return *(const bf16x8*)(smem + d*65536 + hA*16384 + p);
  };
  auto rdB = [&](int d, int rloc, int ks)->bf16x8{
    int b = rloc*128 + ks*64 + lhi*16;
    int p = b ^ (((b >> 9) & 1) << 5);
    return *(const bf16x8*)(smem + d*65536 + 32768 + hB*16384 + p);
  };

  f32x4 acc[8][4] = {};

  stA(0, 0, 0); stB(0, 0, 0); stB(0, 0, 1); stA(0, 0, 1);
  asm volatile("s_waitcnt vmcnt(0)" ::: "memory");
  __builtin_amdgcn_s_barrier();

  for (int t = 0; t < nk; ++t){
    int d = t & 1, dn = d ^ 1, kkn = (t + 1) << 6;
    bool pf = (t + 1 < nk);
    bf16x8 aR[8], bQ0[4], bQ1[4];

    // ---- phase 0: Q00 ----
    #pragma unroll
    for (int ii = 0; ii < 4; ++ii){
      aR[ii*2]   = rdA(d, ii*16 + lrow, 0);
      aR[ii*2+1] = rdA(d, ii*16 + lrow, 1);
    }
    #pragma unroll
    for (int j = 0; j < 2; ++j){
      bQ0[j*2]   = rdB(d, (wc&1)*64 + j*16 + lrow, 0);
      bQ0[j*2+1] = rdB(d, (wc&1)*64 + j*16 + lrow, 1);
    }
    if (pf){ stA(dn, kkn, 0); stB(dn, kkn, 0); }
    asm volatile("s_waitcnt lgkmcnt(0)" ::: "memory");
    __builtin_amdgcn_sched_barrier(0);
    __builtin_amdgcn_s_setprio(1);
    #pragma unroll
    for (int ii = 0; ii < 4; ++ii)
      #pragma unroll
      for (int j = 0; j < 2; ++j){
        acc[ii][j] = __builtin_amdgcn_mfma_f32_16x16x32_bf16(aR[ii*2],   bQ0[j*2],   acc[ii][j], 0, 0, 0);
        acc[ii][j] = __builtin_amdgcn_mfma_f32_16x16x32_bf16(aR[ii*2+1], bQ0[j*2+1], acc[ii][j], 0, 0, 0);
      }
    __builtin_amdgcn_s_setprio(0);
    if (pf) asm volatile("s_waitcnt vmcnt(6)" ::: "memory");
    else    asm volatile("s_waitcnt vmcnt(2)" ::: "memory");
    __builtin_amdgcn_sched_barrier(0);
    __builtin_amdgcn_s_barrier();

    // ---- phase 1: Q01 ----
    #pragma unroll
    for (int j = 0; j < 2; ++j){
      bQ1[j*2]   = rdB(d, (wc&1)*64 + 32 + j*16 + lrow, 0);
      bQ1[j*2+1] = rdB(d, (wc&1)*64 + 32 + j*16 + lrow, 1);
    }
    if (pf) stB(dn, kkn, 1);
    asm volatile("s_waitcnt lgkmcnt(0)" ::: "memory");
    __builtin_amdgcn_sched_barrier(0);
    __builtin_amdgcn_s_setprio(1);
    #pragma unroll
    for (int ii = 0; ii < 4; ++ii)
      #pragma unroll
      for (int j = 0; j < 2; ++j){
        acc[ii][2+j] = __builtin_amdgcn_mfma_f32_16x16x32_bf16(aR[ii*2],   bQ1[j*2],   acc[ii][2+j], 0, 0, 0);
        acc[ii][2+j] = __builtin_amdgcn_mfma_f32_16x16x32_bf16(aR[ii*2+1], bQ1[j*2+1], acc[ii][2+j], 0, 0, 0);
      }
    __builtin_amdgcn_s_setprio(0);
    if (pf) asm volatile("s_waitcnt vmcnt(6)" ::: "memory");
    else    asm volatile("s_waitcnt vmcnt(0)" ::: "memory");
    __builtin_amdgcn_sched_barrier(0);
    __builtin_amdgcn_s_barrier();

    // ---- phase 2: Q11 ----
    #pragma unroll
    for (int ii = 0; ii < 4; ++ii){
      aR[ii*2]   = rdA(d, 64 + ii*16 + lrow, 0);
      aR[ii*2+1] = rdA(d, 64 + ii*16 + lrow, 1);
    }
    if (pf) stA(dn, kkn, 1);
    asm volatile("s_waitcnt lgkmcnt(0)" ::: "memory");
    __builtin_amdgcn_sched_barrier(0);
    __builtin_amdgcn_s_setprio(1);
    #pragma unroll
    for (int ii = 0; ii < 4; ++ii)
      #pragma unroll
      for (int j = 0; j < 2; ++j){
        acc[4+ii][2+j] = __builtin_amdgcn_mfma_f32_16x16x32_bf16(aR[ii*2],   bQ1[j*2],   acc[4+ii][2+j], 0, 0, 0);
        acc[4+ii][2+j] = __builtin_amdgcn_mfma_f32_16x16x32_bf16(aR[ii*2+1], bQ1[j*2+1], acc[4+ii][2+j], 0, 0, 0);
      }
    __builtin_amdgcn_s_setprio(0);
    __builtin_amdgcn_s_barrier();

    // ---- phase 3: Q10 ----
    __builtin_amdgcn_s_setprio(1);
    #pragma unroll
    for (int ii = 0; ii < 4; ++ii)
      #pragma unroll
      for (int j = 0; j < 2; ++j){
        acc[4+ii][j] = __builtin_amdgcn_mfma_f32_16x16x32_bf16(aR[ii*2],   bQ0[j*2],   acc[4+ii][j], 0, 0, 0);
        acc[4+ii][j] = __builtin_amdgcn_mfma_f32_16x16x32_bf16(aR[ii*2+1], bQ0[j*2+1], acc[4+ii][j], 0, 0, 0);
      }
    __builtin_amdgcn_s_setprio(0);
    if (pf) asm volatile("s_waitcnt vmcnt(4)" ::: "memory");
    __builtin_amdgcn_sched_barrier(0);
    __builtin_amdgcn_s_barrier();
  }

  #pragma unroll
  for (int i = 0; i < 8; ++i){
    #pragma unroll
    for (int j = 0; j < 4; ++j){
      int col = n0 + wc*64 + j*16 + lrow;
      float bv = 0.f;
      if constexpr (EPI == 0) bv = bias[col];
      #pragma unroll
      for (int q = 0; q < 4; ++q){
        int row = m0 + wr*128 + i*16 + lhi*4 + q;
        size_t idx = (size_t)row*ldc + col;
        float v = acc[i][j][q] + bv;
        if constexpr (EPI == 4){
          float a0v = bf2f(aux[idx]);
          v = a0v / (1.f + __expf(-a0v)) * v;
        }
        ((u16*)Cout)[idx] = f2bf(v);
      }
    }
  }
}

// ---- 128x128 GEMM (3-buffer counted vmcnt) — O-proj / W2 / fallback ----
template<int EPI>
__global__ __launch_bounds__(256) void k_gemm_bt(
    const u16* __restrict__ A, const u16* __restrict__ Bt,
    const float* __restrict__ bias, const float* __restrict__ res,
    const u16* __restrict__ aux,
    void* __restrict__ Cout, int M, int N, int K,
    int lda, int ldb, int ldc)
{
  __shared__ __align__(16) u16 As[3][128*32];
  __shared__ __align__(16) u16 Bs[3][128*32];
  int tid = threadIdx.x;

  int nwg = gridDim.x, wg = blockIdx.x;
  int qq = nwg >> 3, rr = nwg & 7;
  int xcd = wg & 7, sub = wg >> 3;
  int swz = (xcd < rr ? xcd*(qq+1) : rr*(qq+1) + (xcd-rr)*qq) + sub;
  int nbx = N >> 7;
  int m0 = (swz / nbx) << 7, n0 = (swz % nbx) << 7;

  int lane = tid & 63, wave = tid >> 6;
  int wr = wave >> 1, wc = wave & 1;
  int lrow = lane & 15, lhi = lane >> 4;
  f32x4 acc[4][4] = {};
  int srow = tid >> 2;
  int scol = (tid & 3) * 8;
  const int nk = K >> 5;

  auto stage = [&](int slot, int kt){
    int k0 = kt << 5;
    #pragma unroll
    for (int c = 0; c < 2; ++c){
      int r = c*64 + srow;
      __builtin_amdgcn_global_load_lds(
        (const AS1 void*)(A + (size_t)(m0 + r)*lda + k0 + scol),
        (AS3 void*)(&As[slot][r*32 + scol]), 16, 0, 0);
      __builtin_amdgcn_global_load_lds(
        (const AS1 void*)(Bt + (size_t)(n0 + r)*ldb + k0 + scol),
        (AS3 void*)(&Bs[slot][r*32 + scol]), 16, 0, 0);
    }
  };

  stage(0, 0);
  if (nk > 1) stage(1, 1);
  if (nk > 1) asm volatile("s_waitcnt vmcnt(4)" ::: "memory");
  else        asm volatile("s_waitcnt vmcnt(0)" ::: "memory");
  __builtin_amdgcn_s_barrier();

  for (int kt = 0; kt < nk; ++kt){
    int cur = kt % 3;
    if (kt + 2 < nk) stage((kt + 2) % 3, kt + 2);
    bf16x8 af[4], bfv[4];
    #pragma unroll
    for (int i = 0; i < 4; ++i){
      af[i]  = *(const bf16x8*)(&As[cur][(wr*64 + i*16 + lrow)*32 + lhi*8]);
      bfv[i] = *(const bf16x8*)(&Bs[cur][(wc*64 + i*16 + lrow)*32 + lhi*8]);
    }
    #pragma unroll
    for (int i = 0; i < 4; ++i)
      #pragma unroll
      for (int j = 0; j < 4; ++j)
        acc[i][j] = __builtin_amdgcn_mfma_f32_16x16x32_bf16(af[i], bfv[j], acc[i][j], 0, 0, 0);
    if (kt + 2 < nk) asm volatile("s_waitcnt vmcnt(4)" ::: "memory");
    else             asm volatile("s_waitcnt vmcnt(0)" ::: "memory");
    __builtin_amdgcn_s_barrier();
  }

  #pragma unroll
  for (int i = 0; i < 4; ++i){
    #pragma unroll
    for (int j = 0; j < 4; ++j){
      int col = n0 + wc*64 + j*16 + lrow;
      float bv = 0.f;
      if constexpr (EPI == 0 || EPI == 1) bv = bias[col];
      #pragma unroll
      for (int q = 0; q < 4; ++q){
        int row = m0 + wr*64 + i*16 + lhi*4 + q;
        size_t idx = (size_t)row*ldc + col;
        float v = acc[i][j][q] + bv;
        if constexpr (EPI == 1 || EPI == 3) v += res[idx];
        if constexpr (EPI == 4){
          float a0 = bf2f(aux[idx]);
          v = a0 / (1.f + __expf(-a0)) * v;
        }
        if constexpr (EPI == 0 || EPI == 2 || EPI == 4) ((u16*)Cout)[idx] = f2bf(v);
        else ((float*)Cout)[idx] = v;
      }
    }
  }
}

// ---- causal flash attention: paired-qblock load balancing ----
// Grid = 256 blocks (1/CU). Block (bh, j) processes q-blocks qi=15-j then
// qi=j of the same head: per-block tile count = 34, constant (no tail).
// 128 q-rows/item, 8 waves x 16 rows, KVBLK=64, double-buffered staging.
__global__ __launch_bounds__(512) void k_attn(
    const u16* __restrict__ Q, const u16* __restrict__ Kb,
    const u16* __restrict__ Vt, u16* __restrict__ O, int ldq)
{
  int tid = threadIdx.x, lane = tid & 63, wave = tid >> 6;  // 8 waves
  int lrow = lane & 15, lhi = lane >> 4;
  int bidx = blockIdx.x;
  int bh = bidx >> 3, j = bidx & 7;
  int b = bh >> 4, h = bh & 15;

  __shared__ __align__(16) u16 Kbuf[2][64*128];   // 32 KB
  __shared__ __align__(16) u16 Vbuf[2][128*64];   // 32 KB
  __shared__ __align__(16) u16 P_lds[8][16*64];   // 16 KB
  char* pw = (char*)&P_lds[wave][0];
  const float sc2 = 0.08838834764831845f * 1.44269504088896340736f;

  auto stage = [&](int bufi, int kt){
    int kv0 = kt << 6;
    char* kd = (char*)&Kbuf[bufi][0];
    char* vd = (char*)&Vbuf[bufi][0];
    #pragma unroll
    for (int L = 0; L < 2; ++L){
      int cid = wave*128 + L*64 + lane;        // 0..1023
      int r = cid >> 4, c = cid & 15;          // K: row 0..63, chunk 0..15
      int cg = c ^ (r & 7);
      __builtin_amdgcn_global_load_lds(
        (const AS1 void*)(Kb + (size_t)(b*SS + kv0 + r)*ldq + h*DK + cg*8),
        (AS3 void*)(kd + wave*2048 + L*1024 + lane*16), 16, 0, 0);
      int dd = cid >> 3, c8 = cid & 7;         // V: row 0..127, chunk 0..7
      int cv = c8 ^ (dd & 7);
      __builtin_amdgcn_global_load_lds(
        (const AS1 void*)(Vt + (size_t)bh*DK*SS + (size_t)dd*SS + kv0 + cv*8),
        (AS3 void*)(vd + wave*2048 + L*1024 + lane*16), 16, 0, 0);
    }
  };

  #pragma unroll 1
  for (int item = 0; item < 2; ++item){
    int qi = item == 0 ? 15 - j : j;
    int qs = qi * 128;
    int nt = 2*qi + 2;
    int qrow = qs + wave * 16;

    bf16x8 qf[4];
    const u16* qbase = Q + (size_t)(b*SS + qrow + lrow)*ldq + h*DK + lhi*8;
    #pragma unroll
    for (int dc = 0; dc < 4; ++dc) qf[dc] = *(const bf16x8*)(qbase + dc*32);

    f32x4 accO[8] = {};
    float mr[4] = {-1e30f,-1e30f,-1e30f,-1e30f};
    float lr[4] = {0.f,0.f,0.f,0.f};

    stage(0, 0);
    __syncthreads();

    for (int kt = 0; kt < nt; ++kt){
      int cur = kt & 1;
      if (kt + 1 < nt) stage(cur ^ 1, kt + 1);
      int kv0 = kt << 6;
      if (kv0 <= qrow + 15){   // wave-uniform causal gate
        const char* kl = (const char*)&Kbuf[cur][0];
        const char* vl = (const char*)&Vbuf[cur][0];
        bool domask = (kv0 + 63 > qrow);

        f32x4 sf[4];
        #pragma unroll
        for (int hf = 0; hf < 4; ++hf){
          int rl = hf*16 + lrow;
          int sw = rl & 7;
          f32x4 a = {};
          #pragma unroll
          for (int dc = 0; dc < 4; ++dc){
            bf16x8 kf = *(const bf16x8*)(kl + rl*256 + (((lhi + dc*4) ^ sw) << 4));
            a = __builtin_amdgcn_mfma_f32_16x16x32_bf16(qf[dc], kf, a, 0, 0, 0);
          }
          sf[hf] = a;
        }

        float p[4][4], mx[4];
        #pragma unroll
        for (int q = 0; q < 4; ++q){
          float s0 = sf[0][q]*sc2, s1 = sf[1][q]*sc2, s2 = sf[2][q]*sc2, s3 = sf[3][q]*sc2;
          if (domask){
            int qg = qrow + lhi*4 + q;
            if (kv0      + lrow > qg) s0 = -1e30f;
            if (kv0 + 16 + lrow > qg) s1 = -1e30f;
            if (kv0 + 32 + lrow > qg) s2 = -1e30f;
            if (kv0 + 48 + lrow > qg) s3 = -1e30f;
          }
          p[q][0]=s0; p[q][1]=s1; p[q][2]=s2; p[q][3]=s3;
          float m = fmaxf(fmaxf(s0,s1), fmaxf(s2,s3));
          m = fmaxf(m, __shfl_xor(m, 1, 64));
          m = fmaxf(m, __shfl_xor(m, 2, 64));
          m = fmaxf(m, __shfl_xor(m, 4, 64));
          m = fmaxf(m, __shfl_xor(m, 8, 64));
          mx[q] = m;
        }
        float dmax = fmaxf(fmaxf(mx[0]-mr[0], mx[1]-mr[1]), fmaxf(mx[2]-mr[2], mx[3]-mr[3]));
        bool rescale = !__all(dmax <= 8.0f);
        float al[4];
        #pragma unroll
        for (int q = 0; q < 4; ++q){
          if (rescale){
            float mn = fmaxf(mr[q], mx[q]);
            al[q] = fexp2(mr[q] - mn);
            mr[q] = mn;
          } else al[q] = 1.0f;
          p[q][0] = fexp2(p[q][0] - mr[q]);
          p[q][1] = fexp2(p[q][1] - mr[q]);
          p[q][2] = fexp2(p[q][2] - mr[q]);
          p[q][3] = fexp2(p[q][3] - mr[q]);
          float sm = (p[q][0] + p[q][1]) + (p[q][2] + p[q][3]);
          sm += __shfl_xor(sm, 1, 64);
          sm += __shfl_xor(sm, 2, 64);
          sm += __shfl_xor(sm, 4, 64);
          sm += __shfl_xor(sm, 8, 64);
          lr[q] = lr[q]*al[q] + sm;
        }
        if (rescale){
          #pragma unroll
          for (int f = 0; f < 8; ++f)
            #pragma unroll
            for (int q = 0; q < 4; ++q) accO[f][q] *= al[q];
        }

        #pragma unroll
        for (int q = 0; q < 4; ++q){
          int row = lhi*4 + q;
          int rb = row*128, sw = (row & 7) << 4;
          #pragma unroll
          for (int hf = 0; hf < 4; ++hf)
            *(u16*)(pw + rb + ((hf*32 + lrow*2) ^ sw)) = cvt_bf16(p[q][hf]);
        }
        __builtin_amdgcn_sched_barrier(0);
        int rsw = (lrow & 7) << 4;
        bf16x8 pa0 = *(const bf16x8*)(pw + lrow*128 + ((     lhi*16) ^ rsw));
        bf16x8 pa1 = *(const bf16x8*)(pw + lrow*128 + ((64 + lhi*16) ^ rsw));

        #pragma unroll
        for (int f = 0; f < 8; ++f){
          int d = f*16 + lrow;
          int swv = d & 7;
          bf16x8 v0 = *(const bf16x8*)(vl + d*128 + (((lhi    ) ^ swv) << 4));
          bf16x8 v1 = *(const bf16x8*)(vl + d*128 + (((lhi + 4) ^ swv) << 4));
          accO[f] = __builtin_amdgcn_mfma_f32_16x16x32_bf16(pa0, v0, accO[f], 0, 0, 0);
          accO[f] = __builtin_amdgcn_mfma_f32_16x16x32_bf16(pa1, v1, accO[f], 0, 0, 0);
        }
      }
      __syncthreads();
    }

    #pragma unroll
    for (int q = 0; q < 4; ++q){
      float inv = 1.0f / lr[q];
      #pragma unroll
      for (int f = 0; f < 8; ++f){
        int row = b*SS + qrow + lhi*4 + q;
        int col = h*DK + f*16 + lrow;
        O[(size_t)row*D_MODEL + col] = cvt_bf16(accO[f][q] * inv);
      }
    }
    __syncthreads();  // item A fully done (incl. O-write) before item B restages
  }
}

extern "C" void kernel_launch(void* const* d_in, const int* in_sizes, int n_in,
                              void* d_out, int out_size, void* d_ws, size_t ws_size,
                              hipStream_t stream)
{
  (void)in_sizes; (void)n_in; (void)out_size;
  const float* x  = (const float*)d_in[0];
  const float* wq = (const float*)d_in[2];
  const float* bq = (const float*)d_in[3];
  const float* wk = (const float*)d_in[4];
  const float* bk = (const float*)d_in[5];
  const float* wv = (const float*)d_in[6];
  const float* bv = (const float*)d_in[7];
  const float* wo = (const float*)d_in[8];
  const float* bo = (const float*)d_in[9];
  const float* g1 = (const float*)d_in[10];
  const float* g2 = (const float*)d_in[11];
  const float* w1 = (const float*)d_in[12];
  const float* w3 = (const float*)d_in[13];  // w3 precedes w2 in dict order
  const float* w2 = (const float*)d_in[14];
  float* out = (float*)d_out;

  const size_t MB = 1u << 20;
  const size_t WFF2 = (size_t)D_MODEL * DFF * sizeof(u16);
  const size_t NEED = 112*MB + WFF2 + 32768;
  if (ws_size < NEED) return;
  char* ws = (char*)d_ws;
  u16* bufA = (u16*)(ws + 0);        // 16 MiB: nbf1 -> aob -> nbf2
  u16* qkv  = (u16*)(ws + 16*MB);    // 48 MiB fused QKV [4096][6144]
  u16* h1   = qkv;                   // [4096][5632], aliases qkv after attn
  u16* wqkvt= (u16*)(ws + 64*MB);    // 24 MiB: wq^T|wk^T|wv^T [6144][2048]
  u16* w1t  = wqkvt;                 // [5632][2048], aliases after QKV GEMM
  u16* wot  = (u16*)(ws + 88*MB);    // 8 MiB
  u16* w3t  = (u16*)(ws + 88*MB);    // [5632][2048], aliases wot+vtb after O-proj
  u16* vtb  = (u16*)(ws + 96*MB);    // 16 MiB
  u16* w2t  = (u16*)(ws + 112*MB);   // [2048][5504]
  float* bqkv = (float*)(ws + 112*MB + WFF2);
  // fp32 residual x1 lives in d_out

  bool big = true;
  big &= hipFuncSetAttribute((const void*)k_gemm8p<0>, hipFuncAttributeMaxDynamicSharedMemorySize, 131072) == hipSuccess;
  big &= hipFuncSetAttribute((const void*)k_gemm8p<2>, hipFuncAttributeMaxDynamicSharedMemorySize, 131072) == hipSuccess;
  big &= hipFuncSetAttribute((const void*)k_gemm8p<4>, hipFuncAttributeMaxDynamicSharedMemorySize, 131072) == hipSuccess;

  dim3 tb(32, 8);
  k_transpose_w<<<dim3(64,64), tb, 0, stream>>>(wq, wqkvt,               D_MODEL, D_MODEL);
  k_transpose_w<<<dim3(64,64), tb, 0, stream>>>(wk, wqkvt + 2048*2048,   D_MODEL, D_MODEL);
  k_transpose_w<<<dim3(64,64), tb, 0, stream>>>(wv, wqkvt + 2*2048*2048, D_MODEL, D_MODEL);
  k_transpose_w<<<dim3(64,64), tb, 0, stream>>>(wo, wot, D_MODEL, D_MODEL);
  k_transpose_w<<<dim3(64, DFF/32), tb, 0, stream>>>(w2, w2t, DFF, D_MODEL);
  k_concat3<<<24, 256, 0, stream>>>(bq, bk, bv, bqkv);

  k_rmsnorm<<<MTOK, 256, 0, stream>>>(x, g1, bufA);
  if (big)
    k_gemm8p<0><<<(MTOK/256)*(DQKV/256), 512, 131072, stream>>>(bufA, wqkvt, bqkv, nullptr, qkv, MTOK, DQKV, D_MODEL, D_MODEL, D_MODEL, DQKV);
  else
    k_gemm_bt<0><<<(DQKV/128)*(MTOK/128), 256, 0, stream>>>(bufA, wqkvt, bqkv, nullptr, nullptr, qkv, MTOK, DQKV, D_MODEL, D_MODEL, D_MODEL, DQKV);
  k_transpose_v<<<dim3(SS/32, 128), tb, 0, stream>>>(qkv + 4096, vtb, DQKV);
  k_attn<<<dim3(BB*NHEADS*8), 512, 0, stream>>>(qkv, qkv + 2048, vtb, bufA, DQKV);
  k_transpose_w<<<dim3(DFFP/32, 64), tb, 0, stream>>>(w1, w1t, D_MODEL, DFF);
  k_gemm_bt<1><<<16*32, 256, 0, stream>>>(bufA, wot, bo, x, nullptr, out, MTOK, D_MODEL, D_MODEL, D_MODEL, D_MODEL, D_MODEL);
  k_transpose_w<<<dim3(DFFP/32, 64), tb, 0, stream>>>(w3, w3t, D_MODEL, DFF);
  k_rmsnorm<<<MTOK, 256, 0, stream>>>(out, g2, bufA);
  if (big){
    k_gemm8p<2><<<(MTOK/256)*(DFFP/256), 512, 131072, stream>>>(bufA, w1t, nullptr, nullptr, h1, MTOK, DFFP, D_MODEL, D_MODEL, D_MODEL, DFFP);
    k_gemm8p<4><<<(MTOK/256)*(DFFP/256), 512, 131072, stream>>>(bufA, w3t, nullptr, h1, h1, MTOK, DFFP, D_MODEL, D_MODEL, D_MODEL, DFFP);
  } else {
    k_gemm_bt<2><<<(DFFP/128)*32, 256, 0, stream>>>(bufA, w1t, nullptr, nullptr, nullptr, h1, MTOK, DFFP, D_MODEL, D_MODEL, D_MODEL, DFFP);
    k_gemm_bt<4><<<(DFFP/128)*32, 256, 0, stream>>>(bufA, w3t, nullptr, nullptr, h1, h1, MTOK, DFFP, D_MODEL, D_MODEL, D_MODEL, DFFP);
  }
  k_gemm_bt<3><<<16*32, 256, 0, stream>>>(h1, w2t, nullptr, out, nullptr, out, MTOK, D_MODEL, DFF, DFFP, DFF, D_MODEL);
}

// Round 10
// 735.666 us; speedup vs baseline: 1.1736x; 1.0574x over previous
//
#include <hip/hip_runtime.h>
#include <stdint.h>

typedef unsigned short u16;
typedef __bf16 bf16x8 __attribute__((ext_vector_type(8)));
typedef float f32x4 __attribute__((ext_vector_type(4)));

#define D_MODEL 2048
#define NHEADS 16
#define DK 128
#define DFF 5504
#define DFFP 5632   // DFF padded to 256 multiple
#define BB 2
#define SS 2048
#define MTOK 4096
#define DQKV 6144

#define AS1 __attribute__((address_space(1)))
#define AS3 __attribute__((address_space(3)))

__device__ __forceinline__ u16 f2bf(float f){
  union { float f; uint32_t u; } v; v.f = f;
  uint32_t r = v.u + 0x7fffu + ((v.u >> 16) & 1u);
  return (u16)(r >> 16);
}
__device__ __forceinline__ float bf2f(u16 u){
  union { uint32_t u; float f; } v; v.u = ((uint32_t)u) << 16;
  return v.f;
}
__device__ __forceinline__ u16 cvt_bf16(float f){
  union { __bf16 h; u16 u; } v; v.h = (__bf16)f; return v.u;
}
__device__ __forceinline__ float fexp2(float x){
#if __has_builtin(__builtin_amdgcn_exp2f)
  return __builtin_amdgcn_exp2f(x);
#else
  return exp2f(x);
#endif
}

// ---- fp32 W[K][Nsrc] -> bf16 Wt[n][K], zero-fill n >= Nsrc ----
__global__ __launch_bounds__(256) void k_transpose_w(const float* __restrict__ W,
                                                     u16* __restrict__ Wt, int K, int Nsrc){
  __shared__ float tile[32][33];
  int n0 = blockIdx.x * 32, k0 = blockIdx.y * 32;
  int tx = threadIdx.x, ty = threadIdx.y;  // (32,8)
  #pragma unroll
  for (int r = 0; r < 4; ++r){
    int n = n0 + tx;
    tile[ty + r*8][tx] = (n < Nsrc) ? W[(size_t)(k0 + ty + r*8) * Nsrc + n] : 0.0f;
  }
  __syncthreads();
  #pragma unroll
  for (int r = 0; r < 4; ++r)
    Wt[(size_t)(n0 + ty + r*8) * K + k0 + tx] = f2bf(tile[tx][ty + r*8]);
}

// ---- per-head V transpose from fused QKV ----
__global__ __launch_bounds__(256) void k_transpose_v(const u16* __restrict__ V,
                                                     u16* __restrict__ Vt, int ld){
  __shared__ u16 tile[32][33];
  int s0 = blockIdx.x * 32;
  int bh = blockIdx.y >> 2, dt = blockIdx.y & 3;
  int b = bh >> 4, h = bh & 15;
  int tx = threadIdx.x, ty = threadIdx.y;
  #pragma unroll
  for (int r = 0; r < 4; ++r)
    tile[ty + r*8][tx] = V[(size_t)(b*SS + s0 + ty + r*8) * ld + h*DK + dt*32 + tx];
  __syncthreads();
  #pragma unroll
  for (int r = 0; r < 4; ++r)
    Vt[(size_t)(bh*DK + dt*32 + ty + r*8) * SS + s0 + tx] = tile[tx][ty + r*8];
}

__global__ __launch_bounds__(256) void k_concat3(const float* __restrict__ a,
                                                 const float* __restrict__ b,
                                                 const float* __restrict__ c,
                                                 float* __restrict__ o){
  int i = blockIdx.x*256 + threadIdx.x;
  if (i >= DQKV) return;
  o[i] = (i < 2048) ? a[i] : (i < 4096 ? b[i-2048] : c[i-4096]);
}

// ---- RMSNorm: fp32 row -> bf16 row ----
__global__ __launch_bounds__(256) void k_rmsnorm(const float* __restrict__ X,
                                                 const float* __restrict__ g,
                                                 u16* __restrict__ out){
  int row = blockIdx.x, tid = threadIdx.x;
  const float* x = X + (size_t)row * D_MODEL;
  float4 a = ((const float4*)x)[tid*2];
  float4 b = ((const float4*)x)[tid*2+1];
  float ss = a.x*a.x + a.y*a.y + a.z*a.z + a.w*a.w
           + b.x*b.x + b.y*b.y + b.z*b.z + b.w*b.w;
  #pragma unroll
  for (int m = 1; m < 64; m <<= 1) ss += __shfl_xor(ss, m, 64);
  __shared__ float red[4];
  if ((tid & 63) == 0) red[tid >> 6] = ss;
  __syncthreads();
  float tot = red[0] + red[1] + red[2] + red[3];
  float sc = rsqrtf(tot * (1.0f / D_MODEL) + 1e-6f);
  float4 ga = ((const float4*)g)[tid*2];
  float4 gb = ((const float4*)g)[tid*2+1];
  uint32_t w0 = f2bf(a.x*sc*ga.x) | ((uint32_t)f2bf(a.y*sc*ga.y) << 16);
  uint32_t w1 = f2bf(a.z*sc*ga.z) | ((uint32_t)f2bf(a.w*sc*ga.w) << 16);
  uint32_t w2 = f2bf(b.x*sc*gb.x) | ((uint32_t)f2bf(b.y*sc*gb.y) << 16);
  uint32_t w3 = f2bf(b.z*sc*gb.z) | ((uint32_t)f2bf(b.w*sc*gb.w) << 16);
  ((uint4*)(out + (size_t)row * D_MODEL))[tid] = make_uint4(w0, w1, w2, w3);
}

// ============ 256x256 8-wave GEMM — 8-phase template, row&7 chunk swizzle ============
// Swizzle (both sides, G4 form): within each 128B row, 16B-chunk' = chunk ^ (row&7)
// -> 16-lane groups spread over 8 bank-quads (2-way = free). Involution; row bits
// untouched, so pre-swizzled global source + swizzled ds_read stay consistent.
template<int EPI>
__global__ __launch_bounds__(512, 2) void k_gemm8p(
    const u16* __restrict__ A, const u16* __restrict__ Bt,
    const float* __restrict__ bias, const u16* __restrict__ aux,
    void* __restrict__ Cout, int M, int N, int K,
    int lda, int ldb, int ldc)
{
  extern __shared__ __align__(16) char smem[];
  const int tid = threadIdx.x;
  const int lane = tid & 63, wid = tid >> 6;
  const int wr = wid >> 2, wc = wid & 3;        // 2M x 4N waves
  const int lrow = lane & 15, lhi = lane >> 4;

  int nwg = gridDim.x, wg = blockIdx.x;
  int qq = nwg >> 3, rr = nwg & 7;
  int xcd = wg & 7, sub = wg >> 3;
  int swz = (xcd < rr ? xcd*(qq+1) : rr*(qq+1) + (xcd-rr)*qq) + sub;
  int nbx = N >> 8;
  int m0 = (swz / nbx) << 8, n0 = (swz % nbx) << 8;

  const int nk = K >> 6;                         // BK = 64
  const int hA = wr, hB = wc >> 1;
  const int gA = wc;
  const int gB = (wr << 1) | (wc & 1);

  auto stA = [&](int d, int kk, int q){
    #pragma unroll
    for (int L = 0; L < 2; ++L){
      int p = q*8192 + gA*2048 + L*1024 + lane*16;   // physical (linear dest)
      int row = p >> 7;
      int o = (p & 127) ^ ((row & 7) << 4);          // logical in-row byte
      __builtin_amdgcn_global_load_lds(
        (const AS1 void*)(A + (size_t)(m0 + hA*128 + row)*lda + kk + (o >> 1)),
        (AS3 void*)(smem + d*65536 + hA*16384 + p), 16, 0, 0);
    }
  };
  auto stB = [&](int d, int kk, int s){
    #pragma unroll
    for (int L = 0; L < 2; ++L){
      int p = s*4096 + (gB >> 1)*8192 + (gB & 1)*2048 + L*1024 + lane*16;
      int row = p >> 7;
      int o = (p & 127) ^ ((row & 7) << 4);
      __builtin_amdgcn_global_load_lds(
        (const AS1 void*)(Bt + (size_t)(n0 + hB*128 + row)*ldb + kk + (o >> 1)),
        (AS3 void*)(smem + d*65536 + 32768 + hB*16384 + p), 16, 0, 0);
    }
  };
  auto rdA = [&](int d, int rloc, int ks)->bf16x8{
    int p = rloc*128 + ((ks*64 + lhi*16) ^ ((rloc & 7) << 4));
    return *(const bf16x8*)(smem + d*65536 + hA*16384 + p);
  };
  auto rdB = [&](int d, int rloc, int ks)->bf16x8{
    int p = rloc*128 + ((ks*64 + lhi*16) ^ ((rloc & 7) << 4));
    return *(const bf16x8*)(smem + d*65536 + 32768 + hB*16384 + p);
  };

  f32x4 acc[8][4] = {};

  stA(0, 0, 0); stB(0, 0, 0); stB(0, 0, 1); stA(0, 0, 1);
  asm volatile("s_waitcnt vmcnt(0)" ::: "memory");
  __builtin_amdgcn_s_barrier();

  for (int t = 0; t < nk; ++t){
    int d = t & 1, dn = d ^ 1, kkn = (t + 1) << 6;
    bool pf = (t + 1 < nk);
    bf16x8 aR[8], bQ0[4], bQ1[4];

    // ---- phase 0: Q00 ----
    #pragma unroll
    for (int ii = 0; ii < 4; ++ii){
      aR[ii*2]   = rdA(d, ii*16 + lrow, 0);
      aR[ii*2+1] = rdA(d, ii*16 + lrow, 1);
    }
    #pragma unroll
    for (int j = 0; j < 2; ++j){
      bQ0[j*2]   = rdB(d, (wc&1)*64 + j*16 + lrow, 0);
      bQ0[j*2+1] = rdB(d, (wc&1)*64 + j*16 + lrow, 1);
    }
    if (pf){ stA(dn, kkn, 0); stB(dn, kkn, 0); }
    asm volatile("s_waitcnt lgkmcnt(0)" ::: "memory");
    __builtin_amdgcn_sched_barrier(0);
    __builtin_amdgcn_s_setprio(1);
    #pragma unroll
    for (int ii = 0; ii < 4; ++ii)
      #pragma unroll
      for (int j = 0; j < 2; ++j){
        acc[ii][j] = __builtin_amdgcn_mfma_f32_16x16x32_bf16(aR[ii*2],   bQ0[j*2],   acc[ii][j], 0, 0, 0);
        acc[ii][j] = __builtin_amdgcn_mfma_f32_16x16x32_bf16(aR[ii*2+1], bQ0[j*2+1], acc[ii][j], 0, 0, 0);
      }
    __builtin_amdgcn_s_setprio(0);
    if (pf) asm volatile("s_waitcnt vmcnt(6)" ::: "memory");
    else    asm volatile("s_waitcnt vmcnt(2)" ::: "memory");
    __builtin_amdgcn_sched_barrier(0);
    __builtin_amdgcn_s_barrier();

    // ---- phase 1: Q01 ----
    #pragma unroll
    for (int j = 0; j < 2; ++j){
      bQ1[j*2]   = rdB(d, (wc&1)*64 + 32 + j*16 + lrow, 0);
      bQ1[j*2+1] = rdB(d, (wc&1)*64 + 32 + j*16 + lrow, 1);
    }
    if (pf) stB(dn, kkn, 1);
    asm volatile("s_waitcnt lgkmcnt(0)" ::: "memory");
    __builtin_amdgcn_sched_barrier(0);
    __builtin_amdgcn_s_setprio(1);
    #pragma unroll
    for (int ii = 0; ii < 4; ++ii)
      #pragma unroll
      for (int j = 0; j < 2; ++j){
        acc[ii][2+j] = __builtin_amdgcn_mfma_f32_16x16x32_bf16(aR[ii*2],   bQ1[j*2],   acc[ii][2+j], 0, 0, 0);
        acc[ii][2+j] = __builtin_amdgcn_mfma_f32_16x16x32_bf16(aR[ii*2+1], bQ1[j*2+1], acc[ii][2+j], 0, 0, 0);
      }
    __builtin_amdgcn_s_setprio(0);
    if (pf) asm volatile("s_waitcnt vmcnt(6)" ::: "memory");
    else    asm volatile("s_waitcnt vmcnt(0)" ::: "memory");
    __builtin_amdgcn_sched_barrier(0);
    __builtin_amdgcn_s_barrier();

    // ---- phase 2: Q11 ----
    #pragma unroll
    for (int ii = 0; ii < 4; ++ii){
      aR[ii*2]   = rdA(d, 64 + ii*16 + lrow, 0);
      aR[ii*2+1] = rdA(d, 64 + ii*16 + lrow, 1);
    }
    if (pf) stA(dn, kkn, 1);
    asm volatile("s_waitcnt lgkmcnt(0)" ::: "memory");
    __builtin_amdgcn_sched_barrier(0);
    __builtin_amdgcn_s_setprio(1);
    #pragma unroll
    for (int ii = 0; ii < 4; ++ii)
      #pragma unroll
      for (int j = 0; j < 2; ++j){
        acc[4+ii][2+j] = __builtin_amdgcn_mfma_f32_16x16x32_bf16(aR[ii*2],   bQ1[j*2],   acc[4+ii][2+j], 0, 0, 0);
        acc[4+ii][2+j] = __builtin_amdgcn_mfma_f32_16x16x32_bf16(aR[ii*2+1], bQ1[j*2+1], acc[4+ii][2+j], 0, 0, 0);
      }
    __builtin_amdgcn_s_setprio(0);
    __builtin_amdgcn_s_barrier();

    // ---- phase 3: Q10 ----
    __builtin_amdgcn_s_setprio(1);
    #pragma unroll
    for (int ii = 0; ii < 4; ++ii)
      #pragma unroll
      for (int j = 0; j < 2; ++j){
        acc[4+ii][j] = __builtin_amdgcn_mfma_f32_16x16x32_bf16(aR[ii*2],   bQ0[j*2],   acc[4+ii][j], 0, 0, 0);
        acc[4+ii][j] = __builtin_amdgcn_mfma_f32_16x16x32_bf16(aR[ii*2+1], bQ0[j*2+1], acc[4+ii][j], 0, 0, 0);
      }
    __builtin_amdgcn_s_setprio(0);
    if (pf) asm volatile("s_waitcnt vmcnt(4)" ::: "memory");
    __builtin_amdgcn_sched_barrier(0);
    __builtin_amdgcn_s_barrier();
  }

  #pragma unroll
  for (int i = 0; i < 8; ++i){
    #pragma unroll
    for (int j = 0; j < 4; ++j){
      int col = n0 + wc*64 + j*16 + lrow;
      float bv = 0.f;
      if constexpr (EPI == 0) bv = bias[col];
      #pragma unroll
      for (int q = 0; q < 4; ++q){
        int row = m0 + wr*128 + i*16 + lhi*4 + q;
        size_t idx = (size_t)row*ldc + col;
        float v = acc[i][j][q] + bv;
        if constexpr (EPI == 4){
          float a0v = bf2f(aux[idx]);
          v = a0v / (1.f + __expf(-a0v)) * v;
        }
        ((u16*)Cout)[idx] = f2bf(v);
      }
    }
  }
}

// ---- 128x128 GEMM (3-buffer counted vmcnt, row&3 chunk swizzle) ----
template<int EPI>
__global__ __launch_bounds__(256) void k_gemm_bt(
    const u16* __restrict__ A, const u16* __restrict__ Bt,
    const float* __restrict__ bias, const float* __restrict__ res,
    const u16* __restrict__ aux,
    void* __restrict__ Cout, int M, int N, int K,
    int lda, int ldb, int ldc)
{
  __shared__ __align__(16) u16 As[3][128*32];
  __shared__ __align__(16) u16 Bs[3][128*32];
  int tid = threadIdx.x;

  int nwg = gridDim.x, wg = blockIdx.x;
  int qq = nwg >> 3, rr = nwg & 7;
  int xcd = wg & 7, sub = wg >> 3;
  int swz = (xcd < rr ? xcd*(qq+1) : rr*(qq+1) + (xcd-rr)*qq) + sub;
  int nbx = N >> 7;
  int m0 = (swz / nbx) << 7, n0 = (swz % nbx) << 7;

  int lane = tid & 63, wave = tid >> 6;
  int wr = wave >> 1, wc = wave & 1;
  int lrow = lane & 15, lhi = lane >> 4;
  f32x4 acc[4][4] = {};
  int srow = tid >> 2;                 // LDS row this thread stages
  int schk = tid & 3;                  // dest 16B-chunk (linear)
  const int nk = K >> 5;

  auto stage = [&](int slot, int kt){
    int k0 = kt << 5;
    int c = schk ^ (srow & 3);         // pre-swizzled source chunk
    #pragma unroll
    for (int cc = 0; cc < 2; ++cc){
      int r = cc*64 + srow;
      __builtin_amdgcn_global_load_lds(
        (const AS1 void*)(A + (size_t)(m0 + r)*lda + k0 + c*8),
        (AS3 void*)(&As[slot][r*32 + schk*8]), 16, 0, 0);
      __builtin_amdgcn_global_load_lds(
        (const AS1 void*)(Bt + (size_t)(n0 + r)*ldb + k0 + c*8),
        (AS3 void*)(&Bs[slot][r*32 + schk*8]), 16, 0, 0);
    }
  };

  stage(0, 0);
  if (nk > 1) stage(1, 1);
  if (nk > 1) asm volatile("s_waitcnt vmcnt(4)" ::: "memory");
  else        asm volatile("s_waitcnt vmcnt(0)" ::: "memory");
  __builtin_amdgcn_s_barrier();

  for (int kt = 0; kt < nk; ++kt){
    int cur = kt % 3;
    if (kt + 2 < nk) stage((kt + 2) % 3, kt + 2);
    int rchk = lhi ^ (lrow & 3);       // swizzled read chunk (row&3 == lrow&3)
    bf16x8 af[4], bfv[4];
    #pragma unroll
    for (int i = 0; i < 4; ++i){
      af[i]  = *(const bf16x8*)(&As[cur][(wr*64 + i*16 + lrow)*32 + rchk*8]);
      bfv[i] = *(const bf16x8*)(&Bs[cur][(wc*64 + i*16 + lrow)*32 + rchk*8]);
    }
    #pragma unroll
    for (int i = 0; i < 4; ++i)
      #pragma unroll
      for (int j = 0; j < 4; ++j)
        acc[i][j] = __builtin_amdgcn_mfma_f32_16x16x32_bf16(af[i], bfv[j], acc[i][j], 0, 0, 0);
    if (kt + 2 < nk) asm volatile("s_waitcnt vmcnt(4)" ::: "memory");
    else             asm volatile("s_waitcnt vmcnt(0)" ::: "memory");
    __builtin_amdgcn_s_barrier();
  }

  #pragma unroll
  for (int i = 0; i < 4; ++i){
    #pragma unroll
    for (int j = 0; j < 4; ++j){
      int col = n0 + wc*64 + j*16 + lrow;
      float bv = 0.f;
      if constexpr (EPI == 0 || EPI == 1) bv = bias[col];
      #pragma unroll
      for (int q = 0; q < 4; ++q){
        int row = m0 + wr*64 + i*16 + lhi*4 + q;
        size_t idx = (size_t)row*ldc + col;
        float v = acc[i][j][q] + bv;
        if constexpr (EPI == 1 || EPI == 3) v += res[idx];
        if constexpr (EPI == 4){
          float a0 = bf2f(aux[idx]);
          v = a0 / (1.f + __expf(-a0)) * v;
        }
        if constexpr (EPI == 0 || EPI == 2 || EPI == 4) ((u16*)Cout)[idx] = f2bf(v);
        else ((float*)Cout)[idx] = v;
      }
    }
  }
}

// ---- causal flash attention: paired-qblock load balancing (unchanged) ----
__global__ __launch_bounds__(512) void k_attn(
    const u16* __restrict__ Q, const u16* __restrict__ Kb,
    const u16* __restrict__ Vt, u16* __restrict__ O, int ldq)
{
  int tid = threadIdx.x, lane = tid & 63, wave = tid >> 6;  // 8 waves
  int lrow = lane & 15, lhi = lane >> 4;
  int bidx = blockIdx.x;
  int bh = bidx >> 3, j = bidx & 7;
  int b = bh >> 4, h = bh & 15;

  __shared__ __align__(16) u16 Kbuf[2][64*128];   // 32 KB
  __shared__ __align__(16) u16 Vbuf[2][128*64];   // 32 KB
  __shared__ __align__(16) u16 P_lds[8][16*64];   // 16 KB
  char* pw = (char*)&P_lds[wave][0];
  const float sc2 = 0.08838834764831845f * 1.44269504088896340736f;

  auto stage = [&](int bufi, int kt){
    int kv0 = kt << 6;
    char* kd = (char*)&Kbuf[bufi][0];
    char* vd = (char*)&Vbuf[bufi][0];
    #pragma unroll
    for (int L = 0; L < 2; ++L){
      int cid = wave*128 + L*64 + lane;
      int r = cid >> 4, c = cid & 15;
      int cg = c ^ (r & 7);
      __builtin_amdgcn_global_load_lds(
        (const AS1 void*)(Kb + (size_t)(b*SS + kv0 + r)*ldq + h*DK + cg*8),
        (AS3 void*)(kd + wave*2048 + L*1024 + lane*16), 16, 0, 0);
      int dd = cid >> 3, c8 = cid & 7;
      int cv = c8 ^ (dd & 7);
      __builtin_amdgcn_global_load_lds(
        (const AS1 void*)(Vt + (size_t)bh*DK*SS + (size_t)dd*SS + kv0 + cv*8),
        (AS3 void*)(vd + wave*2048 + L*1024 + lane*16), 16, 0, 0);
    }
  };

  #pragma unroll 1
  for (int item = 0; item < 2; ++item){
    int qi = item == 0 ? 15 - j : j;
    int qs = qi * 128;
    int nt = 2*qi + 2;
    int qrow = qs + wave * 16;

    bf16x8 qf[4];
    const u16* qbase = Q + (size_t)(b*SS + qrow + lrow)*ldq + h*DK + lhi*8;
    #pragma unroll
    for (int dc = 0; dc < 4; ++dc) qf[dc] = *(const bf16x8*)(qbase + dc*32);

    f32x4 accO[8] = {};
    float mr[4] = {-1e30f,-1e30f,-1e30f,-1e30f};
    float lr[4] = {0.f,0.f,0.f,0.f};

    stage(0, 0);
    __syncthreads();

    for (int kt = 0; kt < nt; ++kt){
      int cur = kt & 1;
      if (kt + 1 < nt) stage(cur ^ 1, kt + 1);
      int kv0 = kt << 6;
      if (kv0 <= qrow + 15){
        const char* kl = (const char*)&Kbuf[cur][0];
        const char* vl = (const char*)&Vbuf[cur][0];
        bool domask = (kv0 + 63 > qrow);

        f32x4 sf[4];
        #pragma unroll
        for (int hf = 0; hf < 4; ++hf){
          int rl = hf*16 + lrow;
          int sw = rl & 7;
          f32x4 a = {};
          #pragma unroll
          for (int dc = 0; dc < 4; ++dc){
            bf16x8 kf = *(const bf16x8*)(kl + rl*256 + (((lhi + dc*4) ^ sw) << 4));
            a = __builtin_amdgcn_mfma_f32_16x16x32_bf16(qf[dc], kf, a, 0, 0, 0);
          }
          sf[hf] = a;
        }

        float p[4][4], mx[4];
        #pragma unroll
        for (int q = 0; q < 4; ++q){
          float s0 = sf[0][q]*sc2, s1 = sf[1][q]*sc2, s2 = sf[2][q]*sc2, s3 = sf[3][q]*sc2;
          if (domask){
            int qg = qrow + lhi*4 + q;
            if (kv0      + lrow > qg) s0 = -1e30f;
            if (kv0 + 16 + lrow > qg) s1 = -1e30f;
            if (kv0 + 32 + lrow > qg) s2 = -1e30f;
            if (kv0 + 48 + lrow > qg) s3 = -1e30f;
          }
          p[q][0]=s0; p[q][1]=s1; p[q][2]=s2; p[q][3]=s3;
          float m = fmaxf(fmaxf(s0,s1), fmaxf(s2,s3));
          m = fmaxf(m, __shfl_xor(m, 1, 64));
          m = fmaxf(m, __shfl_xor(m, 2, 64));
          m = fmaxf(m, __shfl_xor(m, 4, 64));
          m = fmaxf(m, __shfl_xor(m, 8, 64));
          mx[q] = m;
        }
        float dmax = fmaxf(fmaxf(mx[0]-mr[0], mx[1]-mr[1]), fmaxf(mx[2]-mr[2], mx[3]-mr[3]));
        bool rescale = !__all(dmax <= 8.0f);
        float al[4];
        #pragma unroll
        for (int q = 0; q < 4; ++q){
          if (rescale){
            float mn = fmaxf(mr[q], mx[q]);
            al[q] = fexp2(mr[q] - mn);
            mr[q] = mn;
          } else al[q] = 1.0f;
          p[q][0] = fexp2(p[q][0] - mr[q]);
          p[q][1] = fexp2(p[q][1] - mr[q]);
          p[q][2] = fexp2(p[q][2] - mr[q]);
          p[q][3] = fexp2(p[q][3] - mr[q]);
          float sm = (p[q][0] + p[q][1]) + (p[q][2] + p[q][3]);
          sm += __shfl_xor(sm, 1, 64);
          sm += __shfl_xor(sm, 2, 64);
          sm += __shfl_xor(sm, 4, 64);
          sm += __shfl_xor(sm, 8, 64);
          lr[q] = lr[q]*al[q] + sm;
        }
        if (rescale){
          #pragma unroll
          for (int f = 0; f < 8; ++f)
            #pragma unroll
            for (int q = 0; q < 4; ++q) accO[f][q] *= al[q];
        }

        #pragma unroll
        for (int q = 0; q < 4; ++q){
          int row = lhi*4 + q;
          int rb = row*128, sw = (row & 7) << 4;
          #pragma unroll
          for (int hf = 0; hf < 4; ++hf)
            *(u16*)(pw + rb + ((hf*32 + lrow*2) ^ sw)) = cvt_bf16(p[q][hf]);
        }
        __builtin_amdgcn_sched_barrier(0);
        int rsw = (lrow & 7) << 4;
        bf16x8 pa0 = *(const bf16x8*)(pw + lrow*128 + ((     lhi*16) ^ rsw));
        bf16x8 pa1 = *(const bf16x8*)(pw + lrow*128 + ((64 + lhi*16) ^ rsw));

        #pragma unroll
        for (int f = 0; f < 8; ++f){
          int d = f*16 + lrow;
          int swv = d & 7;
          bf16x8 v0 = *(const bf16x8*)(vl + d*128 + (((lhi    ) ^ swv) << 4));
          bf16x8 v1 = *(const bf16x8*)(vl + d*128 + (((lhi + 4) ^ swv) << 4));
          accO[f] = __builtin_amdgcn_mfma_f32_16x16x32_bf16(pa0, v0, accO[f], 0, 0, 0);
          accO[f] = __builtin_amdgcn_mfma_f32_16x16x32_bf16(pa1, v1, accO[f], 0, 0, 0);
        }
      }
      __syncthreads();
    }

    #pragma unroll
    for (int q = 0; q < 4; ++q){
      float inv = 1.0f / lr[q];
      #pragma unroll
      for (int f = 0; f < 8; ++f){
        int row = b*SS + qrow + lhi*4 + q;
        int col = h*DK + f*16 + lrow;
        O[(size_t)row*D_MODEL + col] = cvt_bf16(accO[f][q] * inv);
      }
    }
    __syncthreads();
  }
}

extern "C" void kernel_launch(void* const* d_in, const int* in_sizes, int n_in,
                              void* d_out, int out_size, void* d_ws, size_t ws_size,
                              hipStream_t stream)
{
  (void)in_sizes; (void)n_in; (void)out_size;
  const float* x  = (const float*)d_in[0];
  const float* wq = (const float*)d_in[2];
  const float* bq = (const float*)d_in[3];
  const float* wk = (const float*)d_in[4];
  const float* bk = (const float*)d_in[5];
  const float* wv = (const float*)d_in[6];
  const float* bv = (const float*)d_in[7];
  const float* wo = (const float*)d_in[8];
  const float* bo = (const float*)d_in[9];
  const float* g1 = (const float*)d_in[10];
  const float* g2 = (const float*)d_in[11];
  const float* w1 = (const float*)d_in[12];
  const float* w3 = (const float*)d_in[13];  // w3 precedes w2 in dict order
  const float* w2 = (const float*)d_in[14];
  float* out = (float*)d_out;

  const size_t MB = 1u << 20;
  const size_t WFF2 = (size_t)D_MODEL * DFF * sizeof(u16);
  const size_t NEED = 112*MB + WFF2 + 32768;
  if (ws_size < NEED) return;
  char* ws = (char*)d_ws;
  u16* bufA = (u16*)(ws + 0);        // 16 MiB: nbf1 -> aob -> nbf2
  u16* qkv  = (u16*)(ws + 16*MB);    // 48 MiB fused QKV [4096][6144]
  u16* h1   = qkv;                   // [4096][5632], aliases qkv after attn
  u16* wqkvt= (u16*)(ws + 64*MB);    // 24 MiB: wq^T|wk^T|wv^T [6144][2048]
  u16* w1t  = wqkvt;                 // [5632][2048], aliases after QKV GEMM
  u16* wot  = (u16*)(ws + 88*MB);    // 8 MiB
  u16* w3t  = (u16*)(ws + 88*MB);    // [5632][2048], aliases wot+vtb after O-proj
  u16* vtb  = (u16*)(ws + 96*MB);    // 16 MiB
  u16* w2t  = (u16*)(ws + 112*MB);   // [2048][5504]
  float* bqkv = (float*)(ws + 112*MB + WFF2);
  // fp32 residual x1 lives in d_out

  bool big = true;
  big &= hipFuncSetAttribute((const void*)k_gemm8p<0>, hipFuncAttributeMaxDynamicSharedMemorySize, 131072) == hipSuccess;
  big &= hipFuncSetAttribute((const void*)k_gemm8p<2>, hipFuncAttributeMaxDynamicSharedMemorySize, 131072) == hipSuccess;
  big &= hipFuncSetAttribute((const void*)k_gemm8p<4>, hipFuncAttributeMaxDynamicSharedMemorySize, 131072) == hipSuccess;

  dim3 tb(32, 8);
  k_transpose_w<<<dim3(64,64), tb, 0, stream>>>(wq, wqkvt,               D_MODEL, D_MODEL);
  k_transpose_w<<<dim3(64,64), tb, 0, stream>>>(wk, wqkvt + 2048*2048,   D_MODEL, D_MODEL);
  k_transpose_w<<<dim3(64,64), tb, 0, stream>>>(wv, wqkvt + 2*2048*2048, D_MODEL, D_MODEL);
  k_transpose_w<<<dim3(64,64), tb, 0, stream>>>(wo, wot, D_MODEL, D_MODEL);
  k_transpose_w<<<dim3(64, DFF/32), tb, 0, stream>>>(w2, w2t, DFF, D_MODEL);
  k_concat3<<<24, 256, 0, stream>>>(bq, bk, bv, bqkv);

  k_rmsnorm<<<MTOK, 256, 0, stream>>>(x, g1, bufA);
  if (big)
    k_gemm8p<0><<<(MTOK/256)*(DQKV/256), 512, 131072, stream>>>(bufA, wqkvt, bqkv, nullptr, qkv, MTOK, DQKV, D_MODEL, D_MODEL, D_MODEL, DQKV);
  else
    k_gemm_bt<0><<<(DQKV/128)*(MTOK/128), 256, 0, stream>>>(bufA, wqkvt, bqkv, nullptr, nullptr, qkv, MTOK, DQKV, D_MODEL, D_MODEL, D_MODEL, DQKV);
  k_transpose_v<<<dim3(SS/32, 128), tb, 0, stream>>>(qkv + 4096, vtb, DQKV);
  k_attn<<<dim3(BB*NHEADS*8), 512, 0, stream>>>(qkv, qkv + 2048, vtb, bufA, DQKV);
  k_transpose_w<<<dim3(DFFP/32, 64), tb, 0, stream>>>(w1, w1t, D_MODEL, DFF);
  k_gemm_bt<1><<<16*32, 256, 0, stream>>>(bufA, wot, bo, x, nullptr, out, MTOK, D_MODEL, D_MODEL, D_MODEL, D_MODEL, D_MODEL);
  k_transpose_w<<<dim3(DFFP/32, 64), tb, 0, stream>>>(w3, w3t, D_MODEL, DFF);
  k_rmsnorm<<<MTOK, 256, 0, stream>>>(out, g2, bufA);
  if (big){
    k_gemm8p<2><<<(MTOK/256)*(DFFP/256), 512, 131072, stream>>>(bufA, w1t, nullptr, nullptr, h1, MTOK, DFFP, D_MODEL, D_MODEL, D_MODEL, DFFP);
    k_gemm8p<4><<<(MTOK/256)*(DFFP/256), 512, 131072, stream>>>(bufA, w3t, nullptr, h1, h1, MTOK, DFFP, D_MODEL, D_MODEL, D_MODEL, DFFP);
  } else {
    k_gemm_bt<2><<<(DFFP/128)*32, 256, 0, stream>>>(bufA, w1t, nullptr, nullptr, nullptr, h1, MTOK, DFFP, D_MODEL, D_MODEL, D_MODEL, DFFP);
    k_gemm_bt<4><<<(DFFP/128)*32, 256, 0, stream>>>(bufA, w3t, nullptr, nullptr, h1, h1, MTOK, DFFP, D_MODEL, D_MODEL, D_MODEL, DFFP);
  }
  k_gemm_bt<3><<<16*32, 256, 0, stream>>>(h1, w2t, nullptr, out, nullptr, out, MTOK, D_MODEL, DFF, DFFP, DFF, D_MODEL);
}

// Round 11
// 721.821 us; speedup vs baseline: 1.1961x; 1.0192x over previous
//
#include <hip/hip_runtime.h>
#include <stdint.h>

typedef unsigned short u16;
typedef __bf16 bf16x8 __attribute__((ext_vector_type(8)));
typedef float f32x4 __attribute__((ext_vector_type(4)));

#define D_MODEL 2048
#define NHEADS 16
#define DK 128
#define DFF 5504
#define DFFP 5632   // DFF padded to 256 multiple
#define BB 2
#define SS 2048
#define MTOK 4096
#define DQKV 6144

#define AS1 __attribute__((address_space(1)))
#define AS3 __attribute__((address_space(3)))

__device__ __forceinline__ u16 f2bf(float f){
  union { float f; uint32_t u; } v; v.f = f;
  uint32_t r = v.u + 0x7fffu + ((v.u >> 16) & 1u);
  return (u16)(r >> 16);
}
__device__ __forceinline__ float bf2f(u16 u){
  union { uint32_t u; float f; } v; v.u = ((uint32_t)u) << 16;
  return v.f;
}
__device__ __forceinline__ u16 cvt_bf16(float f){
  union { __bf16 h; u16 u; } v; v.h = (__bf16)f; return v.u;
}
__device__ __forceinline__ float fexp2(float x){
#if __has_builtin(__builtin_amdgcn_exp2f)
  return __builtin_amdgcn_exp2f(x);
#else
  return exp2f(x);
#endif
}

// ---- fp32 W[K][Nsrc] -> bf16 Wt[n][K], zero-fill n >= Nsrc ----
__global__ __launch_bounds__(256) void k_transpose_w(const float* __restrict__ W,
                                                     u16* __restrict__ Wt, int K, int Nsrc){
  __shared__ float tile[32][33];
  int n0 = blockIdx.x * 32, k0 = blockIdx.y * 32;
  int tx = threadIdx.x, ty = threadIdx.y;  // (32,8)
  #pragma unroll
  for (int r = 0; r < 4; ++r){
    int n = n0 + tx;
    tile[ty + r*8][tx] = (n < Nsrc) ? W[(size_t)(k0 + ty + r*8) * Nsrc + n] : 0.0f;
  }
  __syncthreads();
  #pragma unroll
  for (int r = 0; r < 4; ++r)
    Wt[(size_t)(n0 + ty + r*8) * K + k0 + tx] = f2bf(tile[tx][ty + r*8]);
}

// ---- per-head V transpose from fused QKV ----
__global__ __launch_bounds__(256) void k_transpose_v(const u16* __restrict__ V,
                                                     u16* __restrict__ Vt, int ld){
  __shared__ u16 tile[32][33];
  int s0 = blockIdx.x * 32;
  int bh = blockIdx.y >> 2, dt = blockIdx.y & 3;
  int b = bh >> 4, h = bh & 15;
  int tx = threadIdx.x, ty = threadIdx.y;
  #pragma unroll
  for (int r = 0; r < 4; ++r)
    tile[ty + r*8][tx] = V[(size_t)(b*SS + s0 + ty + r*8) * ld + h*DK + dt*32 + tx];
  __syncthreads();
  #pragma unroll
  for (int r = 0; r < 4; ++r)
    Vt[(size_t)(bh*DK + dt*32 + ty + r*8) * SS + s0 + tx] = tile[tx][ty + r*8];
}

__global__ __launch_bounds__(256) void k_concat3(const float* __restrict__ a,
                                                 const float* __restrict__ b,
                                                 const float* __restrict__ c,
                                                 float* __restrict__ o){
  int i = blockIdx.x*256 + threadIdx.x;
  if (i >= DQKV) return;
  o[i] = (i < 2048) ? a[i] : (i < 4096 ? b[i-2048] : c[i-4096]);
}

// ---- RMSNorm: fp32 row -> bf16 row ----
__global__ __launch_bounds__(256) void k_rmsnorm(const float* __restrict__ X,
                                                 const float* __restrict__ g,
                                                 u16* __restrict__ out){
  int row = blockIdx.x, tid = threadIdx.x;
  const float* x = X + (size_t)row * D_MODEL;
  float4 a = ((const float4*)x)[tid*2];
  float4 b = ((const float4*)x)[tid*2+1];
  float ss = a.x*a.x + a.y*a.y + a.z*a.z + a.w*a.w
           + b.x*b.x + b.y*b.y + b.z*b.z + b.w*b.w;
  #pragma unroll
  for (int m = 1; m < 64; m <<= 1) ss += __shfl_xor(ss, m, 64);
  __shared__ float red[4];
  if ((tid & 63) == 0) red[tid >> 6] = ss;
  __syncthreads();
  float tot = red[0] + red[1] + red[2] + red[3];
  float sc = rsqrtf(tot * (1.0f / D_MODEL) + 1e-6f);
  float4 ga = ((const float4*)g)[tid*2];
  float4 gb = ((const float4*)g)[tid*2+1];
  uint32_t w0 = f2bf(a.x*sc*ga.x) | ((uint32_t)f2bf(a.y*sc*ga.y) << 16);
  uint32_t w1 = f2bf(a.z*sc*ga.z) | ((uint32_t)f2bf(a.w*sc*ga.w) << 16);
  uint32_t w2 = f2bf(b.x*sc*gb.x) | ((uint32_t)f2bf(b.y*sc*gb.y) << 16);
  uint32_t w3 = f2bf(b.z*sc*gb.z) | ((uint32_t)f2bf(b.w*sc*gb.w) << 16);
  ((uint4*)(out + (size_t)row * D_MODEL))[tid] = make_uint4(w0, w1, w2, w3);
}

// ---- hg = silu(h1) * h3 (bf16, 8 elems/thread) ----
__global__ __launch_bounds__(256) void k_silu_mul(const u16* __restrict__ a,
                                                  const u16* __restrict__ b,
                                                  u16* __restrict__ o, int n8){
  int i = blockIdx.x * 256 + threadIdx.x;
  if (i >= n8) return;
  uint4 av = ((const uint4*)a)[i];
  uint4 bv = ((const uint4*)b)[i];
  uint32_t aa[4] = {av.x, av.y, av.z, av.w};
  uint32_t bb[4] = {bv.x, bv.y, bv.z, bv.w};
  uint32_t rr[4];
  #pragma unroll
  for (int j = 0; j < 4; ++j){
    float x0 = bf2f((u16)(aa[j] & 0xffff)), x1 = bf2f((u16)(aa[j] >> 16));
    float y0 = bf2f((u16)(bb[j] & 0xffff)), y1 = bf2f((u16)(bb[j] >> 16));
    float r0 = x0 / (1.f + __expf(-x0)) * y0;
    float r1 = x1 / (1.f + __expf(-x1)) * y1;
    rr[j] = f2bf(r0) | ((uint32_t)f2bf(r1) << 16);
  }
  ((uint4*)o)[i] = make_uint4(rr[0], rr[1], rr[2], rr[3]);
}

// ============ 256x256 8-wave GEMM — 8-phase, 2-barrier, 2D-XCD-patch ============
// row&7 chunk swizzle both-sides (conflict-free, verified r10).
// EPI 0: bf16 +bias; EPI 2: bf16; EPI 5: dual bf16 out (n0<5632 -> Cout, else aux-5632)
template<int EPI>
__global__ __launch_bounds__(512, 2) void k_gemm8p(
    const u16* __restrict__ A, const u16* __restrict__ Bt,
    const float* __restrict__ bias, const u16* __restrict__ aux,
    void* __restrict__ Cout, int M, int N, int K,
    int lda, int ldb, int ldc)
{
  extern __shared__ __align__(16) char smem[];
  const int tid = threadIdx.x;
  const int lane = tid & 63, wid = tid >> 6;
  const int wr = wid >> 2, wc = wid & 3;        // 2M x 4N waves
  const int lrow = lane & 15, lhi = lane >> 4;

  // XCD mapping: 2D patch (2 M-halves x 4 N-quads) when divisible; else m204 1D.
  int nwg = gridDim.x, wg = blockIdx.x;
  int nbx = N >> 8, nbm = M >> 8;
  int xcd = wg & 7, sub = wg >> 3;
  int m0, n0;
  if ((nwg & 7) == 0 && (nbm & 1) == 0 && (nbx & 3) == 0){
    int mh = nbm >> 1;
    int mr = sub % mh, nc = sub / mh;           // consecutive sub share B-tile
    m0 = (((xcd & 1) * mh) + mr) << 8;
    n0 = (((xcd >> 1) * (nbx >> 2)) + nc) << 8;
  } else {
    int qq = nwg >> 3, rr2 = nwg & 7;
    int swz = (xcd < rr2 ? xcd*(qq+1) : rr2*(qq+1) + (xcd-rr2)*qq) + sub;
    m0 = (swz / nbx) << 8; n0 = (swz % nbx) << 8;
  }

  const int nk = K >> 6;                         // BK = 64
  const int hA = wr, hB = wc >> 1;
  const int gA = wc;
  const int gB = (wr << 1) | (wc & 1);

  auto stA = [&](int d, int kk, int q){
    #pragma unroll
    for (int L = 0; L < 2; ++L){
      int p = q*8192 + gA*2048 + L*1024 + lane*16;   // physical (linear dest)
      int row = p >> 7;
      int o = (p & 127) ^ ((row & 7) << 4);          // logical in-row byte
      __builtin_amdgcn_global_load_lds(
        (const AS1 void*)(A + (size_t)(m0 + hA*128 + row)*lda + kk + (o >> 1)),
        (AS3 void*)(smem + d*65536 + hA*16384 + p), 16, 0, 0);
    }
  };
  auto stB = [&](int d, int kk, int s){
    #pragma unroll
    for (int L = 0; L < 2; ++L){
      int p = s*4096 + (gB >> 1)*8192 + (gB & 1)*2048 + L*1024 + lane*16;
      int row = p >> 7;
      int o = (p & 127) ^ ((row & 7) << 4);
      __builtin_amdgcn_global_load_lds(
        (const AS1 void*)(Bt + (size_t)(n0 + hB*128 + row)*ldb + kk + (o >> 1)),
        (AS3 void*)(smem + d*65536 + 32768 + hB*16384 + p), 16, 0, 0);
    }
  };
  auto rdA = [&](int d, int rloc, int ks)->bf16x8{
    int p = rloc*128 + ((ks*64 + lhi*16) ^ ((rloc & 7) << 4));
    return *(const bf16x8*)(smem + d*65536 + hA*16384 + p);
  };
  auto rdB = [&](int d, int rloc, int ks)->bf16x8{
    int p = rloc*128 + ((ks*64 + lhi*16) ^ ((rloc & 7) << 4));
    return *(const bf16x8*)(smem + d*65536 + 32768 + hB*16384 + p);
  };

  f32x4 acc[8][4] = {};

  stA(0, 0, 0); stB(0, 0, 0); stB(0, 0, 1); stA(0, 0, 1);
  asm volatile("s_waitcnt vmcnt(0)" ::: "memory");
  __builtin_amdgcn_s_barrier();

  for (int t = 0; t < nk; ++t){
    int d = t & 1, dn = d ^ 1, kkn = (t + 1) << 6;
    bool pf = (t + 1 < nk);
    bf16x8 aR[8], bQ0[4], bQ1[4];

    // ---- phase 0: Q00 (reads A q0: 8, B own q0: 4; stage A-q0 + B-s0 of t+1) ----
    #pragma unroll
    for (int ii = 0; ii < 4; ++ii){
      aR[ii*2]   = rdA(d, ii*16 + lrow, 0);
      aR[ii*2+1] = rdA(d, ii*16 + lrow, 1);
    }
    #pragma unroll
    for (int j = 0; j < 2; ++j){
      bQ0[j*2]   = rdB(d, (wc&1)*64 + j*16 + lrow, 0);
      bQ0[j*2+1] = rdB(d, (wc&1)*64 + j*16 + lrow, 1);
    }
    if (pf){ stA(dn, kkn, 0); stB(dn, kkn, 0); }
    __builtin_amdgcn_s_barrier();                     // barrier 1: all issued
    asm volatile("s_waitcnt lgkmcnt(0)" ::: "memory");
    __builtin_amdgcn_sched_barrier(0);
    __builtin_amdgcn_s_setprio(1);
    #pragma unroll
    for (int ii = 0; ii < 4; ++ii)
      #pragma unroll
      for (int j = 0; j < 2; ++j){
        acc[ii][j] = __builtin_amdgcn_mfma_f32_16x16x32_bf16(aR[ii*2],   bQ0[j*2],   acc[ii][j], 0, 0, 0);
        acc[ii][j] = __builtin_amdgcn_mfma_f32_16x16x32_bf16(aR[ii*2+1], bQ0[j*2+1], acc[ii][j], 0, 0, 0);
      }
    __builtin_amdgcn_s_setprio(0);
    if (pf) asm volatile("s_waitcnt vmcnt(6)" ::: "memory");
    else    asm volatile("s_waitcnt vmcnt(2)" ::: "memory");
    __builtin_amdgcn_sched_barrier(0);
    __builtin_amdgcn_s_barrier();                     // barrier 2

    // ---- phase 1: Q01 (reads B own q1: 4; stage B-s1 of t+1; reuse aR) ----
    #pragma unroll
    for (int j = 0; j < 2; ++j){
      bQ1[j*2]   = rdB(d, (wc&1)*64 + 32 + j*16 + lrow, 0);
      bQ1[j*2+1] = rdB(d, (wc&1)*64 + 32 + j*16 + lrow, 1);
    }
    if (pf) stB(dn, kkn, 1);
    __builtin_amdgcn_s_barrier();
    asm volatile("s_waitcnt lgkmcnt(0)" ::: "memory");
    __builtin_amdgcn_sched_barrier(0);
    __builtin_amdgcn_s_setprio(1);
    #pragma unroll
    for (int ii = 0; ii < 4; ++ii)
      #pragma unroll
      for (int j = 0; j < 2; ++j){
        acc[ii][2+j] = __builtin_amdgcn_mfma_f32_16x16x32_bf16(aR[ii*2],   bQ1[j*2],   acc[ii][2+j], 0, 0, 0);
        acc[ii][2+j] = __builtin_amdgcn_mfma_f32_16x16x32_bf16(aR[ii*2+1], bQ1[j*2+1], acc[ii][2+j], 0, 0, 0);
      }
    __builtin_amdgcn_s_setprio(0);
    if (pf) asm volatile("s_waitcnt vmcnt(6)" ::: "memory");
    else    asm volatile("s_waitcnt vmcnt(0)" ::: "memory");
    __builtin_amdgcn_sched_barrier(0);
    __builtin_amdgcn_s_barrier();

    // ---- phase 2: Q11 (reads A q1: 8; stage A-q1 of t+1; reuse bQ1) ----
    #pragma unroll
    for (int ii = 0; ii < 4; ++ii){
      aR[ii*2]   = rdA(d, 64 + ii*16 + lrow, 0);
      aR[ii*2+1] = rdA(d, 64 + ii*16 + lrow, 1);
    }
    if (pf) stA(dn, kkn, 1);
    __builtin_amdgcn_s_barrier();
    asm volatile("s_waitcnt lgkmcnt(0)" ::: "memory");
    __builtin_amdgcn_sched_barrier(0);
    __builtin_amdgcn_s_setprio(1);
    #pragma unroll
    for (int ii = 0; ii < 4; ++ii)
      #pragma unroll
      for (int j = 0; j < 2; ++j){
        acc[4+ii][2+j] = __builtin_amdgcn_mfma_f32_16x16x32_bf16(aR[ii*2],   bQ1[j*2],   acc[4+ii][2+j], 0, 0, 0);
        acc[4+ii][2+j] = __builtin_amdgcn_mfma_f32_16x16x32_bf16(aR[ii*2+1], bQ1[j*2+1], acc[4+ii][2+j], 0, 0, 0);
      }
    __builtin_amdgcn_s_setprio(0);
    __builtin_amdgcn_s_barrier();

    // ---- phase 3: Q10 (no reads; reuse aR + bQ0) ----
    __builtin_amdgcn_s_setprio(1);
    #pragma unroll
    for (int ii = 0; ii < 4; ++ii)
      #pragma unroll
      for (int j = 0; j < 2; ++j){
        acc[4+ii][j] = __builtin_amdgcn_mfma_f32_16x16x32_bf16(aR[ii*2],   bQ0[j*2],   acc[4+ii][j], 0, 0, 0);
        acc[4+ii][j] = __builtin_amdgcn_mfma_f32_16x16x32_bf16(aR[ii*2+1], bQ0[j*2+1], acc[4+ii][j], 0, 0, 0);
      }
    __builtin_amdgcn_s_setprio(0);
    if (pf) asm volatile("s_waitcnt vmcnt(4)" ::: "memory");
    __builtin_amdgcn_sched_barrier(0);
    __builtin_amdgcn_s_barrier();
  }

  // epilogue
  u16* Cw = (u16*)Cout;
  int cofs = 0;
  if constexpr (EPI == 5){
    if (n0 >= 5632){ Cw = (u16*)aux; cofs = 5632; }
  }
  #pragma unroll
  for (int i = 0; i < 8; ++i){
    #pragma unroll
    for (int j = 0; j < 4; ++j){
      int col = n0 + wc*64 + j*16 + lrow;
      float bv = 0.f;
      if constexpr (EPI == 0) bv = bias[col];
      #pragma unroll
      for (int q = 0; q < 4; ++q){
        int row = m0 + wr*128 + i*16 + lhi*4 + q;
        float v = acc[i][j][q] + bv;
        Cw[(size_t)row*ldc + (col - cofs)] = f2bf(v);
      }
    }
  }
}

// ---- 128x128 GEMM (3-buffer counted vmcnt, row&3 chunk swizzle) ----
template<int EPI>
__global__ __launch_bounds__(256) void k_gemm_bt(
    const u16* __restrict__ A, const u16* __restrict__ Bt,
    const float* __restrict__ bias, const float* __restrict__ res,
    const u16* __restrict__ aux,
    void* __restrict__ Cout, int M, int N, int K,
    int lda, int ldb, int ldc)
{
  __shared__ __align__(16) u16 As[3][128*32];
  __shared__ __align__(16) u16 Bs[3][128*32];
  int tid = threadIdx.x;

  int nwg = gridDim.x, wg = blockIdx.x;
  int qq = nwg >> 3, rr = nwg & 7;
  int xcd = wg & 7, sub = wg >> 3;
  int swz = (xcd < rr ? xcd*(qq+1) : rr*(qq+1) + (xcd-rr)*qq) + sub;
  int nbx = N >> 7;
  int m0 = (swz / nbx) << 7, n0 = (swz % nbx) << 7;

  int lane = tid & 63, wave = tid >> 6;
  int wr = wave >> 1, wc = wave & 1;
  int lrow = lane & 15, lhi = lane >> 4;
  f32x4 acc[4][4] = {};
  int srow = tid >> 2;
  int schk = tid & 3;
  const int nk = K >> 5;

  auto stage = [&](int slot, int kt){
    int k0 = kt << 5;
    int c = schk ^ (srow & 3);
    #pragma unroll
    for (int cc = 0; cc < 2; ++cc){
      int r = cc*64 + srow;
      __builtin_amdgcn_global_load_lds(
        (const AS1 void*)(A + (size_t)(m0 + r)*lda + k0 + c*8),
        (AS3 void*)(&As[slot][r*32 + schk*8]), 16, 0, 0);
      __builtin_amdgcn_global_load_lds(
        (const AS1 void*)(Bt + (size_t)(n0 + r)*ldb + k0 + c*8),
        (AS3 void*)(&Bs[slot][r*32 + schk*8]), 16, 0, 0);
    }
  };

  stage(0, 0);
  if (nk > 1) stage(1, 1);
  if (nk > 1) asm volatile("s_waitcnt vmcnt(4)" ::: "memory");
  else        asm volatile("s_waitcnt vmcnt(0)" ::: "memory");
  __builtin_amdgcn_s_barrier();

  for (int kt = 0; kt < nk; ++kt){
    int cur = kt % 3;
    if (kt + 2 < nk) stage((kt + 2) % 3, kt + 2);
    int rchk = lhi ^ (lrow & 3);
    bf16x8 af[4], bfv[4];
    #pragma unroll
    for (int i = 0; i < 4; ++i){
      af[i]  = *(const bf16x8*)(&As[cur][(wr*64 + i*16 + lrow)*32 + rchk*8]);
      bfv[i] = *(const bf16x8*)(&Bs[cur][(wc*64 + i*16 + lrow)*32 + rchk*8]);
    }
    #pragma unroll
    for (int i = 0; i < 4; ++i)
      #pragma unroll
      for (int j = 0; j < 4; ++j)
        acc[i][j] = __builtin_amdgcn_mfma_f32_16x16x32_bf16(af[i], bfv[j], acc[i][j], 0, 0, 0);
    if (kt + 2 < nk) asm volatile("s_waitcnt vmcnt(4)" ::: "memory");
    else             asm volatile("s_waitcnt vmcnt(0)" ::: "memory");
    __builtin_amdgcn_s_barrier();
  }

  #pragma unroll
  for (int i = 0; i < 4; ++i){
    #pragma unroll
    for (int j = 0; j < 4; ++j){
      int col = n0 + wc*64 + j*16 + lrow;
      float bv = 0.f;
      if constexpr (EPI == 0 || EPI == 1) bv = bias[col];
      #pragma unroll
      for (int q = 0; q < 4; ++q){
        int row = m0 + wr*64 + i*16 + lhi*4 + q;
        size_t idx = (size_t)row*ldc + col;
        float v = acc[i][j][q] + bv;
        if constexpr (EPI == 1 || EPI == 3) v += res[idx];
        if constexpr (EPI == 4){
          float a0 = bf2f(aux[idx]);
          v = a0 / (1.f + __expf(-a0)) * v;
        }
        if constexpr (EPI == 0 || EPI == 2 || EPI == 4) ((u16*)Cout)[idx] = f2bf(v);
        else ((float*)Cout)[idx] = v;
      }
    }
  }
}

// ---- causal flash attention: paired-qblock load balancing (unchanged) ----
__global__ __launch_bounds__(512) void k_attn(
    const u16* __restrict__ Q, const u16* __restrict__ Kb,
    const u16* __restrict__ Vt, u16* __restrict__ O, int ldq)
{
  int tid = threadIdx.x, lane = tid & 63, wave = tid >> 6;  // 8 waves
  int lrow = lane & 15, lhi = lane >> 4;
  int bidx = blockIdx.x;
  int bh = bidx >> 3, j = bidx & 7;
  int b = bh >> 4, h = bh & 15;

  __shared__ __align__(16) u16 Kbuf[2][64*128];
  __shared__ __align__(16) u16 Vbuf[2][128*64];
  __shared__ __align__(16) u16 P_lds[8][16*64];
  char* pw = (char*)&P_lds[wave][0];
  const float sc2 = 0.08838834764831845f * 1.44269504088896340736f;

  auto stage = [&](int bufi, int kt){
    int kv0 = kt << 6;
    char* kd = (char*)&Kbuf[bufi][0];
    char* vd = (char*)&Vbuf[bufi][0];
    #pragma unroll
    for (int L = 0; L < 2; ++L){
      int cid = wave*128 + L*64 + lane;
      int r = cid >> 4, c = cid & 15;
      int cg = c ^ (r & 7);
      __builtin_amdgcn_global_load_lds(
        (const AS1 void*)(Kb + (size_t)(b*SS + kv0 + r)*ldq + h*DK + cg*8),
        (AS3 void*)(kd + wave*2048 + L*1024 + lane*16), 16, 0, 0);
      int dd = cid >> 3, c8 = cid & 7;
      int cv = c8 ^ (dd & 7);
      __builtin_amdgcn_global_load_lds(
        (const AS1 void*)(Vt + (size_t)bh*DK*SS + (size_t)dd*SS + kv0 + cv*8),
        (AS3 void*)(vd + wave*2048 + L*1024 + lane*16), 16, 0, 0);
    }
  };

  #pragma unroll 1
  for (int item = 0; item < 2; ++item){
    int qi = item == 0 ? 15 - j : j;
    int qs = qi * 128;
    int nt = 2*qi + 2;
    int qrow = qs + wave * 16;

    bf16x8 qf[4];
    const u16* qbase = Q + (size_t)(b*SS + qrow + lrow)*ldq + h*DK + lhi*8;
    #pragma unroll
    for (int dc = 0; dc < 4; ++dc) qf[dc] = *(const bf16x8*)(qbase + dc*32);

    f32x4 accO[8] = {};
    float mr[4] = {-1e30f,-1e30f,-1e30f,-1e30f};
    float lr[4] = {0.f,0.f,0.f,0.f};

    stage(0, 0);
    __syncthreads();

    for (int kt = 0; kt < nt; ++kt){
      int cur = kt & 1;
      if (kt + 1 < nt) stage(cur ^ 1, kt + 1);
      int kv0 = kt << 6;
      if (kv0 <= qrow + 15){
        const char* kl = (const char*)&Kbuf[cur][0];
        const char* vl = (const char*)&Vbuf[cur][0];
        bool domask = (kv0 + 63 > qrow);

        f32x4 sf[4];
        #pragma unroll
        for (int hf = 0; hf < 4; ++hf){
          int rl = hf*16 + lrow;
          int sw = rl & 7;
          f32x4 a = {};
          #pragma unroll
          for (int dc = 0; dc < 4; ++dc){
            bf16x8 kf = *(const bf16x8*)(kl + rl*256 + (((lhi + dc*4) ^ sw) << 4));
            a = __builtin_amdgcn_mfma_f32_16x16x32_bf16(qf[dc], kf, a, 0, 0, 0);
          }
          sf[hf] = a;
        }

        float p[4][4], mx[4];
        #pragma unroll
        for (int q = 0; q < 4; ++q){
          float s0 = sf[0][q]*sc2, s1 = sf[1][q]*sc2, s2 = sf[2][q]*sc2, s3 = sf[3][q]*sc2;
          if (domask){
            int qg = qrow + lhi*4 + q;
            if (kv0      + lrow > qg) s0 = -1e30f;
            if (kv0 + 16 + lrow > qg) s1 = -1e30f;
            if (kv0 + 32 + lrow > qg) s2 = -1e30f;
            if (kv0 + 48 + lrow > qg) s3 = -1e30f;
          }
          p[q][0]=s0; p[q][1]=s1; p[q][2]=s2; p[q][3]=s3;
          float m = fmaxf(fmaxf(s0,s1), fmaxf(s2,s3));
          m = fmaxf(m, __shfl_xor(m, 1, 64));
          m = fmaxf(m, __shfl_xor(m, 2, 64));
          m = fmaxf(m, __shfl_xor(m, 4, 64));
          m = fmaxf(m, __shfl_xor(m, 8, 64));
          mx[q] = m;
        }
        float dmax = fmaxf(fmaxf(mx[0]-mr[0], mx[1]-mr[1]), fmaxf(mx[2]-mr[2], mx[3]-mr[3]));
        bool rescale = !__all(dmax <= 8.0f);
        float al[4];
        #pragma unroll
        for (int q = 0; q < 4; ++q){
          if (rescale){
            float mn = fmaxf(mr[q], mx[q]);
            al[q] = fexp2(mr[q] - mn);
            mr[q] = mn;
          } else al[q] = 1.0f;
          p[q][0] = fexp2(p[q][0] - mr[q]);
          p[q][1] = fexp2(p[q][1] - mr[q]);
          p[q][2] = fexp2(p[q][2] - mr[q]);
          p[q][3] = fexp2(p[q][3] - mr[q]);
          float sm = (p[q][0] + p[q][1]) + (p[q][2] + p[q][3]);
          sm += __shfl_xor(sm, 1, 64);
          sm += __shfl_xor(sm, 2, 64);
          sm += __shfl_xor(sm, 4, 64);
          sm += __shfl_xor(sm, 8, 64);
          lr[q] = lr[q]*al[q] + sm;
        }
        if (rescale){
          #pragma unroll
          for (int f = 0; f < 8; ++f)
            #pragma unroll
            for (int q = 0; q < 4; ++q) accO[f][q] *= al[q];
        }

        #pragma unroll
        for (int q = 0; q < 4; ++q){
          int row = lhi*4 + q;
          int rb = row*128, sw = (row & 7) << 4;
          #pragma unroll
          for (int hf = 0; hf < 4; ++hf)
            *(u16*)(pw + rb + ((hf*32 + lrow*2) ^ sw)) = cvt_bf16(p[q][hf]);
        }
        __builtin_amdgcn_sched_barrier(0);
        int rsw = (lrow & 7) << 4;
        bf16x8 pa0 = *(const bf16x8*)(pw + lrow*128 + ((     lhi*16) ^ rsw));
        bf16x8 pa1 = *(const bf16x8*)(pw + lrow*128 + ((64 + lhi*16) ^ rsw));

        #pragma unroll
        for (int f = 0; f < 8; ++f){
          int d = f*16 + lrow;
          int swv = d & 7;
          bf16x8 v0 = *(const bf16x8*)(vl + d*128 + (((lhi    ) ^ swv) << 4));
          bf16x8 v1 = *(const bf16x8*)(vl + d*128 + (((lhi + 4) ^ swv) << 4));
          accO[f] = __builtin_amdgcn_mfma_f32_16x16x32_bf16(pa0, v0, accO[f], 0, 0, 0);
          accO[f] = __builtin_amdgcn_mfma_f32_16x16x32_bf16(pa1, v1, accO[f], 0, 0, 0);
        }
      }
      __syncthreads();
    }

    #pragma unroll
    for (int q = 0; q < 4; ++q){
      float inv = 1.0f / lr[q];
      #pragma unroll
      for (int f = 0; f < 8; ++f){
        int row = b*SS + qrow + lhi*4 + q;
        int col = h*DK + f*16 + lrow;
        O[(size_t)row*D_MODEL + col] = cvt_bf16(accO[f][q] * inv);
      }
    }
    __syncthreads();
  }
}

extern "C" void kernel_launch(void* const* d_in, const int* in_sizes, int n_in,
                              void* d_out, int out_size, void* d_ws, size_t ws_size,
                              hipStream_t stream)
{
  (void)in_sizes; (void)n_in; (void)out_size;
  const float* x  = (const float*)d_in[0];
  const float* wq = (const float*)d_in[2];
  const float* bq = (const float*)d_in[3];
  const float* wk = (const float*)d_in[4];
  const float* bk = (const float*)d_in[5];
  const float* wv = (const float*)d_in[6];
  const float* bv = (const float*)d_in[7];
  const float* wo = (const float*)d_in[8];
  const float* bo = (const float*)d_in[9];
  const float* g1 = (const float*)d_in[10];
  const float* g2 = (const float*)d_in[11];
  const float* w1 = (const float*)d_in[12];
  const float* w3 = (const float*)d_in[13];  // w3 precedes w2 in dict order
  const float* w2 = (const float*)d_in[14];
  float* out = (float*)d_out;

  // ---- workspace layout (audited, lifetime-aliased; NEED = 181.95 MB) ----
  const size_t MB = 1u << 20;
  const size_t W2T_B = (size_t)D_MODEL * DFF * sizeof(u16);       // 22,544,384
  const size_t NEED = 152*MB + W2T_B + 32768;                     // 181,952,512
  if (ws_size < NEED) return;
  char* ws = (char*)d_ws;
  u16* bufA  = (u16*)(ws + 0);        // 16 MiB: nbf1 -> aob -> nbf2
  u16* qkv   = (u16*)(ws + 16*MB);    // 48 MiB fused QKV [4096][6144]
  u16* h1    = qkv;                   // [4096][5632] = 44 MiB, aliases after attn
  u16* wqkvt = (u16*)(ws + 64*MB);    // 24 MiB, dead after QKV GEMM
  u16* w1w3t = (u16*)(ws + 64*MB);    // [11264][2048] = 44 MiB (64-108): w1-half 64-86, w3-half 86-108
  u16* wot   = (u16*)(ws + 88*MB);    // 8 MiB (overlaps w3-half: w3 transpose AFTER O-proj)
  u16* vtb   = (u16*)(ws + 96*MB);    // 16 MiB (dead after attn)
  u16* h3    = (u16*)(ws + 108*MB);   // [4096][5632] = 44 MiB (108-152)
  u16* w2t   = (u16*)(ws + 152*MB);   // [2048][5504] = 21.5 MiB
  float* bqkv = (float*)(ws + 152*MB + W2T_B);
  // fp32 residual x1 lives in d_out

  bool big = true;
  big &= hipFuncSetAttribute((const void*)k_gemm8p<0>, hipFuncAttributeMaxDynamicSharedMemorySize, 131072) == hipSuccess;
  big &= hipFuncSetAttribute((const void*)k_gemm8p<5>, hipFuncAttributeMaxDynamicSharedMemorySize, 131072) == hipSuccess;

  dim3 tb(32, 8);
  k_transpose_w<<<dim3(64,64), tb, 0, stream>>>(wq, wqkvt,               D_MODEL, D_MODEL);
  k_transpose_w<<<dim3(64,64), tb, 0, stream>>>(wk, wqkvt + 2048*2048,   D_MODEL, D_MODEL);
  k_transpose_w<<<dim3(64,64), tb, 0, stream>>>(wv, wqkvt + 2*2048*2048, D_MODEL, D_MODEL);
  k_transpose_w<<<dim3(64,64), tb, 0, stream>>>(wo, wot, D_MODEL, D_MODEL);
  k_transpose_w<<<dim3(64, DFF/32), tb, 0, stream>>>(w2, w2t, DFF, D_MODEL);
  k_concat3<<<24, 256, 0, stream>>>(bq, bk, bv, bqkv);

  k_rmsnorm<<<MTOK, 256, 0, stream>>>(x, g1, bufA);
  if (big)
    k_gemm8p<0><<<(MTOK/256)*(DQKV/256), 512, 131072, stream>>>(bufA, wqkvt, bqkv, nullptr, qkv, MTOK, DQKV, D_MODEL, D_MODEL, D_MODEL, DQKV);
  else
    k_gemm_bt<0><<<(DQKV/128)*(MTOK/128), 256, 0, stream>>>(bufA, wqkvt, bqkv, nullptr, nullptr, qkv, MTOK, DQKV, D_MODEL, D_MODEL, D_MODEL, DQKV);
  k_transpose_v<<<dim3(SS/32, 128), tb, 0, stream>>>(qkv + 4096, vtb, DQKV);
  // w1 -> rows 0-5631 of w1w3t (64-86 MiB region, dead wqkvt): after QKV GEMM
  k_transpose_w<<<dim3(DFFP/32, 64), tb, 0, stream>>>(w1, w1w3t, D_MODEL, DFF);
  k_attn<<<dim3(BB*NHEADS*8), 512, 0, stream>>>(qkv, qkv + 2048, vtb, bufA, DQKV);
  k_gemm_bt<1><<<16*32, 256, 0, stream>>>(bufA, wot, bo, x, nullptr, out, MTOK, D_MODEL, D_MODEL, D_MODEL, D_MODEL, D_MODEL);
  // w3 -> rows 5632-11263 of w1w3t (86-108 MiB, overlaps wot+vtb): after O-proj & attn
  k_transpose_w<<<dim3(DFFP/32, 64), tb, 0, stream>>>(w3, w1w3t + (size_t)DFFP*2048, D_MODEL, DFF);
  k_rmsnorm<<<MTOK, 256, 0, stream>>>(out, g2, bufA);
  if (big){
    // combined W1|W3: N=11264, dual output h1/h3 (split at n0=5632), ldc=DFFP
    k_gemm8p<5><<<(MTOK/256)*((2*DFFP)/256), 512, 131072, stream>>>(bufA, w1w3t, nullptr, h3, h1, MTOK, 2*DFFP, D_MODEL, D_MODEL, D_MODEL, DFFP);
  } else {
    k_gemm_bt<2><<<(DFFP/128)*32, 256, 0, stream>>>(bufA, w1w3t, nullptr, nullptr, nullptr, h1, MTOK, DFFP, D_MODEL, D_MODEL, D_MODEL, DFFP);
    k_gemm_bt<2><<<(DFFP/128)*32, 256, 0, stream>>>(bufA, w1w3t + (size_t)DFFP*2048, nullptr, nullptr, nullptr, h3, MTOK, DFFP, D_MODEL, D_MODEL, D_MODEL, DFFP);
  }
  k_silu_mul<<<(MTOK*DFFP/8 + 255)/256, 256, 0, stream>>>(h1, h3, h1, MTOK*DFFP/8);
  k_gemm_bt<3><<<16*32, 256, 0, stream>>>(h1, w2t, nullptr, out, nullptr, out, MTOK, D_MODEL, DFF, DFFP, DFF, D_MODEL);
}

// Round 12
// 671.744 us; speedup vs baseline: 1.2853x; 1.0745x over previous
//
#include <hip/hip_runtime.h>
#include <stdint.h>

typedef unsigned short u16;
typedef __bf16 bf16x8 __attribute__((ext_vector_type(8)));
typedef float f32x4 __attribute__((ext_vector_type(4)));

#define D_MODEL 2048
#define NHEADS 16
#define DK 128
#define DFF 5504
#define DFFP 5632   // DFF padded to 256 multiple
#define BB 2
#define SS 2048
#define MTOK 4096
#define DQKV 6144

#define AS1 __attribute__((address_space(1)))
#define AS3 __attribute__((address_space(3)))

__device__ __forceinline__ u16 f2bf(float f){
  union { float f; uint32_t u; } v; v.f = f;
  uint32_t r = v.u + 0x7fffu + ((v.u >> 16) & 1u);
  return (u16)(r >> 16);
}
__device__ __forceinline__ float bf2f(u16 u){
  union { uint32_t u; float f; } v; v.u = ((uint32_t)u) << 16;
  return v.f;
}
__device__ __forceinline__ u16 cvt_bf16(float f){
  union { __bf16 h; u16 u; } v; v.h = (__bf16)f; return v.u;
}
__device__ __forceinline__ float fexp2(float x){
#if __has_builtin(__builtin_amdgcn_exp2f)
  return __builtin_amdgcn_exp2f(x);
#else
  return exp2f(x);
#endif
}

// ---- fp32 W[K][Nsrc] -> bf16 Wt[n][K], zero-fill n >= Nsrc ----
__global__ __launch_bounds__(256) void k_transpose_w(const float* __restrict__ W,
                                                     u16* __restrict__ Wt, int K, int Nsrc){
  __shared__ float tile[32][33];
  int n0 = blockIdx.x * 32, k0 = blockIdx.y * 32;
  int tx = threadIdx.x, ty = threadIdx.y;  // (32,8)
  #pragma unroll
  for (int r = 0; r < 4; ++r){
    int n = n0 + tx;
    tile[ty + r*8][tx] = (n < Nsrc) ? W[(size_t)(k0 + ty + r*8) * Nsrc + n] : 0.0f;
  }
  __syncthreads();
  #pragma unroll
  for (int r = 0; r < 4; ++r)
    Wt[(size_t)(n0 + ty + r*8) * K + k0 + tx] = f2bf(tile[tx][ty + r*8]);
}

// ---- per-head V transpose from fused QKV ----
__global__ __launch_bounds__(256) void k_transpose_v(const u16* __restrict__ V,
                                                     u16* __restrict__ Vt, int ld){
  __shared__ u16 tile[32][33];
  int s0 = blockIdx.x * 32;
  int bh = blockIdx.y >> 2, dt = blockIdx.y & 3;
  int b = bh >> 4, h = bh & 15;
  int tx = threadIdx.x, ty = threadIdx.y;
  #pragma unroll
  for (int r = 0; r < 4; ++r)
    tile[ty + r*8][tx] = V[(size_t)(b*SS + s0 + ty + r*8) * ld + h*DK + dt*32 + tx];
  __syncthreads();
  #pragma unroll
  for (int r = 0; r < 4; ++r)
    Vt[(size_t)(bh*DK + dt*32 + ty + r*8) * SS + s0 + tx] = tile[tx][ty + r*8];
}

__global__ __launch_bounds__(256) void k_concat3(const float* __restrict__ a,
                                                 const float* __restrict__ b,
                                                 const float* __restrict__ c,
                                                 float* __restrict__ o){
  int i = blockIdx.x*256 + threadIdx.x;
  if (i >= DQKV) return;
  o[i] = (i < 2048) ? a[i] : (i < 4096 ? b[i-2048] : c[i-4096]);
}

// ---- RMSNorm: fp32 row -> bf16 row ----
__global__ __launch_bounds__(256) void k_rmsnorm(const float* __restrict__ X,
                                                 const float* __restrict__ g,
                                                 u16* __restrict__ out){
  int row = blockIdx.x, tid = threadIdx.x;
  const float* x = X + (size_t)row * D_MODEL;
  float4 a = ((const float4*)x)[tid*2];
  float4 b = ((const float4*)x)[tid*2+1];
  float ss = a.x*a.x + a.y*a.y + a.z*a.z + a.w*a.w
           + b.x*b.x + b.y*b.y + b.z*b.z + b.w*b.w;
  #pragma unroll
  for (int m = 1; m < 64; m <<= 1) ss += __shfl_xor(ss, m, 64);
  __shared__ float red[4];
  if ((tid & 63) == 0) red[tid >> 6] = ss;
  __syncthreads();
  float tot = red[0] + red[1] + red[2] + red[3];
  float sc = rsqrtf(tot * (1.0f / D_MODEL) + 1e-6f);
  float4 ga = ((const float4*)g)[tid*2];
  float4 gb = ((const float4*)g)[tid*2+1];
  uint32_t w0 = f2bf(a.x*sc*ga.x) | ((uint32_t)f2bf(a.y*sc*ga.y) << 16);
  uint32_t w1 = f2bf(a.z*sc*ga.z) | ((uint32_t)f2bf(a.w*sc*ga.w) << 16);
  uint32_t w2 = f2bf(b.x*sc*gb.x) | ((uint32_t)f2bf(b.y*sc*gb.y) << 16);
  uint32_t w3 = f2bf(b.z*sc*gb.z) | ((uint32_t)f2bf(b.w*sc*gb.w) << 16);
  ((uint4*)(out + (size_t)row * D_MODEL))[tid] = make_uint4(w0, w1, w2, w3);
}

// ---- hg = silu(h1) * h3 (bf16, 8 elems/thread) ----
__global__ __launch_bounds__(256) void k_silu_mul(const u16* __restrict__ a,
                                                  const u16* __restrict__ b,
                                                  u16* __restrict__ o, int n8){
  int i = blockIdx.x * 256 + threadIdx.x;
  if (i >= n8) return;
  uint4 av = ((const uint4*)a)[i];
  uint4 bv = ((const uint4*)b)[i];
  uint32_t aa[4] = {av.x, av.y, av.z, av.w};
  uint32_t bb[4] = {bv.x, bv.y, bv.z, bv.w};
  uint32_t rr[4];
  #pragma unroll
  for (int j = 0; j < 4; ++j){
    float x0 = bf2f((u16)(aa[j] & 0xffff)), x1 = bf2f((u16)(aa[j] >> 16));
    float y0 = bf2f((u16)(bb[j] & 0xffff)), y1 = bf2f((u16)(bb[j] >> 16));
    float r0 = x0 / (1.f + __expf(-x0)) * y0;
    float r1 = x1 / (1.f + __expf(-x1)) * y1;
    rr[j] = f2bf(r0) | ((uint32_t)f2bf(r1) << 16);
  }
  ((uint4*)o)[i] = make_uint4(rr[0], rr[1], rr[2], rr[3]);
}

// ---- out += p0 + p1 (fp32, float4) — split-K reduction into residual ----
__global__ __launch_bounds__(256) void k_add2(float* __restrict__ out,
                                              const float* __restrict__ p0,
                                              const float* __restrict__ p1, int n4){
  int stride = gridDim.x * 256;
  for (int i = blockIdx.x * 256 + threadIdx.x; i < n4; i += stride){
    float4 o = ((const float4*)out)[i];
    float4 a = ((const float4*)p0)[i];
    float4 b = ((const float4*)p1)[i];
    o.x += a.x + b.x; o.y += a.y + b.y; o.z += a.z + b.z; o.w += a.w + b.w;
    ((float4*)out)[i] = o;
  }
}

// ============ 256x256 8-wave GEMM — 8-phase, 2-barrier, 2D-XCD-patch ============
// row&7 chunk swizzle both-sides (conflict-free, verified r10).
// EPI 0: bf16 +bias; EPI 2: bf16; EPI 5: dual bf16 out (n0<5632 -> Cout, else aux-5632)
// EPI 6: split-K x2 -> fp32 partials (slice0 -> Cout, slice1 -> aux), no bias
template<int EPI>
__global__ __launch_bounds__(512, 2) void k_gemm8p(
    const u16* __restrict__ A, const u16* __restrict__ Bt,
    const float* __restrict__ bias, const u16* __restrict__ aux,
    void* __restrict__ Cout, int M, int N, int K,
    int lda, int ldb, int ldc)
{
  extern __shared__ __align__(16) char smem[];
  const int tid = threadIdx.x;
  const int lane = tid & 63, wid = tid >> 6;
  const int wr = wid >> 2, wc = wid & 3;        // 2M x 4N waves
  const int lrow = lane & 15, lhi = lane >> 4;

  int nwg = gridDim.x, wg = blockIdx.x;
  int ksl = 0;
  if constexpr (EPI == 6){
    int hn = nwg >> 1;
    if (wg >= hn){ ksl = 1; wg -= hn; }
    nwg = hn;
    A  += (size_t)ksl * K;   // slice base along K
    Bt += (size_t)ksl * K;
  }

  // XCD mapping: 2D patch (2 M-halves x 4 N-quads) when divisible; else m204 1D.
  int nbx = N >> 8, nbm = M >> 8;
  int xcd = wg & 7, sub = wg >> 3;
  int m0, n0;
  if ((nwg & 7) == 0 && (nbm & 1) == 0 && (nbx & 3) == 0){
    int mh = nbm >> 1;
    int mr = sub % mh, nc = sub / mh;           // consecutive sub share B-tile
    m0 = (((xcd & 1) * mh) + mr) << 8;
    n0 = (((xcd >> 1) * (nbx >> 2)) + nc) << 8;
  } else {
    int qq = nwg >> 3, rr2 = nwg & 7;
    int swz = (xcd < rr2 ? xcd*(qq+1) : rr2*(qq+1) + (xcd-rr2)*qq) + sub;
    m0 = (swz / nbx) << 8; n0 = (swz % nbx) << 8;
  }

  const int nk = K >> 6;                         // BK = 64
  const int hA = wr, hB = wc >> 1;
  const int gA = wc;
  const int gB = (wr << 1) | (wc & 1);

  auto stA = [&](int d, int kk, int q){
    #pragma unroll
    for (int L = 0; L < 2; ++L){
      int p = q*8192 + gA*2048 + L*1024 + lane*16;   // physical (linear dest)
      int row = p >> 7;
      int o = (p & 127) ^ ((row & 7) << 4);          // logical in-row byte
      __builtin_amdgcn_global_load_lds(
        (const AS1 void*)(A + (size_t)(m0 + hA*128 + row)*lda + kk + (o >> 1)),
        (AS3 void*)(smem + d*65536 + hA*16384 + p), 16, 0, 0);
    }
  };
  auto stB = [&](int d, int kk, int s){
    #pragma unroll
    for (int L = 0; L < 2; ++L){
      int p = s*4096 + (gB >> 1)*8192 + (gB & 1)*2048 + L*1024 + lane*16;
      int row = p >> 7;
      int o = (p & 127) ^ ((row & 7) << 4);
      __builtin_amdgcn_global_load_lds(
        (const AS1 void*)(Bt + (size_t)(n0 + hB*128 + row)*ldb + kk + (o >> 1)),
        (AS3 void*)(smem + d*65536 + 32768 + hB*16384 + p), 16, 0, 0);
    }
  };
  auto rdA = [&](int d, int rloc, int ks)->bf16x8{
    int p = rloc*128 + ((ks*64 + lhi*16) ^ ((rloc & 7) << 4));
    return *(const bf16x8*)(smem + d*65536 + hA*16384 + p);
  };
  auto rdB = [&](int d, int rloc, int ks)->bf16x8{
    int p = rloc*128 + ((ks*64 + lhi*16) ^ ((rloc & 7) << 4));
    return *(const bf16x8*)(smem + d*65536 + 32768 + hB*16384 + p);
  };

  f32x4 acc[8][4] = {};

  stA(0, 0, 0); stB(0, 0, 0); stB(0, 0, 1); stA(0, 0, 1);
  asm volatile("s_waitcnt vmcnt(0)" ::: "memory");
  __builtin_amdgcn_s_barrier();

  for (int t = 0; t < nk; ++t){
    int d = t & 1, dn = d ^ 1, kkn = (t + 1) << 6;
    bool pf = (t + 1 < nk);
    bf16x8 aR[8], bQ0[4], bQ1[4];

    // ---- phase 0: Q00 (reads A q0: 8, B own q0: 4; stage A-q0 + B-s0 of t+1) ----
    #pragma unroll
    for (int ii = 0; ii < 4; ++ii){
      aR[ii*2]   = rdA(d, ii*16 + lrow, 0);
      aR[ii*2+1] = rdA(d, ii*16 + lrow, 1);
    }
    #pragma unroll
    for (int j = 0; j < 2; ++j){
      bQ0[j*2]   = rdB(d, (wc&1)*64 + j*16 + lrow, 0);
      bQ0[j*2+1] = rdB(d, (wc&1)*64 + j*16 + lrow, 1);
    }
    if (pf){ stA(dn, kkn, 0); stB(dn, kkn, 0); }
    __builtin_amdgcn_s_barrier();                     // barrier 1: all issued
    asm volatile("s_waitcnt lgkmcnt(0)" ::: "memory");
    __builtin_amdgcn_sched_barrier(0);
    __builtin_amdgcn_s_setprio(1);
    #pragma unroll
    for (int ii = 0; ii < 4; ++ii)
      #pragma unroll
      for (int j = 0; j < 2; ++j){
        acc[ii][j] = __builtin_amdgcn_mfma_f32_16x16x32_bf16(aR[ii*2],   bQ0[j*2],   acc[ii][j], 0, 0, 0);
        acc[ii][j] = __builtin_amdgcn_mfma_f32_16x16x32_bf16(aR[ii*2+1], bQ0[j*2+1], acc[ii][j], 0, 0, 0);
      }
    __builtin_amdgcn_s_setprio(0);
    if (pf) asm volatile("s_waitcnt vmcnt(6)" ::: "memory");
    else    asm volatile("s_waitcnt vmcnt(2)" ::: "memory");
    __builtin_amdgcn_sched_barrier(0);
    __builtin_amdgcn_s_barrier();                     // barrier 2

    // ---- phase 1: Q01 (reads B own q1: 4; stage B-s1 of t+1; reuse aR) ----
    #pragma unroll
    for (int j = 0; j < 2; ++j){
      bQ1[j*2]   = rdB(d, (wc&1)*64 + 32 + j*16 + lrow, 0);
      bQ1[j*2+1] = rdB(d, (wc&1)*64 + 32 + j*16 + lrow, 1);
    }
    if (pf) stB(dn, kkn, 1);
    __builtin_amdgcn_s_barrier();
    asm volatile("s_waitcnt lgkmcnt(0)" ::: "memory");
    __builtin_amdgcn_sched_barrier(0);
    __builtin_amdgcn_s_setprio(1);
    #pragma unroll
    for (int ii = 0; ii < 4; ++ii)
      #pragma unroll
      for (int j = 0; j < 2; ++j){
        acc[ii][2+j] = __builtin_amdgcn_mfma_f32_16x16x32_bf16(aR[ii*2],   bQ1[j*2],   acc[ii][2+j], 0, 0, 0);
        acc[ii][2+j] = __builtin_amdgcn_mfma_f32_16x16x32_bf16(aR[ii*2+1], bQ1[j*2+1], acc[ii][2+j], 0, 0, 0);
      }
    __builtin_amdgcn_s_setprio(0);
    if (pf) asm volatile("s_waitcnt vmcnt(6)" ::: "memory");
    else    asm volatile("s_waitcnt vmcnt(0)" ::: "memory");
    __builtin_amdgcn_sched_barrier(0);
    __builtin_amdgcn_s_barrier();

    // ---- phase 2: Q11 (reads A q1: 8; stage A-q1 of t+1; reuse bQ1) ----
    #pragma unroll
    for (int ii = 0; ii < 4; ++ii){
      aR[ii*2]   = rdA(d, 64 + ii*16 + lrow, 0);
      aR[ii*2+1] = rdA(d, 64 + ii*16 + lrow, 1);
    }
    if (pf) stA(dn, kkn, 1);
    __builtin_amdgcn_s_barrier();
    asm volatile("s_waitcnt lgkmcnt(0)" ::: "memory");
    __builtin_amdgcn_sched_barrier(0);
    __builtin_amdgcn_s_setprio(1);
    #pragma unroll
    for (int ii = 0; ii < 4; ++ii)
      #pragma unroll
      for (int j = 0; j < 2; ++j){
        acc[4+ii][2+j] = __builtin_amdgcn_mfma_f32_16x16x32_bf16(aR[ii*2],   bQ1[j*2],   acc[4+ii][2+j], 0, 0, 0);
        acc[4+ii][2+j] = __builtin_amdgcn_mfma_f32_16x16x32_bf16(aR[ii*2+1], bQ1[j*2+1], acc[4+ii][2+j], 0, 0, 0);
      }
    __builtin_amdgcn_s_setprio(0);
    __builtin_amdgcn_s_barrier();

    // ---- phase 3: Q10 (no reads; reuse aR + bQ0) ----
    __builtin_amdgcn_s_setprio(1);
    #pragma unroll
    for (int ii = 0; ii < 4; ++ii)
      #pragma unroll
      for (int j = 0; j < 2; ++j){
        acc[4+ii][j] = __builtin_amdgcn_mfma_f32_16x16x32_bf16(aR[ii*2],   bQ0[j*2],   acc[4+ii][j], 0, 0, 0);
        acc[4+ii][j] = __builtin_amdgcn_mfma_f32_16x16x32_bf16(aR[ii*2+1], bQ0[j*2+1], acc[4+ii][j], 0, 0, 0);
      }
    __builtin_amdgcn_s_setprio(0);
    if (pf) asm volatile("s_waitcnt vmcnt(4)" ::: "memory");
    __builtin_amdgcn_sched_barrier(0);
    __builtin_amdgcn_s_barrier();
  }

  // epilogue
  if constexpr (EPI == 6){
    float* P = ksl ? (float*)aux : (float*)Cout;
    #pragma unroll
    for (int i = 0; i < 8; ++i)
      #pragma unroll
      for (int j = 0; j < 4; ++j){
        int col = n0 + wc*64 + j*16 + lrow;
        #pragma unroll
        for (int q = 0; q < 4; ++q){
          int row = m0 + wr*128 + i*16 + lhi*4 + q;
          P[(size_t)row*ldc + col] = acc[i][j][q];
        }
      }
    return;
  }
  u16* Cw = (u16*)Cout;
  int cofs = 0;
  if constexpr (EPI == 5){
    if (n0 >= 5632){ Cw = (u16*)aux; cofs = 5632; }
  }
  #pragma unroll
  for (int i = 0; i < 8; ++i){
    #pragma unroll
    for (int j = 0; j < 4; ++j){
      int col = n0 + wc*64 + j*16 + lrow;
      float bv = 0.f;
      if constexpr (EPI == 0) bv = bias[col];
      #pragma unroll
      for (int q = 0; q < 4; ++q){
        int row = m0 + wr*128 + i*16 + lhi*4 + q;
        float v = acc[i][j][q] + bv;
        Cw[(size_t)row*ldc + (col - cofs)] = f2bf(v);
      }
    }
  }
}

// ---- 128x128 GEMM (3-buffer counted vmcnt, row&3 chunk swizzle) ----
template<int EPI>
__global__ __launch_bounds__(256) void k_gemm_bt(
    const u16* __restrict__ A, const u16* __restrict__ Bt,
    const float* __restrict__ bias, const float* __restrict__ res,
    const u16* __restrict__ aux,
    void* __restrict__ Cout, int M, int N, int K,
    int lda, int ldb, int ldc)
{
  __shared__ __align__(16) u16 As[3][128*32];
  __shared__ __align__(16) u16 Bs[3][128*32];
  int tid = threadIdx.x;

  int nwg = gridDim.x, wg = blockIdx.x;
  int qq = nwg >> 3, rr = nwg & 7;
  int xcd = wg & 7, sub = wg >> 3;
  int swz = (xcd < rr ? xcd*(qq+1) : rr*(qq+1) + (xcd-rr)*qq) + sub;
  int nbx = N >> 7;
  int m0 = (swz / nbx) << 7, n0 = (swz % nbx) << 7;

  int lane = tid & 63, wave = tid >> 6;
  int wr = wave >> 1, wc = wave & 1;
  int lrow = lane & 15, lhi = lane >> 4;
  f32x4 acc[4][4] = {};
  int srow = tid >> 2;
  int schk = tid & 3;
  const int nk = K >> 5;

  auto stage = [&](int slot, int kt){
    int k0 = kt << 5;
    int c = schk ^ (srow & 3);
    #pragma unroll
    for (int cc = 0; cc < 2; ++cc){
      int r = cc*64 + srow;
      __builtin_amdgcn_global_load_lds(
        (const AS1 void*)(A + (size_t)(m0 + r)*lda + k0 + c*8),
        (AS3 void*)(&As[slot][r*32 + schk*8]), 16, 0, 0);
      __builtin_amdgcn_global_load_lds(
        (const AS1 void*)(Bt + (size_t)(n0 + r)*ldb + k0 + c*8),
        (AS3 void*)(&Bs[slot][r*32 + schk*8]), 16, 0, 0);
    }
  };

  stage(0, 0);
  if (nk > 1) stage(1, 1);
  if (nk > 1) asm volatile("s_waitcnt vmcnt(4)" ::: "memory");
  else        asm volatile("s_waitcnt vmcnt(0)" ::: "memory");
  __builtin_amdgcn_s_barrier();

  for (int kt = 0; kt < nk; ++kt){
    int cur = kt % 3;
    if (kt + 2 < nk) stage((kt + 2) % 3, kt + 2);
    int rchk = lhi ^ (lrow & 3);
    bf16x8 af[4], bfv[4];
    #pragma unroll
    for (int i = 0; i < 4; ++i){
      af[i]  = *(const bf16x8*)(&As[cur][(wr*64 + i*16 + lrow)*32 + rchk*8]);
      bfv[i] = *(const bf16x8*)(&Bs[cur][(wc*64 + i*16 + lrow)*32 + rchk*8]);
    }
    #pragma unroll
    for (int i = 0; i < 4; ++i)
      #pragma unroll
      for (int j = 0; j < 4; ++j)
        acc[i][j] = __builtin_amdgcn_mfma_f32_16x16x32_bf16(af[i], bfv[j], acc[i][j], 0, 0, 0);
    if (kt + 2 < nk) asm volatile("s_waitcnt vmcnt(4)" ::: "memory");
    else             asm volatile("s_waitcnt vmcnt(0)" ::: "memory");
    __builtin_amdgcn_s_barrier();
  }

  #pragma unroll
  for (int i = 0; i < 4; ++i){
    #pragma unroll
    for (int j = 0; j < 4; ++j){
      int col = n0 + wc*64 + j*16 + lrow;
      float bv = 0.f;
      if constexpr (EPI == 0 || EPI == 1) bv = bias[col];
      #pragma unroll
      for (int q = 0; q < 4; ++q){
        int row = m0 + wr*64 + i*16 + lhi*4 + q;
        size_t idx = (size_t)row*ldc + col;
        float v = acc[i][j][q] + bv;
        if constexpr (EPI == 1 || EPI == 3) v += res[idx];
        if constexpr (EPI == 4){
          float a0 = bf2f(aux[idx]);
          v = a0 / (1.f + __expf(-a0)) * v;
        }
        if constexpr (EPI == 0 || EPI == 2 || EPI == 4) ((u16*)Cout)[idx] = f2bf(v);
        else ((float*)Cout)[idx] = v;
      }
    }
  }
}

// ---- causal flash attention: paired-qblock load balancing (unchanged) ----
__global__ __launch_bounds__(512) void k_attn(
    const u16* __restrict__ Q, const u16* __restrict__ Kb,
    const u16* __restrict__ Vt, u16* __restrict__ O, int ldq)
{
  int tid = threadIdx.x, lane = tid & 63, wave = tid >> 6;  // 8 waves
  int lrow = lane & 15, lhi = lane >> 4;
  int bidx = blockIdx.x;
  int bh = bidx >> 3, j = bidx & 7;
  int b = bh >> 4, h = bh & 15;

  __shared__ __align__(16) u16 Kbuf[2][64*128];
  __shared__ __align__(16) u16 Vbuf[2][128*64];
  __shared__ __align__(16) u16 P_lds[8][16*64];
  char* pw = (char*)&P_lds[wave][0];
  const float sc2 = 0.08838834764831845f * 1.44269504088896340736f;

  auto stage = [&](int bufi, int kt){
    int kv0 = kt << 6;
    char* kd = (char*)&Kbuf[bufi][0];
    char* vd = (char*)&Vbuf[bufi][0];
    #pragma unroll
    for (int L = 0; L < 2; ++L){
      int cid = wave*128 + L*64 + lane;
      int r = cid >> 4, c = cid & 15;
      int cg = c ^ (r & 7);
      __builtin_amdgcn_global_load_lds(
        (const AS1 void*)(Kb + (size_t)(b*SS + kv0 + r)*ldq + h*DK + cg*8),
        (AS3 void*)(kd + wave*2048 + L*1024 + lane*16), 16, 0, 0);
      int dd = cid >> 3, c8 = cid & 7;
      int cv = c8 ^ (dd & 7);
      __builtin_amdgcn_global_load_lds(
        (const AS1 void*)(Vt + (size_t)bh*DK*SS + (size_t)dd*SS + kv0 + cv*8),
        (AS3 void*)(vd + wave*2048 + L*1024 + lane*16), 16, 0, 0);
    }
  };

  #pragma unroll 1
  for (int item = 0; item < 2; ++item){
    int qi = item == 0 ? 15 - j : j;
    int qs = qi * 128;
    int nt = 2*qi + 2;
    int qrow = qs + wave * 16;

    bf16x8 qf[4];
    const u16* qbase = Q + (size_t)(b*SS + qrow + lrow)*ldq + h*DK + lhi*8;
    #pragma unroll
    for (int dc = 0; dc < 4; ++dc) qf[dc] = *(const bf16x8*)(qbase + dc*32);

    f32x4 accO[8] = {};
    float mr[4] = {-1e30f,-1e30f,-1e30f,-1e30f};
    float lr[4] = {0.f,0.f,0.f,0.f};

    stage(0, 0);
    __syncthreads();

    for (int kt = 0; kt < nt; ++kt){
      int cur = kt & 1;
      if (kt + 1 < nt) stage(cur ^ 1, kt + 1);
      int kv0 = kt << 6;
      if (kv0 <= qrow + 15){
        const char* kl = (const char*)&Kbuf[cur][0];
        const char* vl = (const char*)&Vbuf[cur][0];
        bool domask = (kv0 + 63 > qrow);

        f32x4 sf[4];
        #pragma unroll
        for (int hf = 0; hf < 4; ++hf){
          int rl = hf*16 + lrow;
          int sw = rl & 7;
          f32x4 a = {};
          #pragma unroll
          for (int dc = 0; dc < 4; ++dc){
            bf16x8 kf = *(const bf16x8*)(kl + rl*256 + (((lhi + dc*4) ^ sw) << 4));
            a = __builtin_amdgcn_mfma_f32_16x16x32_bf16(qf[dc], kf, a, 0, 0, 0);
          }
          sf[hf] = a;
        }

        float p[4][4], mx[4];
        #pragma unroll
        for (int q = 0; q < 4; ++q){
          float s0 = sf[0][q]*sc2, s1 = sf[1][q]*sc2, s2 = sf[2][q]*sc2, s3 = sf[3][q]*sc2;
          if (domask){
            int qg = qrow + lhi*4 + q;
            if (kv0      + lrow > qg) s0 = -1e30f;
            if (kv0 + 16 + lrow > qg) s1 = -1e30f;
            if (kv0 + 32 + lrow > qg) s2 = -1e30f;
            if (kv0 + 48 + lrow > qg) s3 = -1e30f;
          }
          p[q][0]=s0; p[q][1]=s1; p[q][2]=s2; p[q][3]=s3;
          float m = fmaxf(fmaxf(s0,s1), fmaxf(s2,s3));
          m = fmaxf(m, __shfl_xor(m, 1, 64));
          m = fmaxf(m, __shfl_xor(m, 2, 64));
          m = fmaxf(m, __shfl_xor(m, 4, 64));
          m = fmaxf(m, __shfl_xor(m, 8, 64));
          mx[q] = m;
        }
        float dmax = fmaxf(fmaxf(mx[0]-mr[0], mx[1]-mr[1]), fmaxf(mx[2]-mr[2], mx[3]-mr[3]));
        bool rescale = !__all(dmax <= 8.0f);
        float al[4];
        #pragma unroll
        for (int q = 0; q < 4; ++q){
          if (rescale){
            float mn = fmaxf(mr[q], mx[q]);
            al[q] = fexp2(mr[q] - mn);
            mr[q] = mn;
          } else al[q] = 1.0f;
          p[q][0] = fexp2(p[q][0] - mr[q]);
          p[q][1] = fexp2(p[q][1] - mr[q]);
          p[q][2] = fexp2(p[q][2] - mr[q]);
          p[q][3] = fexp2(p[q][3] - mr[q]);
          float sm = (p[q][0] + p[q][1]) + (p[q][2] + p[q][3]);
          sm += __shfl_xor(sm, 1, 64);
          sm += __shfl_xor(sm, 2, 64);
          sm += __shfl_xor(sm, 4, 64);
          sm += __shfl_xor(sm, 8, 64);
          lr[q] = lr[q]*al[q] + sm;
        }
        if (rescale){
          #pragma unroll
          for (int f = 0; f < 8; ++f)
            #pragma unroll
            for (int q = 0; q < 4; ++q) accO[f][q] *= al[q];
        }

        #pragma unroll
        for (int q = 0; q < 4; ++q){
          int row = lhi*4 + q;
          int rb = row*128, sw = (row & 7) << 4;
          #pragma unroll
          for (int hf = 0; hf < 4; ++hf)
            *(u16*)(pw + rb + ((hf*32 + lrow*2) ^ sw)) = cvt_bf16(p[q][hf]);
        }
        __builtin_amdgcn_sched_barrier(0);
        int rsw = (lrow & 7) << 4;
        bf16x8 pa0 = *(const bf16x8*)(pw + lrow*128 + ((     lhi*16) ^ rsw));
        bf16x8 pa1 = *(const bf16x8*)(pw + lrow*128 + ((64 + lhi*16) ^ rsw));

        #pragma unroll
        for (int f = 0; f < 8; ++f){
          int d = f*16 + lrow;
          int swv = d & 7;
          bf16x8 v0 = *(const bf16x8*)(vl + d*128 + (((lhi    ) ^ swv) << 4));
          bf16x8 v1 = *(const bf16x8*)(vl + d*128 + (((lhi + 4) ^ swv) << 4));
          accO[f] = __builtin_amdgcn_mfma_f32_16x16x32_bf16(pa0, v0, accO[f], 0, 0, 0);
          accO[f] = __builtin_amdgcn_mfma_f32_16x16x32_bf16(pa1, v1, accO[f], 0, 0, 0);
        }
      }
      __syncthreads();
    }

    #pragma unroll
    for (int q = 0; q < 4; ++q){
      float inv = 1.0f / lr[q];
      #pragma unroll
      for (int f = 0; f < 8; ++f){
        int row = b*SS + qrow + lhi*4 + q;
        int col = h*DK + f*16 + lrow;
        O[(size_t)row*D_MODEL + col] = cvt_bf16(accO[f][q] * inv);
      }
    }
    __syncthreads();
  }
}

extern "C" void kernel_launch(void* const* d_in, const int* in_sizes, int n_in,
                              void* d_out, int out_size, void* d_ws, size_t ws_size,
                              hipStream_t stream)
{
  (void)in_sizes; (void)n_in; (void)out_size;
  const float* x  = (const float*)d_in[0];
  const float* wq = (const float*)d_in[2];
  const float* bq = (const float*)d_in[3];
  const float* wk = (const float*)d_in[4];
  const float* bk = (const float*)d_in[5];
  const float* wv = (const float*)d_in[6];
  const float* bv = (const float*)d_in[7];
  const float* wo = (const float*)d_in[8];
  const float* bo = (const float*)d_in[9];
  const float* g1 = (const float*)d_in[10];
  const float* g2 = (const float*)d_in[11];
  const float* w1 = (const float*)d_in[12];
  const float* w3 = (const float*)d_in[13];  // w3 precedes w2 in dict order
  const float* w2 = (const float*)d_in[14];
  float* out = (float*)d_out;

  // ---- workspace layout (audited, lifetime-aliased; NEED = 181.95 MB) ----
  const size_t MB = 1u << 20;
  const size_t W2T_B = (size_t)D_MODEL * DFF * sizeof(u16);       // 22,544,384
  const size_t NEED = 152*MB + W2T_B + 32768;                     // 181,952,512
  if (ws_size < NEED) return;
  char* ws = (char*)d_ws;
  u16* bufA  = (u16*)(ws + 0);        // 16 MiB: nbf1 -> aob -> nbf2
  u16* qkv   = (u16*)(ws + 16*MB);    // 48 MiB fused QKV [4096][6144]
  u16* h1    = qkv;                   // [4096][5632] = 44 MiB, aliases after attn
  u16* wqkvt = (u16*)(ws + 64*MB);    // 24 MiB, dead after QKV GEMM
  u16* w1w3t = (u16*)(ws + 64*MB);    // [11264][2048] = 44 MiB (64-108)
  u16* wot   = (u16*)(ws + 88*MB);    // 8 MiB (w3 transpose AFTER O-proj)
  u16* vtb   = (u16*)(ws + 96*MB);    // 16 MiB (dead after attn)
  u16* h3    = (u16*)(ws + 108*MB);   // [4096][5632] = 44 MiB (108-152)
  float* p0  = (float*)(ws + 64*MB);  // W2 split-K partials (dead w1w3t/vtb/h3 regions)
  float* p1  = (float*)(ws + 96*MB);
  u16* w2t   = (u16*)(ws + 152*MB);   // [2048][5504] = 21.5 MiB
  float* bqkv = (float*)(ws + 152*MB + W2T_B);
  // fp32 residual x1 lives in d_out

  bool big = true;
  big &= hipFuncSetAttribute((const void*)k_gemm8p<0>, hipFuncAttributeMaxDynamicSharedMemorySize, 131072) == hipSuccess;
  big &= hipFuncSetAttribute((const void*)k_gemm8p<5>, hipFuncAttributeMaxDynamicSharedMemorySize, 131072) == hipSuccess;
  big &= hipFuncSetAttribute((const void*)k_gemm8p<6>, hipFuncAttributeMaxDynamicSharedMemorySize, 131072) == hipSuccess;

  dim3 tb(32, 8);
  k_transpose_w<<<dim3(64,64), tb, 0, stream>>>(wq, wqkvt,               D_MODEL, D_MODEL);
  k_transpose_w<<<dim3(64,64), tb, 0, stream>>>(wk, wqkvt + 2048*2048,   D_MODEL, D_MODEL);
  k_transpose_w<<<dim3(64,64), tb, 0, stream>>>(wv, wqkvt + 2*2048*2048, D_MODEL, D_MODEL);
  k_transpose_w<<<dim3(64,64), tb, 0, stream>>>(wo, wot, D_MODEL, D_MODEL);
  k_transpose_w<<<dim3(64, DFF/32), tb, 0, stream>>>(w2, w2t, DFF, D_MODEL);
  k_concat3<<<24, 256, 0, stream>>>(bq, bk, bv, bqkv);

  k_rmsnorm<<<MTOK, 256, 0, stream>>>(x, g1, bufA);
  if (big)
    k_gemm8p<0><<<(MTOK/256)*(DQKV/256), 512, 131072, stream>>>(bufA, wqkvt, bqkv, nullptr, qkv, MTOK, DQKV, D_MODEL, D_MODEL, D_MODEL, DQKV);
  else
    k_gemm_bt<0><<<(DQKV/128)*(MTOK/128), 256, 0, stream>>>(bufA, wqkvt, bqkv, nullptr, nullptr, qkv, MTOK, DQKV, D_MODEL, D_MODEL, D_MODEL, DQKV);
  k_transpose_v<<<dim3(SS/32, 128), tb, 0, stream>>>(qkv + 4096, vtb, DQKV);
  // w1 -> rows 0-5631 of w1w3t (dead wqkvt): after QKV GEMM
  k_transpose_w<<<dim3(DFFP/32, 64), tb, 0, stream>>>(w1, w1w3t, D_MODEL, DFF);
  k_attn<<<dim3(BB*NHEADS*8), 512, 0, stream>>>(qkv, qkv + 2048, vtb, bufA, DQKV);
  k_gemm_bt<1><<<16*32, 256, 0, stream>>>(bufA, wot, bo, x, nullptr, out, MTOK, D_MODEL, D_MODEL, D_MODEL, D_MODEL, D_MODEL);
  // w3 -> rows 5632-11263 of w1w3t (overlaps wot+vtb): after O-proj & attn
  k_transpose_w<<<dim3(DFFP/32, 64), tb, 0, stream>>>(w3, w1w3t + (size_t)DFFP*2048, D_MODEL, DFF);
  k_rmsnorm<<<MTOK, 256, 0, stream>>>(out, g2, bufA);
  if (big){
    // combined W1|W3: N=11264, dual output h1/h3 (split at n0=5632), ldc=DFFP
    k_gemm8p<5><<<(MTOK/256)*((2*DFFP)/256), 512, 131072, stream>>>(bufA, w1w3t, nullptr, h3, h1, MTOK, 2*DFFP, D_MODEL, D_MODEL, D_MODEL, DFFP);
    k_silu_mul<<<(MTOK*DFFP/8 + 255)/256, 256, 0, stream>>>(h1, h3, h1, MTOK*DFFP/8);
    // W2 split-K x2: K=2752 each, 256 blocks (full machine), fp32 partials
    k_gemm8p<6><<<2*(MTOK/256)*(D_MODEL/256), 512, 131072, stream>>>(h1, w2t, nullptr, (const u16*)p1, p0, MTOK, D_MODEL, DFF/2, DFFP, DFF, D_MODEL);
    k_add2<<<2048, 256, 0, stream>>>(out, p0, p1, MTOK*D_MODEL/4);
  } else {
    k_gemm_bt<2><<<(DFFP/128)*32, 256, 0, stream>>>(bufA, w1w3t, nullptr, nullptr, nullptr, h1, MTOK, DFFP, D_MODEL, D_MODEL, D_MODEL, DFFP);
    k_gemm_bt<2><<<(DFFP/128)*32, 256, 0, stream>>>(bufA, w1w3t + (size_t)DFFP*2048, nullptr, nullptr, nullptr, h3, MTOK, DFFP, D_MODEL, D_MODEL, D_MODEL, DFFP);
    k_silu_mul<<<(MTOK*DFFP/8 + 255)/256, 256, 0, stream>>>(h1, h3, h1, MTOK*DFFP/8);
    k_gemm_bt<3><<<16*32, 256, 0, stream>>>(h1, w2t, nullptr, out, nullptr, out, MTOK, D_MODEL, DFF, DFFP, DFF, D_MODEL);
  }
}